// Round 8
// baseline (100522.784 us; speedup 1.0000x reference)
//
#include <hip/hip_runtime.h>
#include <hip/hip_bf16.h>

namespace k77 {

typedef long long ll;

constexpr int D    = 512;
constexpr int DTGT = 128;
constexpr int NB   = 1024;
constexpr int TS   = 64;
constexpr int TT   = 64;
constexpr int G4   = 2048;

template<typename T> __device__ inline double ldT(const T* p, ll i);
template<> __device__ inline double ldT<float>(const float* p, ll i) { return (double)p[i]; }
template<> __device__ inline double ldT<__hip_bfloat16>(const __hip_bfloat16* p, ll i) { return (double)__bfloat162float(p[i]); }
template<typename T> __device__ inline void stT(T* p, ll i, double v);
template<> __device__ inline void stT<float>(float* p, ll i, double v) { p[i] = (float)v; }
template<> __device__ inline void stT<__hip_bfloat16>(__hip_bfloat16* p, ll i, double v) { p[i] = __float2bfloat16((float)v); }

// ---------------- f64-accum precompute GEMM (tables + folds), f32 store ----------------
__global__ void tab_gemm64(const float* __restrict__ A, const float* __restrict__ B,
                           const float* __restrict__ b1, const float* __restrict__ b2,
                           float* __restrict__ C, int M, int N, int K, int ldc, float scale)
{
    int j = blockIdx.x * 256 + threadIdx.x;
    int m = blockIdx.y;
    if (j >= N || m >= M) return;
    const float* ar = A + (size_t)m * K;
    double acc = 0.0;
    for (int k = 0; k < K; ++k) acc += (double)ar[k] * (double)B[(size_t)k * N + j];
    if (b1) acc += (double)b1[j];
    if (b2) acc += (double)b2[j];
    C[(size_t)m * ldc + j] = (float)(acc * (double)scale);
}

// ---------------- encoder gate GEMM, f64: g = h64 @ Wh + table[src] ----------------
__global__ __launch_bounds__(256)
void enc_step64(const double* __restrict__ h, const float* __restrict__ Wh,
                const float* __restrict__ tab, const int* __restrict__ srcw,
                double* __restrict__ g, int K)
{
    __shared__ double As[16][65];
    __shared__ double Bs[16][65];
    const int tid = threadIdx.x;
    const int row0 = blockIdx.y * 64, col0 = blockIdx.x * 64;
    const int ty = tid >> 4, tx = tid & 15;
    double acc[4][4] = {};
    for (int k0 = 0; k0 < K; k0 += 16) {
#pragma unroll
        for (int l = 0; l < 4; ++l) { int t = tid + l * 256; int k = t & 15, m = t >> 4; As[k][m] = h[(size_t)(row0 + m) * D + k0 + k]; }
#pragma unroll
        for (int l = 0; l < 4; ++l) { int t = tid + l * 256; int j = t & 63, kr = t >> 6; Bs[kr][j] = (double)Wh[(size_t)(k0 + kr) * G4 + col0 + j]; }
        __syncthreads();
#pragma unroll
        for (int kk = 0; kk < 16; ++kk) {
            double a[4], b[4];
#pragma unroll
            for (int i = 0; i < 4; ++i) a[i] = As[kk][ty * 4 + i];
#pragma unroll
            for (int j = 0; j < 4; ++j) b[j] = Bs[kk][tx * 4 + j];
#pragma unroll
            for (int i = 0; i < 4; ++i)
#pragma unroll
                for (int j = 0; j < 4; ++j) acc[i][j] += a[i] * b[j];
        }
        __syncthreads();
    }
#pragma unroll
    for (int i = 0; i < 4; ++i) {
        int row = row0 + ty * 4 + i;
        const float* tr = tab + (size_t)srcw[(size_t)row * TS] * G4;
#pragma unroll
        for (int j = 0; j < 4; ++j) {
            int col = col0 + tx * 4 + j;
            g[(size_t)row * G4 + col] = acc[i][j] + (double)tr[col];
        }
    }
}

// ---------------- f64 LSTM cell (encoder) ----------------
__global__ void lstm_cell64(const double* __restrict__ g, int usec,
                            double* __restrict__ c, double* __restrict__ h)
{
    int idx = blockIdx.x * 256 + threadIdx.x;   // NB*D
    int b = idx >> 9, d = idx & (D - 1);
    const double* gr = g + (size_t)b * G4;
    double gi = gr[d], gf = gr[D + d], gg = gr[2 * D + d], go = gr[3 * D + d];
    double cc = usec ? c[idx] : 0.0;
    double si = 1.0 / (1.0 + exp(-gi));
    double sf = 1.0 / (1.0 + exp(-gf));
    double so = 1.0 / (1.0 + exp(-go));
    cc = sf * cc + si * tanh(gg);
    c[idx] = cc;
    h[idx] = so * tanh(cc);
}

// ---------------- K/V' fold, f64 accum: [K|V'] row trow += h64 @ WKVo[rowoff..] ----------------
template<typename KT, typename VT, int ACC>
__global__ __launch_bounds__(256)
void kv_fold64(const double* __restrict__ h, const float* __restrict__ W, int rowoff,
               const float* __restrict__ bias, KT* __restrict__ Kb, VT* __restrict__ Vb, int trow)
{
    __shared__ double As[16][65];
    __shared__ double Bs[16][65];
    const int tid = threadIdx.x;
    const int row0 = blockIdx.y * 64, col0 = blockIdx.x * 64;
    const int ty = tid >> 4, tx = tid & 15;
    double acc[4][4] = {};
    for (int k0 = 0; k0 < D; k0 += 16) {
#pragma unroll
        for (int l = 0; l < 4; ++l) { int t = tid + l * 256; int k = t & 15, m = t >> 4; As[k][m] = h[(size_t)(row0 + m) * D + k0 + k]; }
#pragma unroll
        for (int l = 0; l < 4; ++l) { int t = tid + l * 256; int j = t & 63, kr = t >> 6; Bs[kr][j] = (double)W[(size_t)(rowoff + k0 + kr) * 1024 + col0 + j]; }
        __syncthreads();
#pragma unroll
        for (int kk = 0; kk < 16; ++kk) {
            double a[4], b[4];
#pragma unroll
            for (int i = 0; i < 4; ++i) a[i] = As[kk][ty * 4 + i];
#pragma unroll
            for (int j = 0; j < 4; ++j) b[j] = Bs[kk][tx * 4 + j];
#pragma unroll
            for (int i = 0; i < 4; ++i)
#pragma unroll
                for (int j = 0; j < 4; ++j) acc[i][j] += a[i] * b[j];
        }
        __syncthreads();
    }
#pragma unroll
    for (int i = 0; i < 4; ++i) {
        int b0 = row0 + ty * 4 + i;
#pragma unroll
        for (int j = 0; j < 4; ++j) {
            int col = col0 + tx * 4 + j;
            double v = acc[i][j];
            if (bias) v += (double)bias[col];
            if (col < D) {
                ll ix = ((ll)b0 * TS + trow) * D + col;
                if (ACC) v += ldT(Kb, ix);
                stT(Kb, ix, v);
            } else {
                ll ix = ((ll)b0 * TS + trow) * D + (col - D);
                if (ACC) v += ldT(Vb, ix);
                stT(Vb, ix, v);
            }
        }
    }
}

// ---------------- decoder init: h0 = tanh([hF|hB]@hpw + b), c0 likewise, f64 ----------------
__global__ __launch_bounds__(512)
void hc_init64(const double* __restrict__ hF, const double* __restrict__ hB,
               const double* __restrict__ cF, const double* __restrict__ cB,
               const float* __restrict__ hpw, const float* __restrict__ hpb,
               const float* __restrict__ cpw, const float* __restrict__ cpb,
               double* __restrict__ h0, double* __restrict__ c0)
{
    __shared__ double sh[2][D];
    __shared__ double sc[2][D];
    const int b = blockIdx.x, j = threadIdx.x;
    sh[0][j] = hF[(size_t)b * D + j]; sh[1][j] = hB[(size_t)b * D + j];
    sc[0][j] = cF[(size_t)b * D + j]; sc[1][j] = cB[(size_t)b * D + j];
    __syncthreads();
    double a = (double)hpb[j];
    for (int k = 0; k < D; ++k) a += sh[0][k] * (double)hpw[(size_t)k * D + j];
    for (int k = 0; k < D; ++k) a += sh[1][k] * (double)hpw[(size_t)(k + D) * D + j];
    h0[(size_t)b * D + j] = tanh(a);
    a = (double)cpb[j];
    for (int k = 0; k < D; ++k) a += sc[0][k] * (double)cpw[(size_t)k * D + j];
    for (int k = 0; k < D; ++k) a += sc[1][k] * (double)cpw[(size_t)(k + D) * D + j];
    c0[(size_t)b * D + j] = tanh(a);
}

// ---------------- attention, f64: scores + softmax + ctx ----------------
template<typename KT, typename VT>
__global__ __launch_bounds__(512)
void attn64(const float* __restrict__ qtab, const int* __restrict__ amax,
            const KT* __restrict__ Kb, const VT* __restrict__ Vb,
            float* __restrict__ aout, int step, float* __restrict__ ctx)
{
    const int b = blockIdx.x, tid = threadIdx.x;
    __shared__ double qs[D];
    __shared__ double ss[TS];
    qs[tid] = (double)qtab[(size_t)amax[b] * D + tid];
    __syncthreads();
    const int t = tid >> 3, l8 = tid & 7;
    const ll kbase = ((ll)b * TS + t) * D;
    double acc = 0.0;
    for (int d = l8; d < D; d += 8) acc += qs[d] * ldT(Kb, kbase + d);
    acc += __shfl_xor(acc, 4);
    acc += __shfl_xor(acc, 2);
    acc += __shfl_xor(acc, 1);
    if (l8 == 0) ss[t] = acc;
    __syncthreads();
    if (tid < TS) {
        double v = ss[tid], mx = v;
#pragma unroll
        for (int o = 32; o; o >>= 1) mx = fmax(mx, __shfl_xor(mx, o));
        double e = exp(v - mx), sm = e;
#pragma unroll
        for (int o = 32; o; o >>= 1) sm += __shfl_xor(sm, o);
        double scv = e / sm;
        ss[tid] = scv;
        aout[((size_t)b * TT + step) * TS + tid] = (float)scv;
    }
    __syncthreads();
    double a = 0.0;
    const ll vbase = (ll)b * TS * D + tid;
    for (int t2 = 0; t2 < TS; ++t2) a += ss[t2] * ldT(Vb, vbase + (ll)t2 * D);
    ctx[(size_t)b * D + tid] = (float)a;
}

// ---------------- f64 decoder gates + cell (faithful, 8 batch rows per block) ----------------
__global__ __launch_bounds__(512)
void dec_gates64(const int* __restrict__ amax, const float* __restrict__ demb,
                 const float* __restrict__ ctx, const float* __restrict__ dwi,
                 const float* __restrict__ dwh, const float* __restrict__ dbi,
                 const float* __restrict__ dbh,
                 double* __restrict__ h64, double* __restrict__ c64)
{
    const int d  = threadIdx.x;
    const int b0 = blockIdx.x * 8;
    const double bI = (double)dbi[d]         + (double)dbh[d];
    const double bF = (double)dbi[D + d]     + (double)dbh[D + d];
    const double bG = (double)dbi[2 * D + d] + (double)dbh[2 * D + d];
    const double bO = (double)dbi[3 * D + d] + (double)dbh[3 * D + d];
    double aI[8], aF[8], aG[8], aO[8];
    int tok[8];
#pragma unroll
    for (int bb = 0; bb < 8; ++bb) {
        aI[bb] = bI; aF[bb] = bF; aG[bb] = bG; aO[bb] = bO;
        tok[bb] = amax[b0 + bb];
    }
    for (int k = 0; k < 3 * D; ++k) {
        const float* wr = (k < 2 * D) ? dwi + (size_t)k * G4 : dwh + (size_t)(k - 2 * D) * G4;
        const double w0 = wr[d], w1 = wr[D + d], w2 = wr[2 * D + d], w3 = wr[3 * D + d];
#pragma unroll
        for (int bb = 0; bb < 8; ++bb) {
            double x;
            if (k < D)          x = demb[(size_t)tok[bb] * D + k];
            else if (k < 2 * D) x = ctx[(size_t)(b0 + bb) * D + (k - D)];
            else                x = h64[(size_t)(b0 + bb) * D + (k - 2 * D)];
            aI[bb] += x * w0; aF[bb] += x * w1; aG[bb] += x * w2; aO[bb] += x * w3;
        }
    }
    __syncthreads();
#pragma unroll
    for (int bb = 0; bb < 8; ++bb) {
        const size_t ix = (size_t)(b0 + bb) * D + d;
        const double ci = c64[ix];
        const double i_ = 1.0 / (1.0 + exp(-aI[bb]));
        const double f_ = 1.0 / (1.0 + exp(-aF[bb]));
        const double o_ = 1.0 / (1.0 + exp(-aO[bb]));
        const double c  = f_ * ci + i_ * tanh(aG[bb]);
        c64[ix] = c;
        h64[ix] = o_ * tanh(c);
    }
}

// ---------------- f64 out projection + argmax ----------------
__global__ void out_argmax64(const double* __restrict__ h64, const float* __restrict__ W,
                             const float* __restrict__ bias, float* __restrict__ res,
                             int step, int* __restrict__ amax)
{
    const int b = blockIdx.x, tid = threadIdx.x;   // 128 threads
    __shared__ double hs[D];
    __shared__ double vals[DTGT];
    for (int k = tid; k < D; k += 128) hs[k] = h64[(size_t)b * D + k];
    __syncthreads();
    double acc = (double)bias[tid];
    for (int k = 0; k < D; ++k) acc += hs[k] * (double)W[(size_t)k * DTGT + tid];
    vals[tid] = acc;
    res[((size_t)b * TT + step) * DTGT + tid] = (float)acc;
    __syncthreads();
    if (tid == 0) {
        double best = vals[0]; int bi = 0;
        for (int j = 1; j < DTGT; ++j) if (vals[j] > best) { best = vals[j]; bi = j; }
        amax[b] = bi;
    }
}

__global__ void init_amax(const int* __restrict__ tgt, int* __restrict__ amax)
{
    int b = blockIdx.x * 256 + threadIdx.x;
    if (b < NB) amax[b] = tgt[(size_t)b * TT];
}

} // namespace k77

extern "C" void kernel_launch(void* const* d_in, const int* in_sizes, int n_in,
                              void* d_out, int out_size, void* d_ws, size_t ws_size,
                              hipStream_t stream)
{
    using namespace k77;
    (void)in_sizes; (void)n_in; (void)out_size;

    const int*   src        = (const int*)  d_in[0];
    const int*   tgt        = (const int*)  d_in[1];
    const float* enc_emb_w  = (const float*)d_in[2];
    const float* enc_wi_f   = (const float*)d_in[3];
    const float* enc_wh_f   = (const float*)d_in[4];
    const float* enc_bi_f   = (const float*)d_in[5];
    const float* enc_bh_f   = (const float*)d_in[6];
    const float* enc_wi_b   = (const float*)d_in[7];
    const float* enc_wh_b   = (const float*)d_in[8];
    const float* enc_bi_b   = (const float*)d_in[9];
    const float* enc_bh_b   = (const float*)d_in[10];
    const float* enc_post_w = (const float*)d_in[11];
    const float* enc_post_b = (const float*)d_in[12];
    const float* h_post_w   = (const float*)d_in[13];
    const float* h_post_b   = (const float*)d_in[14];
    const float* c_post_w   = (const float*)d_in[15];
    const float* c_post_b   = (const float*)d_in[16];
    const float* wq_w       = (const float*)d_in[17];
    const float* wq_b       = (const float*)d_in[18];
    const float* wk_w       = (const float*)d_in[19];
    const float* wk_b       = (const float*)d_in[20];
    const float* wv_w       = (const float*)d_in[21];
    const float* wv_b       = (const float*)d_in[22];
    const float* wo_w       = (const float*)d_in[23];
    const float* wo_b       = (const float*)d_in[24];
    const float* dec_emb_w  = (const float*)d_in[25];
    const float* dec_wi     = (const float*)d_in[26];
    const float* dec_wh     = (const float*)d_in[27];
    const float* dec_bi     = (const float*)d_in[28];
    const float* dec_bh     = (const float*)d_in[29];
    const float* dec_post_w = (const float*)d_in[30];
    const float* dec_post_b = (const float*)d_in[31];

    char* base = (char*)d_ws;
    size_t off = 0;
    auto alloc = [&](size_t bytes) { char* p = base + off; off += (bytes + 255) & ~(size_t)255; return (void*)p; };

    // f64 buffers first (alignment)
    double* g64    = (double*)alloc((size_t)NB * G4 * 8);
    double* hB64   = (double*)alloc((size_t)NB * D * 8);
    double* cB64   = (double*)alloc((size_t)NB * D * 8);
    double* hF64   = (double*)alloc((size_t)NB * D * 8);
    double* cF64   = (double*)alloc((size_t)NB * D * 8);
    double* hd64   = (double*)alloc((size_t)NB * D * 8);
    double* cd64   = (double*)alloc((size_t)NB * D * 8);
    // f32 buffers
    float* table_f = (float*)alloc((size_t)128 * G4 * 4);
    float* table_b = (float*)alloc((size_t)128 * G4 * 4);
    float* q_tab   = (float*)alloc((size_t)128 * D * 4);
    float* WKVo    = (float*)alloc((size_t)1024 * 1024 * 4);
    float* bkvo    = (float*)alloc(1024 * 4);
    float* WvT     = (float*)alloc((size_t)1024 * D * 4);
    float* bvT     = (float*)alloc(D * 4);
    float* ctxb    = (float*)alloc((size_t)NB * D * 4);
    int*   amax    = (int*)alloc(1024 * 4);

    const size_t common = off;
    const size_t kvCnt  = (size_t)NB * TS * D;          // per-tensor element count
    const size_t needB  = common + kvCnt * 2 + kvCnt * 4;   // K bf16 + V' f32
    const size_t needC  = common + kvCnt * 2 + kvCnt * 2;   // K bf16 + V' bf16

    const bool tierB = (ws_size >= needB);
    if (!tierB && ws_size < needC) {
        hipMemsetAsync(d_out, 0x7F, 1024, stream);   // sentinel: ws too small
        return;
    }
    __hip_bfloat16* Kh = (__hip_bfloat16*)(base + common);
    float*          Vf = nullptr;
    __hip_bfloat16* Vh = nullptr;
    if (tierB) Vf = (float*)(base + common + kvCnt * 2);
    else       Vh = (__hip_bfloat16*)(base + common + kvCnt * 2);

    float* attn_out = (float*)d_out;                       // output 0: (B,TT,TS) f32
    float* res_out  = attn_out + (size_t)NB * TT * TS;     // output 1: (B,TT,DTGT) f32

    const float scale = 0.044194173824159216f;   // 512^-0.5

    // ---------- precompute (f64 accum, f32 store) ----------
    tab_gemm64<<<dim3(8, 128), 256, 0, stream>>>(enc_emb_w, enc_wi_f, enc_bi_f, enc_bh_f, table_f, 128, G4, D, G4, 1.f);
    tab_gemm64<<<dim3(8, 128), 256, 0, stream>>>(enc_emb_w, enc_wi_b, enc_bi_b, enc_bh_b, table_b, 128, G4, D, G4, 1.f);
    tab_gemm64<<<dim3(2, 128), 256, 0, stream>>>(dec_emb_w, wq_w, wq_b, nullptr, q_tab, 128, D, D, D, scale);
    tab_gemm64<<<dim3(2, 1024), 256, 0, stream>>>(enc_post_w, wk_w, nullptr, nullptr, WKVo, 1024, D, D, 1024, 1.f);
    tab_gemm64<<<dim3(2, 1024), 256, 0, stream>>>(enc_post_w, wv_w, nullptr, nullptr, WvT, 1024, D, D, D, 1.f);
    tab_gemm64<<<dim3(2, 1024), 256, 0, stream>>>(WvT, wo_w, nullptr, nullptr, WKVo + D, 1024, D, D, 1024, 1.f);
    tab_gemm64<<<dim3(2, 1), 256, 0, stream>>>(enc_post_b, wk_w, wk_b, nullptr, bkvo, 1, D, D, D, 1.f);
    tab_gemm64<<<dim3(2, 1), 256, 0, stream>>>(enc_post_b, wv_w, wv_b, nullptr, bvT, 1, D, D, D, 1.f);
    tab_gemm64<<<dim3(2, 1), 256, 0, stream>>>(bvT, wo_w, wo_b, nullptr, bkvo + D, 1, D, D, D, 1.f);

    // ---------- encoder backward pass (f64), writes K/V' rows with bias ----------
    for (int t = 0; t < TS; ++t) {
        const int tf = TS - 1 - t;
        enc_step64<<<dim3(G4 / 64, NB / 64), 256, 0, stream>>>(hB64, enc_wh_b, table_b, src + tf, g64, t ? D : 0);
        lstm_cell64<<<NB * D / 256, 256, 0, stream>>>(g64, t ? 1 : 0, cB64, hB64);
        if (tierB)
            kv_fold64<__hip_bfloat16, float, 0><<<dim3(16, NB / 64), 256, 0, stream>>>(hB64, WKVo, D, bkvo, Kh, Vf, tf);
        else
            kv_fold64<__hip_bfloat16, __hip_bfloat16, 0><<<dim3(16, NB / 64), 256, 0, stream>>>(hB64, WKVo, D, bkvo, Kh, Vh, tf);
    }
    // ---------- encoder forward pass (f64), accumulates ----------
    for (int t = 0; t < TS; ++t) {
        enc_step64<<<dim3(G4 / 64, NB / 64), 256, 0, stream>>>(hF64, enc_wh_f, table_f, src + t, g64, t ? D : 0);
        lstm_cell64<<<NB * D / 256, 256, 0, stream>>>(g64, t ? 1 : 0, cF64, hF64);
        if (tierB)
            kv_fold64<__hip_bfloat16, float, 1><<<dim3(16, NB / 64), 256, 0, stream>>>(hF64, WKVo, 0, nullptr, Kh, Vf, t);
        else
            kv_fold64<__hip_bfloat16, __hip_bfloat16, 1><<<dim3(16, NB / 64), 256, 0, stream>>>(hF64, WKVo, 0, nullptr, Kh, Vh, t);
    }

    // ---------- decoder initial h, c (f64) ----------
    hc_init64<<<NB, 512, 0, stream>>>(hF64, hB64, cF64, cB64,
                                      h_post_w, h_post_b, c_post_w, c_post_b, hd64, cd64);
    init_amax<<<4, 256, 0, stream>>>(tgt, amax);

    // ---------- decoder: 64 steps (all decision math f64) ----------
    for (int st = 0; st < TT; ++st) {
        if (tierB)
            attn64<__hip_bfloat16, float><<<NB, 512, 0, stream>>>(q_tab, amax, Kh, Vf, attn_out, st, ctxb);
        else
            attn64<__hip_bfloat16, __hip_bfloat16><<<NB, 512, 0, stream>>>(q_tab, amax, Kh, Vh, attn_out, st, ctxb);
        dec_gates64<<<NB / 8, 512, 0, stream>>>(amax, dec_emb_w, ctxb, dec_wi, dec_wh,
                                                dec_bi, dec_bh, hd64, cd64);
        out_argmax64<<<NB, 128, 0, stream>>>(hd64, dec_post_w, dec_post_b, res_out, st, amax);
    }
}

// Round 10
// 38840.506 us; speedup vs baseline: 2.5881x; 2.5881x over previous
//
#include <hip/hip_runtime.h>
#include <hip/hip_bf16.h>

namespace k77 {

typedef long long ll;

constexpr int D    = 512;
constexpr int DTGT = 128;
constexpr int NB   = 1024;
constexpr int TS   = 64;
constexpr int TT   = 64;
constexpr int G4   = 2048;

__device__ inline float cvt(float x) { return x; }
__device__ inline float cvt(__hip_bfloat16 x) { return __bfloat162float(x); }

// ---------------- precompute GEMM (f64 accumulate, f32 store): tables + folds ----------------
__global__ void tab_gemm64(const float* __restrict__ A, const float* __restrict__ B,
                           const float* __restrict__ b1, const float* __restrict__ b2,
                           float* __restrict__ C, int M, int N, int K, int ldc, float scale)
{
    int j = blockIdx.x * 256 + threadIdx.x;
    int m = blockIdx.y;
    if (j >= N || m >= M) return;
    const float* ar = A + (size_t)m * K;
    double acc = 0.0;
    for (int k = 0; k < K; ++k) acc += (double)ar[k] * (double)B[(size_t)k * N + j];
    if (b1) acc += (double)b1[j];
    if (b2) acc += (double)b2[j];
    C[(size_t)m * ldc + j] = (float)(acc * (double)scale);
}

// ---------------- generic tiled GEMM: f32 storage/LDS, f64 ACCUMULATION ----------------
// A(row,k) = k<ksplit ? a0[row*ars0+aro0+k] : a1[row*ars1+aro1+(k-ksplit)]
// B(k,j)   = k<ksplit ? B0[(k+bo0)*N+j]     : B1[(k-ksplit+bo1)*N+j]
// epilogue (double): v += bias[col] + tbl[idx[row*idxstride]*N+col]; EPI: 0 none, 1 tanh, 2 accumulate
// C dtype per segment: BF0 (col<csplit -> c0), BF1 (else -> c1); 1 = bf16, 0 = f32
template<int BM, int BN, int BK, int TM, int TN, int EPI, int BF0, int BF1>
__global__ __launch_bounds__((BM / TM) * (BN / TN))
void gemm2(const float* __restrict__ a0, const float* __restrict__ a1,
           int ars0, int aro0, int ars1, int aro1, int ksplit,
           const float* __restrict__ B0, const float* __restrict__ B1, int bo0, int bo1,
           const float* __restrict__ bias,
           const float* __restrict__ tbl, const int* __restrict__ idx, int idxstride,
           void* c0v, void* c1v, ll cs0, ll co0, ll cs1, ll co1, int csplit,
           int N, int K)
{
    constexpr int NT = (BM / TM) * (BN / TN);
    __shared__ float As[BK][BM + 4];
    __shared__ float Bs[BK][BN + 4];
    const int tid  = threadIdx.x;
    const int row0 = blockIdx.y * BM, col0 = blockIdx.x * BN;
    const int ty = tid / (BN / TN);
    const int tx = tid % (BN / TN);

    double acc[TM][TN];
#pragma unroll
    for (int i = 0; i < TM; ++i)
#pragma unroll
        for (int j = 0; j < TN; ++j) acc[i][j] = 0.0;

    for (int k0 = 0; k0 < K; k0 += BK) {
#pragma unroll
        for (int l = 0; l < (BM * BK) / NT; ++l) {
            int t = tid + l * NT;
            int k = t % BK, m = t / BK;
            int kk = k0 + k;
            float v;
            if (kk < ksplit) v = a0[(size_t)(row0 + m) * ars0 + aro0 + kk];
            else             v = a1[(size_t)(row0 + m) * ars1 + aro1 + (kk - ksplit)];
            As[k][m] = v;
        }
#pragma unroll
        for (int l = 0; l < (BN * BK) / NT; ++l) {
            int t = tid + l * NT;
            int j = t % BN, kr = t / BN;
            int kk = k0 + kr;
            float v;
            if (kk < ksplit) v = B0[(size_t)(kk + bo0) * N + col0 + j];
            else             v = B1[(size_t)(kk - ksplit + bo1) * N + col0 + j];
            Bs[kr][j] = v;
        }
        __syncthreads();
#pragma unroll
        for (int kk = 0; kk < BK; ++kk) {
            double a[TM], b[TN];
#pragma unroll
            for (int i = 0; i < TM; ++i) a[i] = (double)As[kk][ty * TM + i];
#pragma unroll
            for (int j = 0; j < TN; ++j) b[j] = (double)Bs[kk][tx * TN + j];
#pragma unroll
            for (int i = 0; i < TM; ++i)
#pragma unroll
                for (int j = 0; j < TN; ++j) acc[i][j] = fma(a[i], b[j], acc[i][j]);
        }
        __syncthreads();
    }

#pragma unroll
    for (int i = 0; i < TM; ++i) {
        int row = row0 + ty * TM + i;
        const float* trow = nullptr;
        if (tbl) trow = tbl + (size_t)idx[(size_t)row * idxstride] * N;
#pragma unroll
        for (int j = 0; j < TN; ++j) {
            int col = col0 + tx * TN + j;
            double v = acc[i][j];
            if (bias) v += (double)bias[col];
            if (trow) v += (double)trow[col];
            if (EPI == 1) v = tanh(v);
            if (col < csplit) {
                ll ix = (ll)row * cs0 + co0 + col;
                if (BF0) {
                    __hip_bfloat16* p = (__hip_bfloat16*)c0v;
                    if (EPI == 2) v += (double)__bfloat162float(p[ix]);
                    p[ix] = __float2bfloat16((float)v);
                } else {
                    float* p = (float*)c0v;
                    if (EPI == 2) v += (double)p[ix];
                    p[ix] = (float)v;
                }
            } else {
                ll ix = (ll)row * cs1 + co1 + (col - csplit);
                if (BF1) {
                    __hip_bfloat16* p = (__hip_bfloat16*)c1v;
                    if (EPI == 2) v += (double)__bfloat162float(p[ix]);
                    p[ix] = __float2bfloat16((float)v);
                } else {
                    float* p = (float*)c1v;
                    if (EPI == 2) v += (double)p[ix];
                    p[ix] = (float)v;
                }
            }
        }
    }
}

// ---------------- LSTM elementwise cell (f32 — same noise class as refs' own f32 ops) ----------------
__global__ void lstm_elem(const float* __restrict__ g, const float* __restrict__ cin,
                          float* __restrict__ cout, float* __restrict__ hout)
{
    int idx = blockIdx.x * 256 + threadIdx.x;   // NB*D
    int b = idx >> 9, d = idx & (D - 1);
    const float* gr = g + (size_t)b * G4;
    float gi = gr[d], gf = gr[D + d], gg = gr[2 * D + d], go = gr[3 * D + d];
    float c = cin ? cin[idx] : 0.f;
    float si = 1.f / (1.f + expf(-gi));
    float sf = 1.f / (1.f + expf(-gf));
    float so = 1.f / (1.f + expf(-go));
    c = sf * c + si * tanhf(gg);
    cout[idx] = c;
    hout[idx] = so * tanhf(c);
}

// ---------------- attention: f64-accum scores + f32 softmax + f64-accum ctx ----------------
template<typename KT, typename VT>
__global__ void attn_kernel(const float* __restrict__ qtab, const int* __restrict__ amax,
                            const KT* __restrict__ Kb, const VT* __restrict__ Vb,
                            float* __restrict__ aout, int step, float* __restrict__ ctx)
{
    const int b = blockIdx.x, tid = threadIdx.x;   // 512 threads
    __shared__ float qs[D];
    __shared__ float ss[TS];
    qs[tid] = qtab[(size_t)amax[b] * D + tid];
    __syncthreads();
    const int t = tid >> 3, l8 = tid & 7;
    const KT* krow = Kb + ((size_t)b * TS + t) * D;
    double acc = 0.0;
    for (int d = l8; d < D; d += 8) acc += (double)qs[d] * (double)cvt(krow[d]);
    acc += __shfl_xor(acc, 4);
    acc += __shfl_xor(acc, 2);
    acc += __shfl_xor(acc, 1);
    if (l8 == 0) ss[t] = (float)acc;
    __syncthreads();
    if (tid < TS) {
        float v = ss[tid];
        float mx = v;
#pragma unroll
        for (int o = 32; o; o >>= 1) mx = fmaxf(mx, __shfl_xor(mx, o));
        float e = expf(v - mx);
        float sm = e;
#pragma unroll
        for (int o = 32; o; o >>= 1) sm += __shfl_xor(sm, o);
        float sc = e / sm;
        ss[tid] = sc;
        aout[((size_t)b * TT + step) * TS + tid] = sc;
    }
    __syncthreads();
    double a = 0.0;
    const VT* vcol = Vb + (size_t)b * TS * D + tid;
    for (int t2 = 0; t2 < TS; ++t2) a += (double)ss[t2] * (double)cvt(vcol[(size_t)t2 * D]);
    ctx[(size_t)b * D + tid] = (float)a;
}

// ---------------- out projection + argmax: f64 accumulate + f64 compare ----------------
__global__ void out_argmax(const float* __restrict__ h, const float* __restrict__ W,
                           const float* __restrict__ bias, float* __restrict__ res,
                           int step, int* __restrict__ amax)
{
    const int b = blockIdx.x, tid = threadIdx.x;   // 128 threads
    __shared__ float hs[D];
    __shared__ double vals[DTGT];
    for (int k = tid; k < D; k += 128) hs[k] = h[(size_t)b * D + k];
    __syncthreads();
    double acc = (double)bias[tid];
    for (int k = 0; k < D; ++k) acc += (double)hs[k] * (double)W[(size_t)k * DTGT + tid];
    vals[tid] = acc;
    res[((size_t)b * TT + step) * DTGT + tid] = (float)acc;
    __syncthreads();
    if (tid == 0) {
        double best = vals[0]; int bi = 0;
        for (int j = 1; j < DTGT; ++j) if (vals[j] > best) { best = vals[j]; bi = j; }
        amax[b] = bi;
    }
}

__global__ void init_amax(const int* __restrict__ tgt, int* __restrict__ amax)
{
    int b = blockIdx.x * 256 + threadIdx.x;
    if (b < NB) amax[b] = tgt[(size_t)b * TT];
}

} // namespace k77

extern "C" void kernel_launch(void* const* d_in, const int* in_sizes, int n_in,
                              void* d_out, int out_size, void* d_ws, size_t ws_size,
                              hipStream_t stream)
{
    using namespace k77;
    (void)in_sizes; (void)n_in; (void)out_size;

    const int*   src        = (const int*)  d_in[0];
    const int*   tgt        = (const int*)  d_in[1];
    const float* enc_emb_w  = (const float*)d_in[2];
    const float* enc_wi_f   = (const float*)d_in[3];
    const float* enc_wh_f   = (const float*)d_in[4];
    const float* enc_bi_f   = (const float*)d_in[5];
    const float* enc_bh_f   = (const float*)d_in[6];
    const float* enc_wi_b   = (const float*)d_in[7];
    const float* enc_wh_b   = (const float*)d_in[8];
    const float* enc_bi_b   = (const float*)d_in[9];
    const float* enc_bh_b   = (const float*)d_in[10];
    const float* enc_post_w = (const float*)d_in[11];
    const float* enc_post_b = (const float*)d_in[12];
    const float* h_post_w   = (const float*)d_in[13];
    const float* h_post_b   = (const float*)d_in[14];
    const float* c_post_w   = (const float*)d_in[15];
    const float* c_post_b   = (const float*)d_in[16];
    const float* wq_w       = (const float*)d_in[17];
    const float* wq_b       = (const float*)d_in[18];
    const float* wk_w       = (const float*)d_in[19];
    const float* wk_b       = (const float*)d_in[20];
    const float* wv_w       = (const float*)d_in[21];
    const float* wv_b       = (const float*)d_in[22];
    const float* wo_w       = (const float*)d_in[23];
    const float* wo_b       = (const float*)d_in[24];
    const float* dec_emb_w  = (const float*)d_in[25];
    const float* dec_wi     = (const float*)d_in[26];
    const float* dec_wh     = (const float*)d_in[27];
    const float* dec_bi     = (const float*)d_in[28];
    const float* dec_bh     = (const float*)d_in[29];
    const float* dec_post_w = (const float*)d_in[30];
    const float* dec_post_b = (const float*)d_in[31];

    float* ws = (float*)d_ws;
    size_t off = 0;
    auto alloc = [&](size_t n) { float* p = ws + off; off += n; return p; };
    float* g       = alloc((size_t)NB * G4);     // gate buffer; also aliased for fold temps
    float* hB      = alloc((size_t)NB * D);
    float* cB      = alloc((size_t)NB * D);
    float* hF      = alloc((size_t)NB * D);
    float* cF      = alloc((size_t)NB * D);
    float* hdec    = alloc((size_t)NB * D);
    float* cdec    = alloc((size_t)NB * D);
    float* ctxb    = alloc((size_t)NB * D);
    float* table_f = alloc((size_t)128 * G4);
    float* table_b = alloc((size_t)128 * G4);
    float* dec_tab = alloc((size_t)128 * G4);
    float* q_tab   = alloc((size_t)128 * D);
    float* WKVo    = alloc((size_t)1024 * 1024); // [WK | WV@wo]
    float* bkvo    = alloc(1024);
    int*   amax    = (int*)alloc(1024);
    // fold temps alias the (not-yet-used) gate buffer
    float* Wv_tmp  = g;                           // 1024*512 floats < NB*G4
    float* bv_tmp  = g + (size_t)1024 * 512;

    const size_t commonF = off;
    const size_t kvCnt   = (size_t)NB * TS * D;                   // 33.5M elements each
    const size_t need    = commonF * 4 + kvCnt * 2 + kvCnt * 4;   // K bf16 + V' f32 (~235 MB)

    if (ws_size < need) {
        hipMemsetAsync(d_out, 0x7F, 1024, stream);   // sentinel: huge absmax => ws too small
        return;
    }
    __hip_bfloat16* Kh = (__hip_bfloat16*)(ws + commonF);
    float*          Vf = (float*)((char*)Kh + kvCnt * 2);

    float* attn_out = (float*)d_out;                       // (B,TT,TS) f32
    float* res_out  = attn_out + (size_t)NB * TT * TS;     // (B,TT,DTGT) f32

    const float scale = 0.044194173824159216f;   // 512^-0.5

    // ---------- one-time precompute (f64-accum folds/tables) ----------
    tab_gemm64<<<dim3(8, 128), 256, 0, stream>>>(enc_emb_w, enc_wi_f, enc_bi_f, enc_bh_f, table_f, 128, G4, D, G4, 1.f);
    tab_gemm64<<<dim3(8, 128), 256, 0, stream>>>(enc_emb_w, enc_wi_b, enc_bi_b, enc_bh_b, table_b, 128, G4, D, G4, 1.f);
    tab_gemm64<<<dim3(8, 128), 256, 0, stream>>>(dec_emb_w, dec_wi,   dec_bi,   dec_bh,   dec_tab, 128, G4, D, G4, 1.f);
    tab_gemm64<<<dim3(2, 128), 256, 0, stream>>>(dec_emb_w, wq_w, wq_b, nullptr, q_tab, 128, D, D, D, scale);
    tab_gemm64<<<dim3(2, 1024), 256, 0, stream>>>(enc_post_w, wk_w, nullptr, nullptr, WKVo, 1024, D, D, 1024, 1.f);
    tab_gemm64<<<dim3(2, 1024), 256, 0, stream>>>(enc_post_w, wv_w, nullptr, nullptr, Wv_tmp, 1024, D, D, D, 1.f);
    tab_gemm64<<<dim3(2, 1024), 256, 0, stream>>>(Wv_tmp, wo_w, nullptr, nullptr, WKVo + D, 1024, D, D, 1024, 1.f);
    tab_gemm64<<<dim3(2, 1), 256, 0, stream>>>(enc_post_b, wk_w, wk_b, nullptr, bkvo, 1, D, D, D, 1.f);
    tab_gemm64<<<dim3(2, 1), 256, 0, stream>>>(enc_post_b, wv_w, wv_b, nullptr, bv_tmp, 1, D, D, D, 1.f);
    tab_gemm64<<<dim3(2, 1), 256, 0, stream>>>(bv_tmp, wo_w, wo_b, nullptr, bkvo + D, 1, D, D, D, 1.f);

    // ---------- encoder backward pass (writes K bf16 / V' f32 rows with bias) ----------
    for (int t = 0; t < TS; ++t) {
        const int tf = TS - 1 - t;
        gemm2<64, 128, 16, 4, 8, 0, 0, 0><<<dim3(G4 / 128, NB / 64), 256, 0, stream>>>(
            hB, hB, D, 0, D, 0, D,
            enc_wh_b, enc_wh_b, 0, 0, nullptr,
            table_b, src + tf, TS,
            g, g, G4, 0, G4, 0, G4, G4, t ? D : 0);
        lstm_elem<<<NB * D / 256, 256, 0, stream>>>(g, t ? cB : nullptr, cB, hB);
        gemm2<64, 128, 16, 4, 8, 0, 1, 0><<<dim3(8, NB / 64), 256, 0, stream>>>(
            hB, hB, D, 0, D, 0, D,
            WKVo, WKVo, D, D, bkvo,
            nullptr, nullptr, 0,
            Kh, Vf, (ll)TS * D, (ll)tf * D, (ll)TS * D, (ll)tf * D, D, 2 * D, D);
    }

    // ---------- encoder forward pass (accumulates into K/V' rows) ----------
    for (int t = 0; t < TS; ++t) {
        gemm2<64, 128, 16, 4, 8, 0, 0, 0><<<dim3(G4 / 128, NB / 64), 256, 0, stream>>>(
            hF, hF, D, 0, D, 0, D,
            enc_wh_f, enc_wh_f, 0, 0, nullptr,
            table_f, src + t, TS,
            g, g, G4, 0, G4, 0, G4, G4, t ? D : 0);
        lstm_elem<<<NB * D / 256, 256, 0, stream>>>(g, t ? cF : nullptr, cF, hF);
        gemm2<64, 128, 16, 4, 8, 2, 1, 0><<<dim3(8, NB / 64), 256, 0, stream>>>(
            hF, hF, D, 0, D, 0, D,
            WKVo, WKVo, 0, 0, nullptr,
            nullptr, nullptr, 0,
            Kh, Vf, (ll)TS * D, (ll)t * D, (ll)TS * D, (ll)t * D, D, 2 * D, D);
    }

    // ---------- decoder initial h, c ----------
    gemm2<64, 128, 16, 4, 8, 1, 0, 0><<<dim3(4, NB / 64), 256, 0, stream>>>(
        hF, hB, D, 0, D, 0, D,
        h_post_w, h_post_w, 0, D, h_post_b,
        nullptr, nullptr, 0,
        hdec, hdec, D, 0, D, 0, D, D, 2 * D);
    gemm2<64, 128, 16, 4, 8, 1, 0, 0><<<dim3(4, NB / 64), 256, 0, stream>>>(
        cF, cB, D, 0, D, 0, D,
        c_post_w, c_post_w, 0, D, c_post_b,
        nullptr, nullptr, 0,
        cdec, cdec, D, 0, D, 0, D, D, 2 * D);

    init_amax<<<4, 256, 0, stream>>>(tgt, amax);

    // ---------- decoder: 64 steps ----------
    for (int st = 0; st < TT; ++st) {
        attn_kernel<__hip_bfloat16, float><<<NB, 512, 0, stream>>>(q_tab, amax, Kh, Vf, attn_out, st, ctxb);
        gemm2<64, 128, 16, 4, 8, 0, 0, 0><<<dim3(G4 / 128, NB / 64), 256, 0, stream>>>(
            ctxb, hdec, D, 0, D, 0, D,
            dec_wi, dec_wh, D, 0, nullptr,
            dec_tab, amax, 1,
            g, g, G4, 0, G4, 0, G4, G4, 2 * D);
        lstm_elem<<<NB * D / 256, 256, 0, stream>>>(g, cdec, cdec, hdec);
        out_argmax<<<NB, 128, 0, stream>>>(hdec, dec_post_w, dec_post_b, res_out, st, amax);
    }
}

// Round 11
// 36067.068 us; speedup vs baseline: 2.7871x; 1.0769x over previous
//
#include <hip/hip_runtime.h>
#include <hip/hip_bf16.h>

namespace k77 {

typedef long long ll;

constexpr int D    = 512;
constexpr int DTGT = 128;
constexpr int NB   = 1024;
constexpr int TS   = 64;
constexpr int TT   = 64;
constexpr int G4   = 2048;

// ---------------- precompute GEMM (f64 accumulate, f32 store), optional gate-permute on store ----------------
// perm: store col j at j' = (j&511)*4 + (j>>9)   [d*4+gate layout]
__global__ void tab_gemm64(const float* __restrict__ A, const float* __restrict__ B,
                           const float* __restrict__ b1, const float* __restrict__ b2,
                           float* __restrict__ C, int M, int N, int K, int ldc, float scale, int perm)
{
    int j = blockIdx.x * 256 + threadIdx.x;
    int m = blockIdx.y;
    if (j >= N || m >= M) return;
    const float* ar = A + (size_t)m * K;
    double acc = 0.0;
    for (int k = 0; k < K; ++k) acc += (double)ar[k] * (double)B[(size_t)k * N + j];
    if (b1) acc += (double)b1[j];
    if (b2) acc += (double)b2[j];
    int j2 = perm ? ((j & 511) * 4 + (j >> 9)) : j;
    C[(size_t)m * ldc + j2] = (float)(acc * (double)scale);
}

// permute a raw [512][2048] weight block (rows rowoff..rowoff+511) into d*4+gate column layout
__global__ void permW(const float* __restrict__ in, float* __restrict__ out, int rowoff)
{
    int j = blockIdx.x * 256 + threadIdx.x;   // 0..2047
    int k = blockIdx.y;                        // 0..511
    out[(size_t)k * G4 + (j & 511) * 4 + (j >> 9)] = in[(size_t)(k + rowoff) * G4 + j];
}

// pre-fill K (bf16) and V' (f32) with their biases so both encoder directions accumulate
__global__ void init_kv(const float* __restrict__ bkvo, __hip_bfloat16* __restrict__ Kb,
                        float* __restrict__ Vb)
{
    for (ll i = (ll)blockIdx.x * 256 + threadIdx.x; i < (ll)NB * TS * D; i += (ll)gridDim.x * 256) {
        int d = (int)(i & (D - 1));
        Kb[i] = __float2bfloat16(bkvo[d]);
        Vb[i] = bkvo[D + d];
    }
}

// ---------------- fused gates GEMM + LSTM cell ----------------
// Tile 64x64, 256 thr, TM=2, TN=8 (=2 gate-quadruples). f64 LDS, f64 accum, f32 cell (r10 class).
// USE2: 2-segment A/B (decoder: A=[ctx|h], B=[dec_wiP|dec_whP]).  blockIdx.z selects direction set.
template<int USE2>
__global__ __launch_bounds__(256)
void gates_cell(const float* __restrict__ a0_0, const float* __restrict__ a0_1,
                const float* __restrict__ a1_0, const float* __restrict__ a1_1,
                const float* __restrict__ B0_0, const float* __restrict__ B0_1,
                const float* __restrict__ B1_0, const float* __restrict__ B1_1,
                const float* __restrict__ tab_0, const float* __restrict__ tab_1,
                const int* __restrict__ idx_0, const int* __restrict__ idx_1, int idxStride,
                float* c_0, float* c_1, float* h_0, float* h_1,
                int K, int useC)
{
    const int zz = blockIdx.z;
    const float* a0  = zz ? a0_1 : a0_0;
    const float* a1  = zz ? a1_1 : a1_0;
    const float* B0  = zz ? B0_1 : B0_0;
    const float* B1  = zz ? B1_1 : B1_0;
    const float* tab = zz ? tab_1 : tab_0;
    const int*   idx = zz ? idx_1 : idx_0;
    float* cb = zz ? c_1 : c_0;
    float* hb = zz ? h_1 : h_0;

    __shared__ double As[16][66];
    __shared__ double Bs[16][72];   // col' = col + (col>>3) swizzle
    const int tid  = threadIdx.x;
    const int row0 = blockIdx.y * 64, col0 = blockIdx.x * 64;
    const int ty = tid >> 3, tx = tid & 7;

    double acc[2][8];
#pragma unroll
    for (int i = 0; i < 2; ++i)
#pragma unroll
        for (int j = 0; j < 8; ++j) acc[i][j] = 0.0;

    for (int k0 = 0; k0 < K; k0 += 16) {
#pragma unroll
        for (int l = 0; l < 4; ++l) {
            int t = tid + l * 256; int k = t & 15, m = t >> 4;
            int kk = k0 + k;
            float v;
            if (USE2 && kk >= D) v = a1[(size_t)(row0 + m) * D + (kk - D)];
            else                 v = a0[(size_t)(row0 + m) * D + kk];
            As[k][m] = (double)v;
        }
#pragma unroll
        for (int l = 0; l < 4; ++l) {
            int t = tid + l * 256; int j = t & 63, kr = t >> 6;
            int kk = k0 + kr;
            float v;
            if (USE2 && kk >= D) v = B1[(size_t)(kk - D) * G4 + col0 + j];
            else                 v = B0[(size_t)kk * G4 + col0 + j];
            Bs[kr][j + (j >> 3)] = (double)v;
        }
        __syncthreads();
        const int bbase = tx * 9;
#pragma unroll
        for (int kk = 0; kk < 16; ++kk) {
            double av0 = As[kk][ty * 2], av1 = As[kk][ty * 2 + 1];
            double b[8];
#pragma unroll
            for (int j = 0; j < 8; ++j) b[j] = Bs[kk][bbase + j];
#pragma unroll
            for (int j = 0; j < 8; ++j) {
                acc[0][j] = fma(av0, b[j], acc[0][j]);
                acc[1][j] = fma(av1, b[j], acc[1][j]);
            }
        }
        __syncthreads();
    }

    // epilogue: add permuted table row, round to f32, run LSTM cell (2 rows x 2 dims/thread)
#pragma unroll
    for (int i = 0; i < 2; ++i) {
        int row = row0 + ty * 2 + i;
        const float* tr = tab + (size_t)idx[(size_t)row * idxStride] * G4;
        int cbase = col0 + tx * 8;
#pragma unroll
        for (int q = 0; q < 2; ++q) {
            int cc = cbase + q * 4;
            int d  = cc >> 2;
            float gi = (float)(acc[i][q * 4 + 0] + (double)tr[cc + 0]);
            float gf = (float)(acc[i][q * 4 + 1] + (double)tr[cc + 1]);
            float gg = (float)(acc[i][q * 4 + 2] + (double)tr[cc + 2]);
            float go = (float)(acc[i][q * 4 + 3] + (double)tr[cc + 3]);
            float c  = useC ? cb[(size_t)row * D + d] : 0.f;
            float si = 1.f / (1.f + expf(-gi));
            float sf = 1.f / (1.f + expf(-gf));
            float so = 1.f / (1.f + expf(-go));
            c = sf * c + si * tanhf(gg);
            cb[(size_t)row * D + d] = c;
            hb[(size_t)row * D + d] = so * tanhf(c);
        }
    }
}

// ---------------- K/V' fold: [K|V'] row trow += h @ WKVo[rowoff..] (f64 accum), both dirs ----------------
__global__ __launch_bounds__(256)
void fold_kernel(const float* __restrict__ h_0, const float* __restrict__ h_1,
                 const float* __restrict__ W,
                 __hip_bfloat16* __restrict__ Kb, float* __restrict__ Vb,
                 int trow0, int trow1)
{
    const int zz = blockIdx.z;
    const float* h = zz ? h_1 : h_0;
    const int rowoff = zz ? D : 0;
    const int trow   = zz ? trow1 : trow0;

    __shared__ double As[16][66];
    __shared__ double Bs[16][72];
    const int tid  = threadIdx.x;
    const int row0 = blockIdx.y * 64, col0 = blockIdx.x * 64;
    const int ty = tid >> 3, tx = tid & 7;

    double acc[2][8];
#pragma unroll
    for (int i = 0; i < 2; ++i)
#pragma unroll
        for (int j = 0; j < 8; ++j) acc[i][j] = 0.0;

    for (int k0 = 0; k0 < D; k0 += 16) {
#pragma unroll
        for (int l = 0; l < 4; ++l) {
            int t = tid + l * 256; int k = t & 15, m = t >> 4;
            As[k][m] = (double)h[(size_t)(row0 + m) * D + k0 + k];
        }
#pragma unroll
        for (int l = 0; l < 4; ++l) {
            int t = tid + l * 256; int j = t & 63, kr = t >> 6;
            Bs[kr][j + (j >> 3)] = (double)W[(size_t)(rowoff + k0 + kr) * 1024 + col0 + j];
        }
        __syncthreads();
        const int bbase = tx * 9;
#pragma unroll
        for (int kk = 0; kk < 16; ++kk) {
            double av0 = As[kk][ty * 2], av1 = As[kk][ty * 2 + 1];
            double b[8];
#pragma unroll
            for (int j = 0; j < 8; ++j) b[j] = Bs[kk][bbase + j];
#pragma unroll
            for (int j = 0; j < 8; ++j) {
                acc[0][j] = fma(av0, b[j], acc[0][j]);
                acc[1][j] = fma(av1, b[j], acc[1][j]);
            }
        }
        __syncthreads();
    }

#pragma unroll
    for (int i = 0; i < 2; ++i) {
        int row = row0 + ty * 2 + i;
#pragma unroll
        for (int j = 0; j < 8; ++j) {
            int col = col0 + tx * 8 + j;
            double v = acc[i][j];
            ll ix = ((ll)row * TS + trow) * D + (col & (D - 1));
            if (col < D) {
                double v2 = v + (double)__bfloat162float(Kb[ix]);
                Kb[ix] = __float2bfloat16((float)v2);
            } else {
                Vb[ix] = (float)((double)Vb[ix] + v);
            }
        }
    }
}

// ---------------- decoder init: h0 = tanh([hF|hB]@hpw + b), c0 likewise (f64 accum) ----------------
__global__ __launch_bounds__(512)
void hc_init(const float* __restrict__ hF, const float* __restrict__ hB,
             const float* __restrict__ cF, const float* __restrict__ cB,
             const float* __restrict__ hpw, const float* __restrict__ hpb,
             const float* __restrict__ cpw, const float* __restrict__ cpb,
             float* __restrict__ h0, float* __restrict__ c0)
{
    __shared__ float s0[D], s1[D], s2[D], s3[D];
    const int b = blockIdx.x, j = threadIdx.x;
    s0[j] = hF[(size_t)b * D + j]; s1[j] = hB[(size_t)b * D + j];
    s2[j] = cF[(size_t)b * D + j]; s3[j] = cB[(size_t)b * D + j];
    __syncthreads();
    double a = (double)hpb[j];
    for (int k = 0; k < D; ++k) a += (double)s0[k] * (double)hpw[(size_t)k * D + j];
    for (int k = 0; k < D; ++k) a += (double)s1[k] * (double)hpw[(size_t)(k + D) * D + j];
    h0[(size_t)b * D + j] = (float)tanh(a);
    a = (double)cpb[j];
    for (int k = 0; k < D; ++k) a += (double)s2[k] * (double)cpw[(size_t)k * D + j];
    for (int k = 0; k < D; ++k) a += (double)s3[k] * (double)cpw[(size_t)(k + D) * D + j];
    c0[(size_t)b * D + j] = (float)tanh(a);
}

// ---------------- attention: f64-accum scores + f32 softmax + f64-accum ctx (r10-verified) ----------------
__global__ void attn_kernel(const float* __restrict__ qtab, const int* __restrict__ amax,
                            const __hip_bfloat16* __restrict__ Kb, const float* __restrict__ Vb,
                            float* __restrict__ aout, int step, float* __restrict__ ctx)
{
    const int b = blockIdx.x, tid = threadIdx.x;   // 512 threads
    __shared__ float qs[D];
    __shared__ float ss[TS];
    qs[tid] = qtab[(size_t)amax[b] * D + tid];
    __syncthreads();
    const int t = tid >> 3, l8 = tid & 7;
    const __hip_bfloat16* krow = Kb + ((size_t)b * TS + t) * D;
    double acc = 0.0;
    for (int d = l8; d < D; d += 8) acc += (double)qs[d] * (double)__bfloat162float(krow[d]);
    acc += __shfl_xor(acc, 4);
    acc += __shfl_xor(acc, 2);
    acc += __shfl_xor(acc, 1);
    if (l8 == 0) ss[t] = (float)acc;
    __syncthreads();
    if (tid < TS) {
        float v = ss[tid];
        float mx = v;
#pragma unroll
        for (int o = 32; o; o >>= 1) mx = fmaxf(mx, __shfl_xor(mx, o));
        float e = expf(v - mx);
        float sm = e;
#pragma unroll
        for (int o = 32; o; o >>= 1) sm += __shfl_xor(sm, o);
        float sc = e / sm;
        ss[tid] = sc;
        aout[((size_t)b * TT + step) * TS + tid] = sc;
    }
    __syncthreads();
    double a = 0.0;
    const float* vcol = Vb + (size_t)b * TS * D + tid;
    for (int t2 = 0; t2 < TS; ++t2) a += (double)ss[t2] * (double)vcol[(size_t)t2 * D];
    ctx[(size_t)b * D + tid] = (float)a;
}

// ---------------- out projection + argmax: f64 accumulate + f64 compare (r10-verified) ----------------
__global__ void out_argmax(const float* __restrict__ h, const float* __restrict__ W,
                           const float* __restrict__ bias, float* __restrict__ res,
                           int step, int* __restrict__ amax)
{
    const int b = blockIdx.x, tid = threadIdx.x;   // 128 threads
    __shared__ float hs[D];
    __shared__ double vals[DTGT];
    for (int k = tid; k < D; k += 128) hs[k] = h[(size_t)b * D + k];
    __syncthreads();
    double acc = (double)bias[tid];
    for (int k = 0; k < D; ++k) acc += (double)hs[k] * (double)W[(size_t)k * DTGT + tid];
    vals[tid] = acc;
    res[((size_t)b * TT + step) * DTGT + tid] = (float)acc;
    __syncthreads();
    if (tid == 0) {
        double best = vals[0]; int bi = 0;
        for (int j = 1; j < DTGT; ++j) if (vals[j] > best) { best = vals[j]; bi = j; }
        amax[b] = bi;
    }
}

__global__ void init_amax(const int* __restrict__ tgt, int* __restrict__ amax)
{
    int b = blockIdx.x * 256 + threadIdx.x;
    if (b < NB) amax[b] = tgt[(size_t)b * TT];
}

} // namespace k77

extern "C" void kernel_launch(void* const* d_in, const int* in_sizes, int n_in,
                              void* d_out, int out_size, void* d_ws, size_t ws_size,
                              hipStream_t stream)
{
    using namespace k77;
    (void)in_sizes; (void)n_in; (void)out_size;

    const int*   src        = (const int*)  d_in[0];
    const int*   tgt        = (const int*)  d_in[1];
    const float* enc_emb_w  = (const float*)d_in[2];
    const float* enc_wi_f   = (const float*)d_in[3];
    const float* enc_wh_f   = (const float*)d_in[4];
    const float* enc_bi_f   = (const float*)d_in[5];
    const float* enc_bh_f   = (const float*)d_in[6];
    const float* enc_wi_b   = (const float*)d_in[7];
    const float* enc_wh_b   = (const float*)d_in[8];
    const float* enc_bi_b   = (const float*)d_in[9];
    const float* enc_bh_b   = (const float*)d_in[10];
    const float* enc_post_w = (const float*)d_in[11];
    const float* enc_post_b = (const float*)d_in[12];
    const float* h_post_w   = (const float*)d_in[13];
    const float* h_post_b   = (const float*)d_in[14];
    const float* c_post_w   = (const float*)d_in[15];
    const float* c_post_b   = (const float*)d_in[16];
    const float* wq_w       = (const float*)d_in[17];
    const float* wq_b       = (const float*)d_in[18];
    const float* wk_w       = (const float*)d_in[19];
    const float* wk_b       = (const float*)d_in[20];
    const float* wv_w       = (const float*)d_in[21];
    const float* wv_b       = (const float*)d_in[22];
    const float* wo_w       = (const float*)d_in[23];
    const float* wo_b       = (const float*)d_in[24];
    const float* dec_emb_w  = (const float*)d_in[25];
    const float* dec_wi     = (const float*)d_in[26];
    const float* dec_wh     = (const float*)d_in[27];
    const float* dec_bi     = (const float*)d_in[28];
    const float* dec_bh     = (const float*)d_in[29];
    const float* dec_post_w = (const float*)d_in[30];
    const float* dec_post_b = (const float*)d_in[31];

    float* ws = (float*)d_ws;
    size_t off = 0;
    auto alloc = [&](size_t n) { float* p = ws + off; off += n; return p; };
    float* hF0     = alloc((size_t)NB * D);
    float* hF1     = alloc((size_t)NB * D);
    float* hB0     = alloc((size_t)NB * D);
    float* hB1     = alloc((size_t)NB * D);
    float* cF      = alloc((size_t)NB * D);
    float* cB      = alloc((size_t)NB * D);
    float* hd0     = alloc((size_t)NB * D);
    float* hd1     = alloc((size_t)NB * D);
    float* cdec    = alloc((size_t)NB * D);
    float* ctxb    = alloc((size_t)NB * D);
    float* tabPf   = alloc((size_t)128 * G4);
    float* tabPb   = alloc((size_t)128 * G4);
    float* dec_tabP= alloc((size_t)128 * G4);
    float* q_tab   = alloc((size_t)128 * D);
    float* WKVo    = alloc((size_t)1024 * 1024);
    float* bkvo    = alloc(1024);
    float* WhPf    = alloc((size_t)D * G4);
    float* WhPb    = alloc((size_t)D * G4);
    float* dec_wiP = alloc((size_t)D * G4);
    float* dec_whP = alloc((size_t)D * G4);
    float* Wv_tmp  = alloc((size_t)1024 * D);
    float* bv_tmp  = alloc(D);
    int*   amax    = (int*)alloc(1024);

    const size_t commonF = off;
    const size_t kvCnt   = (size_t)NB * TS * D;
    const size_t need    = commonF * 4 + kvCnt * 2 + kvCnt * 4;   // ~249 MB

    if (ws_size < need) {
        hipMemsetAsync(d_out, 0x7F, 1024, stream);   // sentinel: ws too small
        return;
    }
    __hip_bfloat16* Kh = (__hip_bfloat16*)(ws + commonF);
    float*          Vf = (float*)((char*)Kh + kvCnt * 2);

    float* attn_out = (float*)d_out;
    float* res_out  = attn_out + (size_t)NB * TT * TS;

    const float scale = 0.044194173824159216f;   // 512^-0.5

    float* hFbuf[2] = {hF0, hF1};
    float* hBbuf[2] = {hB0, hB1};
    float* hd[2]    = {hd0, hd1};

    // ---------- precompute ----------
    tab_gemm64<<<dim3(8, 128), 256, 0, stream>>>(enc_emb_w, enc_wi_f, enc_bi_f, enc_bh_f, tabPf, 128, G4, D, G4, 1.f, 1);
    tab_gemm64<<<dim3(8, 128), 256, 0, stream>>>(enc_emb_w, enc_wi_b, enc_bi_b, enc_bh_b, tabPb, 128, G4, D, G4, 1.f, 1);
    tab_gemm64<<<dim3(8, 128), 256, 0, stream>>>(dec_emb_w, dec_wi,   dec_bi,   dec_bh,   dec_tabP, 128, G4, D, G4, 1.f, 1);
    tab_gemm64<<<dim3(2, 128), 256, 0, stream>>>(dec_emb_w, wq_w, wq_b, nullptr, q_tab, 128, D, D, D, scale, 0);
    tab_gemm64<<<dim3(2, 1024), 256, 0, stream>>>(enc_post_w, wk_w, nullptr, nullptr, WKVo, 1024, D, D, 1024, 1.f, 0);
    tab_gemm64<<<dim3(2, 1024), 256, 0, stream>>>(enc_post_w, wv_w, nullptr, nullptr, Wv_tmp, 1024, D, D, D, 1.f, 0);
    tab_gemm64<<<dim3(2, 1024), 256, 0, stream>>>(Wv_tmp, wo_w, nullptr, nullptr, WKVo + D, 1024, D, D, 1024, 1.f, 0);
    tab_gemm64<<<dim3(2, 1), 256, 0, stream>>>(enc_post_b, wk_w, wk_b, nullptr, bkvo, 1, D, D, D, 1.f, 0);
    tab_gemm64<<<dim3(2, 1), 256, 0, stream>>>(enc_post_b, wv_w, wv_b, nullptr, bv_tmp, 1, D, D, D, 1.f, 0);
    tab_gemm64<<<dim3(2, 1), 256, 0, stream>>>(bv_tmp, wo_w, wo_b, nullptr, bkvo + D, 1, D, D, D, 1.f, 0);
    permW<<<dim3(8, 512), 256, 0, stream>>>(enc_wh_f, WhPf, 0);
    permW<<<dim3(8, 512), 256, 0, stream>>>(enc_wh_b, WhPb, 0);
    permW<<<dim3(8, 512), 256, 0, stream>>>(dec_wi,  dec_wiP, 512);
    permW<<<dim3(8, 512), 256, 0, stream>>>(dec_wh,  dec_whP, 0);
    init_kv<<<2048, 256, 0, stream>>>(bkvo, Kh, Vf);

    // ---------- encoder: 64 fused steps, both directions per launch ----------
    for (int t = 0; t < TS; ++t) {
        gates_cell<0><<<dim3(32, 16, 2), 256, 0, stream>>>(
            hFbuf[t & 1], hBbuf[t & 1], nullptr, nullptr,
            WhPf, WhPb, nullptr, nullptr,
            tabPf, tabPb,
            src + t, src + (TS - 1 - t), TS,
            cF, cB, hFbuf[(t + 1) & 1], hBbuf[(t + 1) & 1],
            t ? D : 0, t ? 1 : 0);
        fold_kernel<<<dim3(16, 16, 2), 256, 0, stream>>>(
            hFbuf[(t + 1) & 1], hBbuf[(t + 1) & 1], WKVo, Kh, Vf, t, TS - 1 - t);
    }

    // ---------- decoder initial h, c ----------
    hc_init<<<NB, 512, 0, stream>>>(hFbuf[0], hBbuf[0], cF, cB,
                                    h_post_w, h_post_b, c_post_w, c_post_b, hd[0], cdec);
    init_amax<<<4, 256, 0, stream>>>(tgt, amax);

    // ---------- decoder: 64 steps ----------
    for (int st = 0; st < TT; ++st) {
        attn_kernel<<<NB, 512, 0, stream>>>(q_tab, amax, Kh, Vf, attn_out, st, ctxb);
        gates_cell<1><<<dim3(32, 16, 1), 256, 0, stream>>>(
            ctxb, ctxb, hd[st & 1], hd[st & 1],
            dec_wiP, dec_wiP, dec_whP, dec_whP,
            dec_tabP, dec_tabP,
            amax, amax, 1,
            cdec, cdec, hd[(st + 1) & 1], hd[(st + 1) & 1],
            2 * D, 1);
        out_argmax<<<NB, 128, 0, stream>>>(hd[(st + 1) & 1], dec_post_w, dec_post_b, res_out, st, amax);
    }
}

// Round 12
// 30722.635 us; speedup vs baseline: 3.2719x; 1.1740x over previous
//
#include <hip/hip_runtime.h>
#include <hip/hip_bf16.h>

namespace k77 {

typedef long long ll;

constexpr int D    = 512;
constexpr int DTGT = 128;
constexpr int NB   = 1024;
constexpr int TS   = 64;
constexpr int TT   = 64;
constexpr int G4   = 2048;

// ---------------- precompute GEMM (f64 accumulate, f32 store), optional gate-permute on store ----------------
// perm: store col j at j' = (j&511)*4 + (j>>9)   [d*4+gate layout]
__global__ void tab_gemm64(const float* __restrict__ A, const float* __restrict__ B,
                           const float* __restrict__ b1, const float* __restrict__ b2,
                           float* __restrict__ C, int M, int N, int K, int ldc, float scale, int perm)
{
    int j = blockIdx.x * 256 + threadIdx.x;
    int m = blockIdx.y;
    if (j >= N || m >= M) return;
    const float* ar = A + (size_t)m * K;
    double acc = 0.0;
    for (int k = 0; k < K; ++k) acc += (double)ar[k] * (double)B[(size_t)k * N + j];
    if (b1) acc += (double)b1[j];
    if (b2) acc += (double)b2[j];
    int j2 = perm ? ((j & 511) * 4 + (j >> 9)) : j;
    C[(size_t)m * ldc + j2] = (float)(acc * (double)scale);
}

// permute a raw [512][2048] weight block (rows rowoff..rowoff+511) into d*4+gate column layout
__global__ void permW(const float* __restrict__ in, float* __restrict__ out, int rowoff)
{
    int j = blockIdx.x * 256 + threadIdx.x;   // 0..2047
    int k = blockIdx.y;                        // 0..511
    out[(size_t)k * G4 + (j & 511) * 4 + (j >> 9)] = in[(size_t)(k + rowoff) * G4 + j];
}

// pre-fill K (bf16) and V' (f32) with their biases so both encoder directions accumulate
__global__ void init_kv(const float* __restrict__ bkvo, __hip_bfloat16* __restrict__ Kb,
                        float* __restrict__ Vb)
{
    for (ll i = (ll)blockIdx.x * 256 + threadIdx.x; i < (ll)NB * TS * D; i += (ll)gridDim.x * 256) {
        int d = (int)(i & (D - 1));
        Kb[i] = __float2bfloat16(bkvo[d]);
        Vb[i] = bkvo[D + d];
    }
}

// ---------------- fused gates GEMM + LSTM cell ----------------
// Tile 64x64, 256 thr, TM=TN=4. f32 LDS (lossless), f64 accum in regs, f32 cell (r10/r11 class).
// Per-output k-summation order identical to r11 (sequential k) => bit-identical results.
// USE2: 2-segment A/B (decoder: A=[ctx|h], B=[dec_wiP|dec_whP]).  blockIdx.z selects direction set.
template<int USE2>
__global__ __launch_bounds__(256)
void gates_cell(const float* __restrict__ a0_0, const float* __restrict__ a0_1,
                const float* __restrict__ a1_0, const float* __restrict__ a1_1,
                const float* __restrict__ B0_0, const float* __restrict__ B0_1,
                const float* __restrict__ B1_0, const float* __restrict__ B1_1,
                const float* __restrict__ tab_0, const float* __restrict__ tab_1,
                const int* __restrict__ idx_0, const int* __restrict__ idx_1, int idxStride,
                float* c_0, float* c_1, float* h_0, float* h_1,
                int K, int useC)
{
    const int zz = blockIdx.z;
    const float* a0  = zz ? a0_1 : a0_0;
    const float* a1  = zz ? a1_1 : a1_0;
    const float* B0  = zz ? B0_1 : B0_0;
    const float* B1  = zz ? B1_1 : B1_0;
    const float* tab = zz ? tab_1 : tab_0;
    const int*   idx = zz ? idx_1 : idx_0;
    float* cb = zz ? c_1 : c_0;
    float* hb = zz ? h_1 : h_0;

    __shared__ float As[32][66];   // ld 66: stage-write 2-way, read conflict-free
    __shared__ float Bs[32][66];
    const int tid  = threadIdx.x;
    const int row0 = blockIdx.y * 64, col0 = blockIdx.x * 64;
    const int ty = tid >> 4, tx = tid & 15;

    double acc[4][4];
#pragma unroll
    for (int i = 0; i < 4; ++i)
#pragma unroll
        for (int j = 0; j < 4; ++j) acc[i][j] = 0.0;

    for (int k0 = 0; k0 < K; k0 += 32) {
#pragma unroll
        for (int l = 0; l < 8; ++l) {
            int t = tid + l * 256;                 // 0..2047
            {   // A: 64 rows x 32 k
                int k = t & 31, m = t >> 5;
                int kk = k0 + k;
                float v;
                if (USE2 && kk >= D) v = a1[(size_t)(row0 + m) * D + (kk - D)];
                else                 v = a0[(size_t)(row0 + m) * D + kk];
                As[k][m] = v;
            }
            {   // B: 32 k x 64 cols
                int j = t & 63, kr = t >> 6;
                int kk = k0 + kr;
                float v;
                if (USE2 && kk >= D) v = B1[(size_t)(kk - D) * G4 + col0 + j];
                else                 v = B0[(size_t)kk * G4 + col0 + j];
                Bs[kr][j] = v;
            }
        }
        __syncthreads();
#pragma unroll
        for (int kk = 0; kk < 32; ++kk) {
            double a4[4], b4[4];
#pragma unroll
            for (int i = 0; i < 4; ++i) a4[i] = (double)As[kk][ty * 4 + i];
#pragma unroll
            for (int j = 0; j < 4; ++j) b4[j] = (double)Bs[kk][tx * 4 + j];
#pragma unroll
            for (int i = 0; i < 4; ++i)
#pragma unroll
                for (int j = 0; j < 4; ++j) acc[i][j] = fma(a4[i], b4[j], acc[i][j]);
        }
        __syncthreads();
    }

    // epilogue: add permuted table row, round to f32, run LSTM cell (4 rows x 1 gate-quadruple/thread)
    const int cc = col0 + tx * 4;
    const int d  = cc >> 2;
#pragma unroll
    for (int i = 0; i < 4; ++i) {
        int row = row0 + ty * 4 + i;
        const float* tr = tab + (size_t)idx[(size_t)row * idxStride] * G4;
        float gi = (float)(acc[i][0] + (double)tr[cc + 0]);
        float gf = (float)(acc[i][1] + (double)tr[cc + 1]);
        float gg = (float)(acc[i][2] + (double)tr[cc + 2]);
        float go = (float)(acc[i][3] + (double)tr[cc + 3]);
        float c  = useC ? cb[(size_t)row * D + d] : 0.f;
        float si = 1.f / (1.f + expf(-gi));
        float sf = 1.f / (1.f + expf(-gf));
        float so = 1.f / (1.f + expf(-go));
        c = sf * c + si * tanhf(gg);
        cb[(size_t)row * D + d] = c;
        hb[(size_t)row * D + d] = so * tanhf(c);
    }
}

// ---------------- K/V' fold: [K|V'] row trow += h @ WKVo[rowoff..] (f64 accum), both dirs ----------------
__global__ __launch_bounds__(256)
void fold_kernel(const float* __restrict__ h_0, const float* __restrict__ h_1,
                 const float* __restrict__ W,
                 __hip_bfloat16* __restrict__ Kb, float* __restrict__ Vb,
                 int trow0, int trow1)
{
    const int zz = blockIdx.z;
    const float* h = zz ? h_1 : h_0;
    const int rowoff = zz ? D : 0;
    const int trow   = zz ? trow1 : trow0;

    __shared__ float As[32][66];
    __shared__ float Bs[32][66];
    const int tid  = threadIdx.x;
    const int row0 = blockIdx.y * 64, col0 = blockIdx.x * 64;
    const int ty = tid >> 4, tx = tid & 15;

    double acc[4][4];
#pragma unroll
    for (int i = 0; i < 4; ++i)
#pragma unroll
        for (int j = 0; j < 4; ++j) acc[i][j] = 0.0;

    for (int k0 = 0; k0 < D; k0 += 32) {
#pragma unroll
        for (int l = 0; l < 8; ++l) {
            int t = tid + l * 256;
            {   int k = t & 31, m = t >> 5;
                As[k][m] = h[(size_t)(row0 + m) * D + k0 + k];
            }
            {   int j = t & 63, kr = t >> 6;
                Bs[kr][j] = W[(size_t)(rowoff + k0 + kr) * 1024 + col0 + j];
            }
        }
        __syncthreads();
#pragma unroll
        for (int kk = 0; kk < 32; ++kk) {
            double a4[4], b4[4];
#pragma unroll
            for (int i = 0; i < 4; ++i) a4[i] = (double)As[kk][ty * 4 + i];
#pragma unroll
            for (int j = 0; j < 4; ++j) b4[j] = (double)Bs[kk][tx * 4 + j];
#pragma unroll
            for (int i = 0; i < 4; ++i)
#pragma unroll
                for (int j = 0; j < 4; ++j) acc[i][j] = fma(a4[i], b4[j], acc[i][j]);
        }
        __syncthreads();
    }

#pragma unroll
    for (int i = 0; i < 4; ++i) {
        int row = row0 + ty * 4 + i;
#pragma unroll
        for (int j = 0; j < 4; ++j) {
            int col = col0 + tx * 4 + j;
            double v = acc[i][j];
            ll ix = ((ll)row * TS + trow) * D + (col & (D - 1));
            if (col < D) {
                double v2 = v + (double)__bfloat162float(Kb[ix]);
                Kb[ix] = __float2bfloat16((float)v2);
            } else {
                Vb[ix] = (float)((double)Vb[ix] + v);
            }
        }
    }
}

// ---------------- decoder init: h0 = tanh([hF|hB]@hpw + b), c0 likewise (f64 accum) ----------------
__global__ __launch_bounds__(512)
void hc_init(const float* __restrict__ hF, const float* __restrict__ hB,
             const float* __restrict__ cF, const float* __restrict__ cB,
             const float* __restrict__ hpw, const float* __restrict__ hpb,
             const float* __restrict__ cpw, const float* __restrict__ cpb,
             float* __restrict__ h0, float* __restrict__ c0)
{
    __shared__ float s0[D], s1[D], s2[D], s3[D];
    const int b = blockIdx.x, j = threadIdx.x;
    s0[j] = hF[(size_t)b * D + j]; s1[j] = hB[(size_t)b * D + j];
    s2[j] = cF[(size_t)b * D + j]; s3[j] = cB[(size_t)b * D + j];
    __syncthreads();
    double a = (double)hpb[j];
    for (int k = 0; k < D; ++k) a += (double)s0[k] * (double)hpw[(size_t)k * D + j];
    for (int k = 0; k < D; ++k) a += (double)s1[k] * (double)hpw[(size_t)(k + D) * D + j];
    h0[(size_t)b * D + j] = (float)tanh(a);
    a = (double)cpb[j];
    for (int k = 0; k < D; ++k) a += (double)s2[k] * (double)cpw[(size_t)k * D + j];
    for (int k = 0; k < D; ++k) a += (double)s3[k] * (double)cpw[(size_t)(k + D) * D + j];
    c0[(size_t)b * D + j] = (float)tanh(a);
}

// ---------------- attention: f64-accum scores + f32 softmax + f64-accum ctx (r10-verified) ----------------
__global__ void attn_kernel(const float* __restrict__ qtab, const int* __restrict__ amax,
                            const __hip_bfloat16* __restrict__ Kb, const float* __restrict__ Vb,
                            float* __restrict__ aout, int step, float* __restrict__ ctx)
{
    const int b = blockIdx.x, tid = threadIdx.x;   // 512 threads
    __shared__ float qs[D];
    __shared__ float ss[TS];
    qs[tid] = qtab[(size_t)amax[b] * D + tid];
    __syncthreads();
    const int t = tid >> 3, l8 = tid & 7;
    const __hip_bfloat16* krow = Kb + ((size_t)b * TS + t) * D;
    double acc = 0.0;
    for (int d = l8; d < D; d += 8) acc += (double)qs[d] * (double)__bfloat162float(krow[d]);
    acc += __shfl_xor(acc, 4);
    acc += __shfl_xor(acc, 2);
    acc += __shfl_xor(acc, 1);
    if (l8 == 0) ss[t] = (float)acc;
    __syncthreads();
    if (tid < TS) {
        float v = ss[tid];
        float mx = v;
#pragma unroll
        for (int o = 32; o; o >>= 1) mx = fmaxf(mx, __shfl_xor(mx, o));
        float e = expf(v - mx);
        float sm = e;
#pragma unroll
        for (int o = 32; o; o >>= 1) sm += __shfl_xor(sm, o);
        float sc = e / sm;
        ss[tid] = sc;
        aout[((size_t)b * TT + step) * TS + tid] = sc;
    }
    __syncthreads();
    double a = 0.0;
    const float* vcol = Vb + (size_t)b * TS * D + tid;
    for (int t2 = 0; t2 < TS; ++t2) a += (double)ss[t2] * (double)vcol[(size_t)t2 * D];
    ctx[(size_t)b * D + tid] = (float)a;
}

// ---------------- out projection + argmax: f64 accumulate + f64 compare (r10-verified) ----------------
__global__ void out_argmax(const float* __restrict__ h, const float* __restrict__ W,
                           const float* __restrict__ bias, float* __restrict__ res,
                           int step, int* __restrict__ amax)
{
    const int b = blockIdx.x, tid = threadIdx.x;   // 128 threads
    __shared__ float hs[D];
    __shared__ double vals[DTGT];
    for (int k = tid; k < D; k += 128) hs[k] = h[(size_t)b * D + k];
    __syncthreads();
    double acc = (double)bias[tid];
    for (int k = 0; k < D; ++k) acc += (double)hs[k] * (double)W[(size_t)k * DTGT + tid];
    vals[tid] = acc;
    res[((size_t)b * TT + step) * DTGT + tid] = (float)acc;
    __syncthreads();
    if (tid == 0) {
        double best = vals[0]; int bi = 0;
        for (int j = 1; j < DTGT; ++j) if (vals[j] > best) { best = vals[j]; bi = j; }
        amax[b] = bi;
    }
}

__global__ void init_amax(const int* __restrict__ tgt, int* __restrict__ amax)
{
    int b = blockIdx.x * 256 + threadIdx.x;
    if (b < NB) amax[b] = tgt[(size_t)b * TT];
}

} // namespace k77

extern "C" void kernel_launch(void* const* d_in, const int* in_sizes, int n_in,
                              void* d_out, int out_size, void* d_ws, size_t ws_size,
                              hipStream_t stream)
{
    using namespace k77;
    (void)in_sizes; (void)n_in; (void)out_size;

    const int*   src        = (const int*)  d_in[0];
    const int*   tgt        = (const int*)  d_in[1];
    const float* enc_emb_w  = (const float*)d_in[2];
    const float* enc_wi_f   = (const float*)d_in[3];
    const float* enc_wh_f   = (const float*)d_in[4];
    const float* enc_bi_f   = (const float*)d_in[5];
    const float* enc_bh_f   = (const float*)d_in[6];
    const float* enc_wi_b   = (const float*)d_in[7];
    const float* enc_wh_b   = (const float*)d_in[8];
    const float* enc_bi_b   = (const float*)d_in[9];
    const float* enc_bh_b   = (const float*)d_in[10];
    const float* enc_post_w = (const float*)d_in[11];
    const float* enc_post_b = (const float*)d_in[12];
    const float* h_post_w   = (const float*)d_in[13];
    const float* h_post_b   = (const float*)d_in[14];
    const float* c_post_w   = (const float*)d_in[15];
    const float* c_post_b   = (const float*)d_in[16];
    const float* wq_w       = (const float*)d_in[17];
    const float* wq_b       = (const float*)d_in[18];
    const float* wk_w       = (const float*)d_in[19];
    const float* wk_b       = (const float*)d_in[20];
    const float* wv_w       = (const float*)d_in[21];
    const float* wv_b       = (const float*)d_in[22];
    const float* wo_w       = (const float*)d_in[23];
    const float* wo_b       = (const float*)d_in[24];
    const float* dec_emb_w  = (const float*)d_in[25];
    const float* dec_wi     = (const float*)d_in[26];
    const float* dec_wh     = (const float*)d_in[27];
    const float* dec_bi     = (const float*)d_in[28];
    const float* dec_bh     = (const float*)d_in[29];
    const float* dec_post_w = (const float*)d_in[30];
    const float* dec_post_b = (const float*)d_in[31];

    float* ws = (float*)d_ws;
    size_t off = 0;
    auto alloc = [&](size_t n) { float* p = ws + off; off += n; return p; };
    float* hF0     = alloc((size_t)NB * D);
    float* hF1     = alloc((size_t)NB * D);
    float* hB0     = alloc((size_t)NB * D);
    float* hB1     = alloc((size_t)NB * D);
    float* cF      = alloc((size_t)NB * D);
    float* cB      = alloc((size_t)NB * D);
    float* hd0     = alloc((size_t)NB * D);
    float* hd1     = alloc((size_t)NB * D);
    float* cdec    = alloc((size_t)NB * D);
    float* ctxb    = alloc((size_t)NB * D);
    float* tabPf   = alloc((size_t)128 * G4);
    float* tabPb   = alloc((size_t)128 * G4);
    float* dec_tabP= alloc((size_t)128 * G4);
    float* q_tab   = alloc((size_t)128 * D);
    float* WKVo    = alloc((size_t)1024 * 1024);
    float* bkvo    = alloc(1024);
    float* WhPf    = alloc((size_t)D * G4);
    float* WhPb    = alloc((size_t)D * G4);
    float* dec_wiP = alloc((size_t)D * G4);
    float* dec_whP = alloc((size_t)D * G4);
    float* Wv_tmp  = alloc((size_t)1024 * D);
    float* bv_tmp  = alloc(D);
    int*   amax    = (int*)alloc(1024);

    const size_t commonF = off;
    const size_t kvCnt   = (size_t)NB * TS * D;
    const size_t need    = commonF * 4 + kvCnt * 2 + kvCnt * 4;   // ~249 MB

    if (ws_size < need) {
        hipMemsetAsync(d_out, 0x7F, 1024, stream);   // sentinel: ws too small
        return;
    }
    __hip_bfloat16* Kh = (__hip_bfloat16*)(ws + commonF);
    float*          Vf = (float*)((char*)Kh + kvCnt * 2);

    float* attn_out = (float*)d_out;
    float* res_out  = attn_out + (size_t)NB * TT * TS;

    const float scale = 0.044194173824159216f;   // 512^-0.5

    float* hFbuf[2] = {hF0, hF1};
    float* hBbuf[2] = {hB0, hB1};
    float* hd[2]    = {hd0, hd1};

    // ---------- precompute ----------
    tab_gemm64<<<dim3(8, 128), 256, 0, stream>>>(enc_emb_w, enc_wi_f, enc_bi_f, enc_bh_f, tabPf, 128, G4, D, G4, 1.f, 1);
    tab_gemm64<<<dim3(8, 128), 256, 0, stream>>>(enc_emb_w, enc_wi_b, enc_bi_b, enc_bh_b, tabPb, 128, G4, D, G4, 1.f, 1);
    tab_gemm64<<<dim3(8, 128), 256, 0, stream>>>(dec_emb_w, dec_wi,   dec_bi,   dec_bh,   dec_tabP, 128, G4, D, G4, 1.f, 1);
    tab_gemm64<<<dim3(2, 128), 256, 0, stream>>>(dec_emb_w, wq_w, wq_b, nullptr, q_tab, 128, D, D, D, scale, 0);
    tab_gemm64<<<dim3(2, 1024), 256, 0, stream>>>(enc_post_w, wk_w, nullptr, nullptr, WKVo, 1024, D, D, 1024, 1.f, 0);
    tab_gemm64<<<dim3(2, 1024), 256, 0, stream>>>(enc_post_w, wv_w, nullptr, nullptr, Wv_tmp, 1024, D, D, D, 1.f, 0);
    tab_gemm64<<<dim3(2, 1024), 256, 0, stream>>>(Wv_tmp, wo_w, nullptr, nullptr, WKVo + D, 1024, D, D, 1024, 1.f, 0);
    tab_gemm64<<<dim3(2, 1), 256, 0, stream>>>(enc_post_b, wk_w, wk_b, nullptr, bkvo, 1, D, D, D, 1.f, 0);
    tab_gemm64<<<dim3(2, 1), 256, 0, stream>>>(enc_post_b, wv_w, wv_b, nullptr, bv_tmp, 1, D, D, D, 1.f, 0);
    tab_gemm64<<<dim3(2, 1), 256, 0, stream>>>(bv_tmp, wo_w, wo_b, nullptr, bkvo + D, 1, D, D, D, 1.f, 0);
    permW<<<dim3(8, 512), 256, 0, stream>>>(enc_wh_f, WhPf, 0);
    permW<<<dim3(8, 512), 256, 0, stream>>>(enc_wh_b, WhPb, 0);
    permW<<<dim3(8, 512), 256, 0, stream>>>(dec_wi,  dec_wiP, 512);
    permW<<<dim3(8, 512), 256, 0, stream>>>(dec_wh,  dec_whP, 0);
    init_kv<<<2048, 256, 0, stream>>>(bkvo, Kh, Vf);

    // ---------- encoder: 64 fused steps, both directions per launch ----------
    for (int t = 0; t < TS; ++t) {
        gates_cell<0><<<dim3(32, 16, 2), 256, 0, stream>>>(
            hFbuf[t & 1], hBbuf[t & 1], nullptr, nullptr,
            WhPf, WhPb, nullptr, nullptr,
            tabPf, tabPb,
            src + t, src + (TS - 1 - t), TS,
            cF, cB, hFbuf[(t + 1) & 1], hBbuf[(t + 1) & 1],
            t ? D : 0, t ? 1 : 0);
        fold_kernel<<<dim3(16, 16, 2), 256, 0, stream>>>(
            hFbuf[(t + 1) & 1], hBbuf[(t + 1) & 1], WKVo, Kh, Vf, t, TS - 1 - t);
    }

    // ---------- decoder initial h, c ----------
    hc_init<<<NB, 512, 0, stream>>>(hFbuf[0], hBbuf[0], cF, cB,
                                    h_post_w, h_post_b, c_post_w, c_post_b, hd[0], cdec);
    init_amax<<<4, 256, 0, stream>>>(tgt, amax);

    // ---------- decoder: 64 steps ----------
    for (int st = 0; st < TT; ++st) {
        attn_kernel<<<NB, 512, 0, stream>>>(q_tab, amax, Kh, Vf, attn_out, st, ctxb);
        gates_cell<1><<<dim3(32, 16, 1), 256, 0, stream>>>(
            ctxb, ctxb, hd[st & 1], hd[st & 1],
            dec_wiP, dec_wiP, dec_whP, dec_whP,
            dec_tabP, dec_tabP,
            amax, amax, 1,
            cdec, cdec, hd[(st + 1) & 1], hd[(st + 1) & 1],
            2 * D, 1);
        out_argmax<<<NB, 128, 0, stream>>>(hd[(st + 1) & 1], dec_post_w, dec_post_b, res_out, st, amax);
    }
}

// Round 14
// 29762.943 us; speedup vs baseline: 3.3774x; 1.0322x over previous
//
#include <hip/hip_runtime.h>
#include <hip/hip_bf16.h>

namespace k77 {

typedef long long ll;
typedef double f64x4 __attribute__((ext_vector_type(4)));

constexpr int D    = 512;
constexpr int DTGT = 128;
constexpr int NB   = 1024;
constexpr int TS   = 64;
constexpr int TT   = 64;
constexpr int G4   = 2048;

// ---------------- runtime MFMA-f64 C/D-layout probe ----------------
// Exact-integer 16x16x4 MFMA vs in-kernel reference under 4 candidate lane->(row,col)
// mappings. Asymmetric A,B (transpose-detecting). Publishes dlay in [0,3], or -1.
__global__ void probe_mfma(int* __restrict__ dlay)
{
    __shared__ double ref[256];
    __shared__ int ok[4];
    const int l = threadIdx.x;           // 64 threads
    const int l15 = l & 15, l4 = l >> 4;
    if (l < 4) ok[l] = 1;
    double a = 1.0 + 3.0 * l15 + 7.0 * l4;    // A[row=l15][k=l4] = 1+3r+7k
    double b = 2.0 + 5.0 * l15 + 11.0 * l4;   // B[k=l4][col=l15] = 2+5c+11k
    f64x4 d = {0.0, 0.0, 0.0, 0.0};
    d = __builtin_amdgcn_mfma_f64_16x16x4f64(a, b, d, 0, 0, 0);
    if (l < 16) {
        for (int j = 0; j < 16; ++j) {
            double s = 0.0;
            for (int k = 0; k < 4; ++k)
                s += (1.0 + 3.0 * l + 7.0 * k) * (2.0 + 5.0 * j + 11.0 * k);
            ref[l * 16 + j] = s;         // ref[row][col], exact ints
        }
    }
    __syncthreads();
#pragma unroll
    for (int n = 0; n < 4; ++n) {
        if (d[n] != ref[(l4 * 4 + n) * 16 + l15]) atomicAnd(&ok[0], 0);  // contiguous rows
        if (d[n] != ref[(l4 + 4 * n) * 16 + l15]) atomicAnd(&ok[1], 0);  // stride-4 rows
        if (d[n] != ref[l15 * 16 + (l4 * 4 + n)]) atomicAnd(&ok[2], 0);  // transposed contiguous
        if (d[n] != ref[l15 * 16 + (l4 + 4 * n)]) atomicAnd(&ok[3], 0);  // transposed stride-4
    }
    __syncthreads();
    if (l == 0) {
        int r = -1;
        for (int i = 3; i >= 0; --i) if (ok[i]) r = i;
        *dlay = r;
    }
}

__global__ void dlay_check(const int* __restrict__ dlay, float* __restrict__ out0)
{
    if (*dlay < 0)
        for (int i = threadIdx.x; i < 256; i += 64) out0[i] = 3.0e38f;   // sentinel
}

__device__ inline void dmap(int dl, int l15, int l4, int n, int& r, int& c)
{
    if (dl == 1)      { r = l4 + 4 * n;  c = l15; }
    else if (dl == 2) { r = l15;         c = l4 * 4 + n; }
    else if (dl == 3) { r = l15;         c = l4 + 4 * n; }
    else              { r = l4 * 4 + n;  c = l15; }
}

// ---------------- precompute GEMM (f64 accumulate, f32 store), optional gate-permute on store ----------------
__global__ void tab_gemm64(const float* __restrict__ A, const float* __restrict__ B,
                           const float* __restrict__ b1, const float* __restrict__ b2,
                           float* __restrict__ C, int M, int N, int K, int ldc, float scale, int perm)
{
    int j = blockIdx.x * 256 + threadIdx.x;
    int m = blockIdx.y;
    if (j >= N || m >= M) return;
    const float* ar = A + (size_t)m * K;
    double acc = 0.0;
    for (int k = 0; k < K; ++k) acc += (double)ar[k] * (double)B[(size_t)k * N + j];
    if (b1) acc += (double)b1[j];
    if (b2) acc += (double)b2[j];
    int j2 = perm ? ((j & 511) * 4 + (j >> 9)) : j;
    C[(size_t)m * ldc + j2] = (float)(acc * (double)scale);
}

// permute a raw [512][2048] weight block (rows rowoff..rowoff+511) into d*4+gate column layout
__global__ void permW(const float* __restrict__ in, float* __restrict__ out, int rowoff)
{
    int j = blockIdx.x * 256 + threadIdx.x;   // 0..2047
    int k = blockIdx.y;                        // 0..511
    out[(size_t)k * G4 + (j & 511) * 4 + (j >> 9)] = in[(size_t)(k + rowoff) * G4 + j];
}

// pre-fill K (bf16) and V' (f32) with their biases so both encoder directions accumulate
__global__ void init_kv(const float* __restrict__ bkvo, __hip_bfloat16* __restrict__ Kb,
                        float* __restrict__ Vb)
{
    for (ll i = (ll)blockIdx.x * 256 + threadIdx.x; i < (ll)NB * TS * D; i += (ll)gridDim.x * 256) {
        int d = (int)(i & (D - 1));
        Kb[i] = __float2bfloat16(bkvo[d]);
        Vb[i] = bkvo[D + d];
    }
}

// ---------------- fused gates GEMM (MFMA f64) + LSTM cell ----------------
// Tile 64x64, 256 thr = 4 waves (2x2 of 32x32), each wave 2x2 mfma_f64_16x16x4 fragments.
// f32 LDS staging (lossless), f64 matrix-pipe accumulation, f32 cell (r10 precision class).
// C/D scatter mapping measured at runtime by probe_mfma (dlayp).
template<int USE2>
__global__ __launch_bounds__(256)
void gates_cell(const float* __restrict__ a0_0, const float* __restrict__ a0_1,
                const float* __restrict__ a1_0, const float* __restrict__ a1_1,
                const float* __restrict__ B0_0, const float* __restrict__ B0_1,
                const float* __restrict__ B1_0, const float* __restrict__ B1_1,
                const float* __restrict__ tab_0, const float* __restrict__ tab_1,
                const int* __restrict__ idx_0, const int* __restrict__ idx_1, int idxStride,
                float* c_0, float* c_1, float* h_0, float* h_1,
                int K, int useC, const int* __restrict__ dlayp)
{
    const int zz = blockIdx.z;
    const float* a0  = zz ? a0_1 : a0_0;
    const float* a1  = zz ? a1_1 : a1_0;
    const float* B0  = zz ? B0_1 : B0_0;
    const float* B1  = zz ? B1_1 : B1_0;
    const float* tab = zz ? tab_1 : tab_0;
    const int*   idx = zz ? idx_1 : idx_0;
    float* cb = zz ? c_1 : c_0;
    float* hb = zz ? h_1 : h_0;

    __shared__ double smem[64 * 66];            // aliased: staging (f32 As/Bs) then gates (f64)
    float* As = (float*)smem;                   // [32][66]
    float* Bs = As + 32 * 66;                   // [32][66]

    const int tid  = threadIdx.x;
    const int row0 = blockIdx.y * 64, col0 = blockIdx.x * 64;
    const int wave = tid >> 6, lane = tid & 63;
    const int wr = wave >> 1, wc = wave & 1;    // 2x2 waves of 32x32
    const int l15 = lane & 15, l4 = lane >> 4;

    f64x4 acc[2][2];
#pragma unroll
    for (int i = 0; i < 2; ++i)
#pragma unroll
        for (int j = 0; j < 2; ++j) acc[i][j] = (f64x4){0.0, 0.0, 0.0, 0.0};

    for (int k0 = 0; k0 < K; k0 += 32) {
#pragma unroll
        for (int l = 0; l < 8; ++l) {
            int t = tid + l * 256;                 // 0..2047
            {   // A: 64 rows x 32 k   As[k][m]
                int k = t & 31, m = t >> 5;
                int kk = k0 + k;
                float v;
                if (USE2 && kk >= D) v = a1[(size_t)(row0 + m) * D + (kk - D)];
                else                 v = a0[(size_t)(row0 + m) * D + kk];
                As[k * 66 + m] = v;
            }
            {   // B: 32 k x 64 cols   Bs[k][j]
                int j = t & 63, kr = t >> 6;
                int kk = k0 + kr;
                float v;
                if (USE2 && kk >= D) v = B1[(size_t)(kk - D) * G4 + col0 + j];
                else                 v = B0[(size_t)kk * G4 + col0 + j];
                Bs[kr * 66 + j] = v;
            }
        }
        __syncthreads();
#pragma unroll
        for (int kk4 = 0; kk4 < 8; ++kk4) {
            const int kr = kk4 * 4 + l4;
            double a0f = (double)As[kr * 66 + wr * 32 + l15];
            double a1f = (double)As[kr * 66 + wr * 32 + 16 + l15];
            double b0f = (double)Bs[kr * 66 + wc * 32 + l15];
            double b1f = (double)Bs[kr * 66 + wc * 32 + 16 + l15];
            acc[0][0] = __builtin_amdgcn_mfma_f64_16x16x4f64(a0f, b0f, acc[0][0], 0, 0, 0);
            acc[0][1] = __builtin_amdgcn_mfma_f64_16x16x4f64(a0f, b1f, acc[0][1], 0, 0, 0);
            acc[1][0] = __builtin_amdgcn_mfma_f64_16x16x4f64(a1f, b0f, acc[1][0], 0, 0, 0);
            acc[1][1] = __builtin_amdgcn_mfma_f64_16x16x4f64(a1f, b1f, acc[1][1], 0, 0, 0);
        }
        __syncthreads();
    }

    // bounce acc -> LDS f64 via the MEASURED mapping so geometry is correct
    const int dl = dlayp[0];
    double* G = smem;                            // [64][66]
#pragma unroll
    for (int tr = 0; tr < 2; ++tr)
#pragma unroll
        for (int tc = 0; tc < 2; ++tc)
#pragma unroll
            for (int n = 0; n < 4; ++n) {
                int r, c;
                dmap(dl, l15, l4, n, r, c);
                G[(wr * 32 + tr * 16 + r) * 66 + (wc * 32 + tc * 16 + c)] = acc[tr][tc][n];
            }
    __syncthreads();

    // epilogue: add permuted table row (f64), round to f32, run LSTM cell
    const int ty = tid >> 4, tx = tid & 15;
    const int cc = col0 + tx * 4;
    const int d  = cc >> 2;
#pragma unroll
    for (int i = 0; i < 4; ++i) {
        int rl  = ty * 4 + i;
        int row = row0 + rl;
        const float* tr = tab + (size_t)idx[(size_t)row * idxStride] * G4;
        float gi = (float)(G[rl * 66 + tx * 4 + 0] + (double)tr[cc + 0]);
        float gf = (float)(G[rl * 66 + tx * 4 + 1] + (double)tr[cc + 1]);
        float gg = (float)(G[rl * 66 + tx * 4 + 2] + (double)tr[cc + 2]);
        float go = (float)(G[rl * 66 + tx * 4 + 3] + (double)tr[cc + 3]);
        float c  = useC ? cb[(size_t)row * D + d] : 0.f;
        float si = 1.f / (1.f + expf(-gi));
        float sf = 1.f / (1.f + expf(-gf));
        float so = 1.f / (1.f + expf(-go));
        c = sf * c + si * tanhf(gg);
        cb[(size_t)row * D + d] = c;
        hb[(size_t)row * D + d] = so * tanhf(c);
    }
}

// ---------------- K/V' fold (MFMA f64): [K|V'] row trow += h @ WKVo[rowoff..], both dirs ----------------
__global__ __launch_bounds__(256)
void fold_kernel(const float* __restrict__ h_0, const float* __restrict__ h_1,
                 const float* __restrict__ W,
                 __hip_bfloat16* __restrict__ Kb, float* __restrict__ Vb,
                 int trow0, int trow1, const int* __restrict__ dlayp)
{
    const int zz = blockIdx.z;
    const float* h = zz ? h_1 : h_0;
    const int rowoff = zz ? D : 0;
    const int trow   = zz ? trow1 : trow0;

    __shared__ float As[32 * 66];
    __shared__ float Bs[32 * 66];
    const int tid  = threadIdx.x;
    const int row0 = blockIdx.y * 64, col0 = blockIdx.x * 64;
    const int wave = tid >> 6, lane = tid & 63;
    const int wr = wave >> 1, wc = wave & 1;
    const int l15 = lane & 15, l4 = lane >> 4;

    f64x4 acc[2][2];
#pragma unroll
    for (int i = 0; i < 2; ++i)
#pragma unroll
        for (int j = 0; j < 2; ++j) acc[i][j] = (f64x4){0.0, 0.0, 0.0, 0.0};

    for (int k0 = 0; k0 < D; k0 += 32) {
#pragma unroll
        for (int l = 0; l < 8; ++l) {
            int t = tid + l * 256;
            {   int k = t & 31, m = t >> 5;
                As[k * 66 + m] = h[(size_t)(row0 + m) * D + k0 + k];
            }
            {   int j = t & 63, kr = t >> 6;
                Bs[kr * 66 + j] = W[(size_t)(rowoff + k0 + kr) * 1024 + col0 + j];
            }
        }
        __syncthreads();
#pragma unroll
        for (int kk4 = 0; kk4 < 8; ++kk4) {
            const int kr = kk4 * 4 + l4;
            double a0f = (double)As[kr * 66 + wr * 32 + l15];
            double a1f = (double)As[kr * 66 + wr * 32 + 16 + l15];
            double b0f = (double)Bs[kr * 66 + wc * 32 + l15];
            double b1f = (double)Bs[kr * 66 + wc * 32 + 16 + l15];
            acc[0][0] = __builtin_amdgcn_mfma_f64_16x16x4f64(a0f, b0f, acc[0][0], 0, 0, 0);
            acc[0][1] = __builtin_amdgcn_mfma_f64_16x16x4f64(a0f, b1f, acc[0][1], 0, 0, 0);
            acc[1][0] = __builtin_amdgcn_mfma_f64_16x16x4f64(a1f, b0f, acc[1][0], 0, 0, 0);
            acc[1][1] = __builtin_amdgcn_mfma_f64_16x16x4f64(a1f, b1f, acc[1][1], 0, 0, 0);
        }
        __syncthreads();
    }

    // direct scattered writes via the measured mapping
    const int dl = dlayp[0];
#pragma unroll
    for (int tr = 0; tr < 2; ++tr)
#pragma unroll
        for (int tc = 0; tc < 2; ++tc)
#pragma unroll
            for (int n = 0; n < 4; ++n) {
                int r, c;
                dmap(dl, l15, l4, n, r, c);
                int row = row0 + wr * 32 + tr * 16 + r;
                int col = col0 + wc * 32 + tc * 16 + c;
                double v = acc[tr][tc][n];
                ll ix = ((ll)row * TS + trow) * D + (col & (D - 1));
                if (col < D) {
                    double v2 = v + (double)__bfloat162float(Kb[ix]);
                    Kb[ix] = __float2bfloat16((float)v2);
                } else {
                    Vb[ix] = (float)((double)Vb[ix] + v);
                }
            }
}

// ---------------- decoder init: h0 = tanh([hF|hB]@hpw + b), c0 likewise (f64 accum) ----------------
__global__ __launch_bounds__(512)
void hc_init(const float* __restrict__ hF, const float* __restrict__ hB,
             const float* __restrict__ cF, const float* __restrict__ cB,
             const float* __restrict__ hpw, const float* __restrict__ hpb,
             const float* __restrict__ cpw, const float* __restrict__ cpb,
             float* __restrict__ h0, float* __restrict__ c0)
{
    __shared__ float s0[D], s1[D], s2[D], s3[D];
    const int b = blockIdx.x, j = threadIdx.x;
    s0[j] = hF[(size_t)b * D + j]; s1[j] = hB[(size_t)b * D + j];
    s2[j] = cF[(size_t)b * D + j]; s3[j] = cB[(size_t)b * D + j];
    __syncthreads();
    double a = (double)hpb[j];
    for (int k = 0; k < D; ++k) a += (double)s0[k] * (double)hpw[(size_t)k * D + j];
    for (int k = 0; k < D; ++k) a += (double)s1[k] * (double)hpw[(size_t)(k + D) * D + j];
    h0[(size_t)b * D + j] = (float)tanh(a);
    a = (double)cpb[j];
    for (int k = 0; k < D; ++k) a += (double)s2[k] * (double)cpw[(size_t)k * D + j];
    for (int k = 0; k < D; ++k) a += (double)s3[k] * (double)cpw[(size_t)(k + D) * D + j];
    c0[(size_t)b * D + j] = (float)tanh(a);
}

// ---------------- attention: f64-accum scores + f32 softmax + f64-accum ctx (r10-verified) ----------------
__global__ void attn_kernel(const float* __restrict__ qtab, const int* __restrict__ amax,
                            const __hip_bfloat16* __restrict__ Kb, const float* __restrict__ Vb,
                            float* __restrict__ aout, int step, float* __restrict__ ctx)
{
    const int b = blockIdx.x, tid = threadIdx.x;   // 512 threads
    __shared__ float qs[D];
    __shared__ float ss[TS];
    qs[tid] = qtab[(size_t)amax[b] * D + tid];
    __syncthreads();
    const int t = tid >> 3, l8 = tid & 7;
    const __hip_bfloat16* krow = Kb + ((size_t)b * TS + t) * D;
    double acc = 0.0;
    for (int d = l8; d < D; d += 8) acc += (double)qs[d] * (double)__bfloat162float(krow[d]);
    acc += __shfl_xor(acc, 4);
    acc += __shfl_xor(acc, 2);
    acc += __shfl_xor(acc, 1);
    if (l8 == 0) ss[t] = (float)acc;
    __syncthreads();
    if (tid < TS) {
        float v = ss[tid];
        float mx = v;
#pragma unroll
        for (int o = 32; o; o >>= 1) mx = fmaxf(mx, __shfl_xor(mx, o));
        float e = expf(v - mx);
        float sm = e;
#pragma unroll
        for (int o = 32; o; o >>= 1) sm += __shfl_xor(sm, o);
        float sc = e / sm;
        ss[tid] = sc;
        aout[((size_t)b * TT + step) * TS + tid] = sc;
    }
    __syncthreads();
    double a = 0.0;
    const float* vcol = Vb + (size_t)b * TS * D + tid;
    for (int t2 = 0; t2 < TS; ++t2) a += (double)ss[t2] * (double)vcol[(size_t)t2 * D];
    ctx[(size_t)b * D + tid] = (float)a;
}

// ---------------- out projection + argmax: f64 accumulate + f64 compare (r10-verified) ----------------
__global__ void out_argmax(const float* __restrict__ h, const float* __restrict__ W,
                           const float* __restrict__ bias, float* __restrict__ res,
                           int step, int* __restrict__ amax)
{
    const int b = blockIdx.x, tid = threadIdx.x;   // 128 threads
    __shared__ float hs[D];
    __shared__ double vals[DTGT];
    for (int k = tid; k < D; k += 128) hs[k] = h[(size_t)b * D + k];
    __syncthreads();
    double acc = (double)bias[tid];
    for (int k = 0; k < D; ++k) acc += (double)hs[k] * (double)W[(size_t)k * DTGT + tid];
    vals[tid] = acc;
    res[((size_t)b * TT + step) * DTGT + tid] = (float)acc;
    __syncthreads();
    if (tid == 0) {
        double best = vals[0]; int bi = 0;
        for (int j = 1; j < DTGT; ++j) if (vals[j] > best) { best = vals[j]; bi = j; }
        amax[b] = bi;
    }
}

__global__ void init_amax(const int* __restrict__ tgt, int* __restrict__ amax)
{
    int b = blockIdx.x * 256 + threadIdx.x;
    if (b < NB) amax[b] = tgt[(size_t)b * TT];
}

} // namespace k77

extern "C" void kernel_launch(void* const* d_in, const int* in_sizes, int n_in,
                              void* d_out, int out_size, void* d_ws, size_t ws_size,
                              hipStream_t stream)
{
    using namespace k77;
    (void)in_sizes; (void)n_in; (void)out_size;

    const int*   src        = (const int*)  d_in[0];
    const int*   tgt        = (const int*)  d_in[1];
    const float* enc_emb_w  = (const float*)d_in[2];
    const float* enc_wi_f   = (const float*)d_in[3];
    const float* enc_wh_f   = (const float*)d_in[4];
    const float* enc_bi_f   = (const float*)d_in[5];
    const float* enc_bh_f   = (const float*)d_in[6];
    const float* enc_wi_b   = (const float*)d_in[7];
    const float* enc_wh_b   = (const float*)d_in[8];
    const float* enc_bi_b   = (const float*)d_in[9];
    const float* enc_bh_b   = (const float*)d_in[10];
    const float* enc_post_w = (const float*)d_in[11];
    const float* enc_post_b = (const float*)d_in[12];
    const float* h_post_w   = (const float*)d_in[13];
    const float* h_post_b   = (const float*)d_in[14];
    const float* c_post_w   = (const float*)d_in[15];
    const float* c_post_b   = (const float*)d_in[16];
    const float* wq_w       = (const float*)d_in[17];
    const float* wq_b       = (const float*)d_in[18];
    const float* wk_w       = (const float*)d_in[19];
    const float* wk_b       = (const float*)d_in[20];
    const float* wv_w       = (const float*)d_in[21];
    const float* wv_b       = (const float*)d_in[22];
    const float* wo_w       = (const float*)d_in[23];
    const float* wo_b       = (const float*)d_in[24];
    const float* dec_emb_w  = (const float*)d_in[25];
    const float* dec_wi     = (const float*)d_in[26];
    const float* dec_wh     = (const float*)d_in[27];
    const float* dec_bi     = (const float*)d_in[28];
    const float* dec_bh     = (const float*)d_in[29];
    const float* dec_post_w = (const float*)d_in[30];
    const float* dec_post_b = (const float*)d_in[31];

    float* ws = (float*)d_ws;
    size_t off = 0;
    auto alloc = [&](size_t n) { float* p = ws + off; off += n; return p; };
    float* hF0     = alloc((size_t)NB * D);
    float* hF1     = alloc((size_t)NB * D);
    float* hB0     = alloc((size_t)NB * D);
    float* hB1     = alloc((size_t)NB * D);
    float* cF      = alloc((size_t)NB * D);
    float* cB      = alloc((size_t)NB * D);
    float* hd0     = alloc((size_t)NB * D);
    float* hd1     = alloc((size_t)NB * D);
    float* cdec    = alloc((size_t)NB * D);
    float* ctxb    = alloc((size_t)NB * D);
    float* tabPf   = alloc((size_t)128 * G4);
    float* tabPb   = alloc((size_t)128 * G4);
    float* dec_tabP= alloc((size_t)128 * G4);
    float* q_tab   = alloc((size_t)128 * D);
    float* WKVo    = alloc((size_t)1024 * 1024);
    float* bkvo    = alloc(1024);
    float* WhPf    = alloc((size_t)D * G4);
    float* WhPb    = alloc((size_t)D * G4);
    float* dec_wiP = alloc((size_t)D * G4);
    float* dec_whP = alloc((size_t)D * G4);
    float* Wv_tmp  = alloc((size_t)1024 * D);
    float* bv_tmp  = alloc(D);
    int*   amax    = (int*)alloc(1024);
    int*   dlayD   = (int*)alloc(64);

    const size_t commonF = off;
    const size_t kvCnt   = (size_t)NB * TS * D;
    const size_t need    = commonF * 4 + kvCnt * 2 + kvCnt * 4;   // ~249 MB

    if (ws_size < need) {
        hipMemsetAsync(d_out, 0x7F, 1024, stream);   // sentinel: ws too small
        return;
    }
    __hip_bfloat16* Kh = (__hip_bfloat16*)(ws + commonF);
    float*          Vf = (float*)((char*)Kh + kvCnt * 2);

    float* attn_out = (float*)d_out;
    float* res_out  = attn_out + (size_t)NB * TT * TS;

    const float scale = 0.044194173824159216f;   // 512^-0.5

    float* hFbuf[2] = {hF0, hF1};
    float* hBbuf[2] = {hB0, hB1};
    float* hd[2]    = {hd0, hd1};

    // ---------- MFMA layout probe ----------
    probe_mfma<<<1, 64, 0, stream>>>(dlayD);
    dlay_check<<<1, 64, 0, stream>>>(dlayD, attn_out);

    // ---------- precompute ----------
    tab_gemm64<<<dim3(8, 128), 256, 0, stream>>>(enc_emb_w, enc_wi_f, enc_bi_f, enc_bh_f, tabPf, 128, G4, D, G4, 1.f, 1);
    tab_gemm64<<<dim3(8, 128), 256, 0, stream>>>(enc_emb_w, enc_wi_b, enc_bi_b, enc_bh_b, tabPb, 128, G4, D, G4, 1.f, 1);
    tab_gemm64<<<dim3(8, 128), 256, 0, stream>>>(dec_emb_w, dec_wi,   dec_bi,   dec_bh,   dec_tabP, 128, G4, D, G4, 1.f, 1);
    tab_gemm64<<<dim3(2, 128), 256, 0, stream>>>(dec_emb_w, wq_w, wq_b, nullptr, q_tab, 128, D, D, D, scale, 0);
    tab_gemm64<<<dim3(2, 1024), 256, 0, stream>>>(enc_post_w, wk_w, nullptr, nullptr, WKVo, 1024, D, D, 1024, 1.f, 0);
    tab_gemm64<<<dim3(2, 1024), 256, 0, stream>>>(enc_post_w, wv_w, nullptr, nullptr, Wv_tmp, 1024, D, D, D, 1.f, 0);
    tab_gemm64<<<dim3(2, 1024), 256, 0, stream>>>(Wv_tmp, wo_w, nullptr, nullptr, WKVo + D, 1024, D, D, 1024, 1.f, 0);
    tab_gemm64<<<dim3(2, 1), 256, 0, stream>>>(enc_post_b, wk_w, wk_b, nullptr, bkvo, 1, D, D, D, 1.f, 0);
    tab_gemm64<<<dim3(2, 1), 256, 0, stream>>>(enc_post_b, wv_w, wv_b, nullptr, bv_tmp, 1, D, D, D, 1.f, 0);
    tab_gemm64<<<dim3(2, 1), 256, 0, stream>>>(bv_tmp, wo_w, wo_b, nullptr, bkvo + D, 1, D, D, D, 1.f, 0);
    permW<<<dim3(8, 512), 256, 0, stream>>>(enc_wh_f, WhPf, 0);
    permW<<<dim3(8, 512), 256, 0, stream>>>(enc_wh_b, WhPb, 0);
    permW<<<dim3(8, 512), 256, 0, stream>>>(dec_wi,  dec_wiP, 512);
    permW<<<dim3(8, 512), 256, 0, stream>>>(dec_wh,  dec_whP, 0);
    init_kv<<<2048, 256, 0, stream>>>(bkvo, Kh, Vf);

    // ---------- encoder: 64 fused steps, both directions per launch ----------
    for (int t = 0; t < TS; ++t) {
        gates_cell<0><<<dim3(32, 16, 2), 256, 0, stream>>>(
            hFbuf[t & 1], hBbuf[t & 1], nullptr, nullptr,
            WhPf, WhPb, nullptr, nullptr,
            tabPf, tabPb,
            src + t, src + (TS - 1 - t), TS,
            cF, cB, hFbuf[(t + 1) & 1], hBbuf[(t + 1) & 1],
            t ? D : 0, t ? 1 : 0, dlayD);
        fold_kernel<<<dim3(16, 16, 2), 256, 0, stream>>>(
            hFbuf[(t + 1) & 1], hBbuf[(t + 1) & 1], WKVo, Kh, Vf, t, TS - 1 - t, dlayD);
    }

    // ---------- decoder initial h, c ----------
    hc_init<<<NB, 512, 0, stream>>>(hFbuf[0], hBbuf[0], cF, cB,
                                    h_post_w, h_post_b, c_post_w, c_post_b, hd[0], cdec);
    init_amax<<<4, 256, 0, stream>>>(tgt, amax);

    // ---------- decoder: 64 steps ----------
    for (int st = 0; st < TT; ++st) {
        attn_kernel<<<NB, 512, 0, stream>>>(q_tab, amax, Kh, Vf, attn_out, st, ctxb);
        gates_cell<1><<<dim3(32, 16, 1), 256, 0, stream>>>(
            ctxb, ctxb, hd[st & 1], hd[st & 1],
            dec_wiP, dec_wiP, dec_whP, dec_whP,
            dec_tabP, dec_tabP,
            amax, amax, 1,
            cdec, cdec, hd[(st + 1) & 1], hd[(st + 1) & 1],
            2 * D, 1, dlayD);
        out_argmax<<<NB, 128, 0, stream>>>(hd[(st + 1) & 1], dec_post_w, dec_post_b, res_out, st, amax);
    }
}

// Round 17
// 27057.614 us; speedup vs baseline: 3.7151x; 1.1000x over previous
//
#include <hip/hip_runtime.h>
#include <hip/hip_bf16.h>

namespace k77 {

typedef long long ll;
typedef double f64x4 __attribute__((ext_vector_type(4)));

constexpr int D    = 512;
constexpr int DTGT = 128;
constexpr int NB   = 1024;
constexpr int TS   = 64;
constexpr int TT   = 64;
constexpr int G4   = 2048;

// ---------------- runtime MFMA-f64 C/D-layout probe (r14-verified) ----------------
__global__ void probe_mfma(int* __restrict__ dlay)
{
    __shared__ double ref[256];
    __shared__ int ok[4];
    const int l = threadIdx.x;           // 64 threads
    const int l15 = l & 15, l4 = l >> 4;
    if (l < 4) ok[l] = 1;
    double a = 1.0 + 3.0 * l15 + 7.0 * l4;
    double b = 2.0 + 5.0 * l15 + 11.0 * l4;
    f64x4 d = {0.0, 0.0, 0.0, 0.0};
    d = __builtin_amdgcn_mfma_f64_16x16x4f64(a, b, d, 0, 0, 0);
    if (l < 16) {
        for (int j = 0; j < 16; ++j) {
            double s = 0.0;
            for (int k = 0; k < 4; ++k)
                s += (1.0 + 3.0 * l + 7.0 * k) * (2.0 + 5.0 * j + 11.0 * k);
            ref[l * 16 + j] = s;
        }
    }
    __syncthreads();
#pragma unroll
    for (int n = 0; n < 4; ++n) {
        if (d[n] != ref[(l4 * 4 + n) * 16 + l15]) atomicAnd(&ok[0], 0);
        if (d[n] != ref[(l4 + 4 * n) * 16 + l15]) atomicAnd(&ok[1], 0);
        if (d[n] != ref[l15 * 16 + (l4 * 4 + n)]) atomicAnd(&ok[2], 0);
        if (d[n] != ref[l15 * 16 + (l4 + 4 * n)]) atomicAnd(&ok[3], 0);
    }
    __syncthreads();
    if (l == 0) {
        int r = -1;
        for (int i = 3; i >= 0; --i) if (ok[i]) r = i;
        *dlay = r;
    }
}

__global__ void dlay_check(const int* __restrict__ dlay, float* __restrict__ out0)
{
    if (*dlay < 0)
        for (int i = threadIdx.x; i < 256; i += 64) out0[i] = 3.0e38f;
}

__device__ __forceinline__ void dmap(int dl, int l15, int l4, int n, int& r, int& c)
{
    if (dl == 1)      { r = l4 + 4 * n;  c = l15; }
    else if (dl == 2) { r = l15;         c = l4 * 4 + n; }
    else if (dl == 3) { r = l15;         c = l4 + 4 * n; }
    else              { r = l4 * 4 + n;  c = l15; }
}

// ---------------- precompute GEMM (f64 accumulate, f32 store) ----------------
__global__ void tab_gemm64(const float* __restrict__ A, const float* __restrict__ B,
                           const float* __restrict__ b1, const float* __restrict__ b2,
                           float* __restrict__ C, int M, int N, int K, int ldc, float scale, int perm)
{
    int j = blockIdx.x * 256 + threadIdx.x;
    int m = blockIdx.y;
    if (j >= N || m >= M) return;
    const float* ar = A + (size_t)m * K;
    double acc = 0.0;
    for (int k = 0; k < K; ++k) acc += (double)ar[k] * (double)B[(size_t)k * N + j];
    if (b1) acc += (double)b1[j];
    if (b2) acc += (double)b2[j];
    int j2 = perm ? ((j & 511) * 4 + (j >> 9)) : j;
    C[(size_t)m * ldc + j2] = (float)(acc * (double)scale);
}

// three 128x2048 permuted tables in one launch (z selects) — inner math verbatim
struct Tab3 { const float *A0,*A1,*A2,*B0,*B1,*B2,*p0,*p1,*p2,*q0,*q1,*q2; float *C0,*C1,*C2; };
__global__ void tab3_gemm64(Tab3 t)
{
    int j = blockIdx.x * 256 + threadIdx.x;   // 0..2047
    int m = blockIdx.y;                        // 0..127
    int z = blockIdx.z;
    const float* A  = z == 0 ? t.A0 : (z == 1 ? t.A1 : t.A2);
    const float* B  = z == 0 ? t.B0 : (z == 1 ? t.B1 : t.B2);
    const float* b1 = z == 0 ? t.p0 : (z == 1 ? t.p1 : t.p2);
    const float* b2 = z == 0 ? t.q0 : (z == 1 ? t.q1 : t.q2);
    float*       C  = z == 0 ? t.C0 : (z == 1 ? t.C1 : t.C2);
    const float* ar = A + (size_t)m * D;
    double acc = 0.0;
    for (int k = 0; k < D; ++k) acc += (double)ar[k] * (double)B[(size_t)k * G4 + j];
    acc += (double)b1[j];
    acc += (double)b2[j];
    C[(size_t)m * G4 + (j & 511) * 4 + (j >> 9)] = (float)acc;
}

// four 512x2048 weight permutes in one launch (z selects)
struct Perm4 { const float *i0,*i1,*i2,*i3; float *o0,*o1,*o2,*o3; int r0,r1,r2,r3; };
__global__ void permW4(Perm4 p)
{
    int j = blockIdx.x * 256 + threadIdx.x;   // 0..2047
    int k = blockIdx.y;                        // 0..511
    int z = blockIdx.z;
    const float* in = z == 0 ? p.i0 : (z == 1 ? p.i1 : (z == 2 ? p.i2 : p.i3));
    float*      out = z == 0 ? p.o0 : (z == 1 ? p.o1 : (z == 2 ? p.o2 : p.o3));
    int      rowoff = z == 0 ? p.r0 : (z == 1 ? p.r1 : (z == 2 ? p.r2 : p.r3));
    out[(size_t)k * G4 + (j & 511) * 4 + (j >> 9)] = in[(size_t)(k + rowoff) * G4 + j];
}

__global__ void init_kv(const float* __restrict__ bkvo, __hip_bfloat16* __restrict__ Kb,
                        float* __restrict__ Vb)
{
    for (ll i = (ll)blockIdx.x * 256 + threadIdx.x; i < (ll)NB * TS * D; i += (ll)gridDim.x * 256) {
        int d = (int)(i & (D - 1));
        Kb[i] = __float2bfloat16(bkvo[d]);
        Vb[i] = bkvo[D + d];
    }
}

// ---------------- gates GEMM (MFMA f64) + LSTM cell body (r14-verbatim) ----------------
template<int USE2>
__device__ __forceinline__ void gates_body(
    double* smem, const float* a0, const float* a1,
    const float* B0, const float* B1,
    const float* tab, const int* idx, int idxStride,
    float* cb, float* hb, int bx, int by, int K, int useC, int dl, int tid)
{
    float* As = (float*)smem;                   // [32][66]
    float* Bs = As + 32 * 66;
    const int row0 = by * 64, col0 = bx * 64;
    const int wave = tid >> 6, lane = tid & 63;
    const int wr = wave >> 1, wc = wave & 1;
    const int l15 = lane & 15, l4 = lane >> 4;

    f64x4 acc[2][2];
#pragma unroll
    for (int i = 0; i < 2; ++i)
#pragma unroll
        for (int j = 0; j < 2; ++j) acc[i][j] = (f64x4){0.0, 0.0, 0.0, 0.0};

    for (int k0 = 0; k0 < K; k0 += 32) {
#pragma unroll
        for (int l = 0; l < 8; ++l) {
            int t = tid + l * 256;
            {   int k = t & 31, m = t >> 5;
                int kk = k0 + k;
                float v;
                if (USE2 && kk >= D) v = a1[(size_t)(row0 + m) * D + (kk - D)];
                else                 v = a0[(size_t)(row0 + m) * D + kk];
                As[k * 66 + m] = v;
            }
            {   int j = t & 63, kr = t >> 6;
                int kk = k0 + kr;
                float v;
                if (USE2 && kk >= D) v = B1[(size_t)(kk - D) * G4 + col0 + j];
                else                 v = B0[(size_t)kk * G4 + col0 + j];
                Bs[kr * 66 + j] = v;
            }
        }
        __syncthreads();
#pragma unroll
        for (int kk4 = 0; kk4 < 8; ++kk4) {
            const int kr = kk4 * 4 + l4;
            double a0f = (double)As[kr * 66 + wr * 32 + l15];
            double a1f = (double)As[kr * 66 + wr * 32 + 16 + l15];
            double b0f = (double)Bs[kr * 66 + wc * 32 + l15];
            double b1f = (double)Bs[kr * 66 + wc * 32 + 16 + l15];
            acc[0][0] = __builtin_amdgcn_mfma_f64_16x16x4f64(a0f, b0f, acc[0][0], 0, 0, 0);
            acc[0][1] = __builtin_amdgcn_mfma_f64_16x16x4f64(a0f, b1f, acc[0][1], 0, 0, 0);
            acc[1][0] = __builtin_amdgcn_mfma_f64_16x16x4f64(a1f, b0f, acc[1][0], 0, 0, 0);
            acc[1][1] = __builtin_amdgcn_mfma_f64_16x16x4f64(a1f, b1f, acc[1][1], 0, 0, 0);
        }
        __syncthreads();
    }

    double* G = smem;                            // [64][66]
#pragma unroll
    for (int tr = 0; tr < 2; ++tr)
#pragma unroll
        for (int tc = 0; tc < 2; ++tc)
#pragma unroll
            for (int n = 0; n < 4; ++n) {
                int r, c;
                dmap(dl, l15, l4, n, r, c);
                G[(wr * 32 + tr * 16 + r) * 66 + (wc * 32 + tc * 16 + c)] = acc[tr][tc][n];
            }
    __syncthreads();

    const int ty = tid >> 4, tx = tid & 15;
    const int cc = col0 + tx * 4;
    const int d  = cc >> 2;
#pragma unroll
    for (int i = 0; i < 4; ++i) {
        int rl  = ty * 4 + i;
        int row = row0 + rl;
        const float* tr = tab + (size_t)idx[(size_t)row * idxStride] * G4;
        float gi = (float)(G[rl * 66 + tx * 4 + 0] + (double)tr[cc + 0]);
        float gf = (float)(G[rl * 66 + tx * 4 + 1] + (double)tr[cc + 1]);
        float gg = (float)(G[rl * 66 + tx * 4 + 2] + (double)tr[cc + 2]);
        float go = (float)(G[rl * 66 + tx * 4 + 3] + (double)tr[cc + 3]);
        float c  = useC ? cb[(size_t)row * D + d] : 0.f;
        float si = 1.f / (1.f + expf(-gi));
        float sf = 1.f / (1.f + expf(-gf));
        float so = 1.f / (1.f + expf(-go));
        c = sf * c + si * tanhf(gg);
        cb[(size_t)row * D + d] = c;
        hb[(size_t)row * D + d] = so * tanhf(c);
    }
}

// ---------------- K/V' fold body (r14-verbatim) ----------------
__device__ __forceinline__ void fold_body(
    double* smem, const float* h, const float* W, int rowoff,
    __hip_bfloat16* Kb, float* Vb, int trow, int bx, int by, int dl, int tid)
{
    float* As = (float*)smem;
    float* Bs = As + 32 * 66;
    const int row0 = by * 64, col0 = bx * 64;
    const int wave = tid >> 6, lane = tid & 63;
    const int wr = wave >> 1, wc = wave & 1;
    const int l15 = lane & 15, l4 = lane >> 4;

    f64x4 acc[2][2];
#pragma unroll
    for (int i = 0; i < 2; ++i)
#pragma unroll
        for (int j = 0; j < 2; ++j) acc[i][j] = (f64x4){0.0, 0.0, 0.0, 0.0};

    for (int k0 = 0; k0 < D; k0 += 32) {
#pragma unroll
        for (int l = 0; l < 8; ++l) {
            int t = tid + l * 256;
            {   int k = t & 31, m = t >> 5;
                As[k * 66 + m] = h[(size_t)(row0 + m) * D + k0 + k];
            }
            {   int j = t & 63, kr = t >> 6;
                Bs[kr * 66 + j] = W[(size_t)(rowoff + k0 + kr) * 1024 + col0 + j];
            }
        }
        __syncthreads();
#pragma unroll
        for (int kk4 = 0; kk4 < 8; ++kk4) {
            const int kr = kk4 * 4 + l4;
            double a0f = (double)As[kr * 66 + wr * 32 + l15];
            double a1f = (double)As[kr * 66 + wr * 32 + 16 + l15];
            double b0f = (double)Bs[kr * 66 + wc * 32 + l15];
            double b1f = (double)Bs[kr * 66 + wc * 32 + 16 + l15];
            acc[0][0] = __builtin_amdgcn_mfma_f64_16x16x4f64(a0f, b0f, acc[0][0], 0, 0, 0);
            acc[0][1] = __builtin_amdgcn_mfma_f64_16x16x4f64(a0f, b1f, acc[0][1], 0, 0, 0);
            acc[1][0] = __builtin_amdgcn_mfma_f64_16x16x4f64(a1f, b0f, acc[1][0], 0, 0, 0);
            acc[1][1] = __builtin_amdgcn_mfma_f64_16x16x4f64(a1f, b1f, acc[1][1], 0, 0, 0);
        }
        __syncthreads();
    }

#pragma unroll
    for (int tr = 0; tr < 2; ++tr)
#pragma unroll
        for (int tc = 0; tc < 2; ++tc)
#pragma unroll
            for (int n = 0; n < 4; ++n) {
                int r, c;
                dmap(dl, l15, l4, n, r, c);
                int row = row0 + wr * 32 + tr * 16 + r;
                int col = col0 + wc * 32 + tc * 16 + c;
                double v = acc[tr][tc][n];
                ll ix = ((ll)row * TS + trow) * D + (col & (D - 1));
                if (col < D) {
                    double v2 = v + (double)__bfloat162float(Kb[ix]);
                    Kb[ix] = __float2bfloat16((float)v2);
                } else {
                    Vb[ix] = (float)((double)Vb[ix] + v);
                }
            }
}

// ---------------- fused ENCODER step: gates(t) tiles + fold(t-1) tiles, one launch ----------------
struct EncArgs {
    const float *hFr, *hBr;          // h(t): gates read AND fold read
    float *hFw, *hBw, *cF, *cB;
    const float *WhPf, *WhPb, *tabPf, *tabPb;
    const int *srcF, *srcB;
    const float *WKVo;
    __hip_bfloat16 *Kb; float *Vb;
    int foldF, foldB;                // fold target rows (step t-1)
    int K, useC, nG;
    const int *dlayp;
};

__global__ __launch_bounds__(256)
void enc_mega(EncArgs a)
{
    __shared__ double smem[64 * 66];
    const int bid = blockIdx.x;
    const int tid = threadIdx.x;
    const int dl  = a.dlayp[0];
    if (bid < a.nG) {
        const int dir = bid >> 9;             // 0 = F, 1 = B
        const int tt  = bid & 511;
        gates_body<0>(smem,
                      dir ? a.hBr : a.hFr, nullptr,
                      dir ? a.WhPb : a.WhPf, nullptr,
                      dir ? a.tabPb : a.tabPf,
                      dir ? a.srcB : a.srcF, TS,
                      dir ? a.cB : a.cF,
                      dir ? a.hBw : a.hFw,
                      tt & 31, tt >> 5, a.K, a.useC, dl, tid);
    } else {
        const int ff = bid - a.nG;            // 0..511
        const int fz = ff >> 8;
        fold_body(smem, fz ? a.hBr : a.hFr, a.WKVo, fz ? D : 0,
                  a.Kb, a.Vb, fz ? a.foldB : a.foldF,
                  ff & 15, (ff >> 4) & 15, dl, tid);
    }
}

// ---------------- decoder gates launch (r14-identical math) ----------------
struct DGArgs {
    const float *ctx, *h;
    const float *wiP, *whP, *tabP;
    const int *amax;
    float *cdec, *hw;
    const int *dlayp;
};

__global__ __launch_bounds__(256)
void dec_gates(DGArgs a)
{
    __shared__ double smem[64 * 66];
    const int bid = blockIdx.x;   // 0..511
    gates_body<1>(smem, a.ctx, a.h, a.wiP, a.whP, a.tabP,
                  a.amax, 1, a.cdec, a.hw, bid & 31, bid >> 5, 2 * D, 1,
                  a.dlayp[0], threadIdx.x);
}

// ---------------- attention for step 0 (r14-verbatim, 512 threads) ----------------
__global__ void attn_kernel(const float* __restrict__ qtab, const int* __restrict__ amax,
                            const __hip_bfloat16* __restrict__ Kb, const float* __restrict__ Vb,
                            float* __restrict__ aout, int step, float* __restrict__ ctx)
{
    const int b = blockIdx.x, tid = threadIdx.x;
    __shared__ float qs[D];
    __shared__ float ss[TS];
    qs[tid] = qtab[(size_t)amax[b] * D + tid];
    __syncthreads();
    const int t = tid >> 3, l8 = tid & 7;
    const __hip_bfloat16* krow = Kb + ((size_t)b * TS + t) * D;
    double acc = 0.0;
    for (int d = l8; d < D; d += 8) acc += (double)qs[d] * (double)__bfloat162float(krow[d]);
    acc += __shfl_xor(acc, 4);
    acc += __shfl_xor(acc, 2);
    acc += __shfl_xor(acc, 1);
    if (l8 == 0) ss[t] = (float)acc;
    __syncthreads();
    if (tid < TS) {
        float v = ss[tid], mx = v;
#pragma unroll
        for (int o = 32; o; o >>= 1) mx = fmaxf(mx, __shfl_xor(mx, o));
        float e = expf(v - mx), sm = e;
#pragma unroll
        for (int o = 32; o; o >>= 1) sm += __shfl_xor(sm, o);
        float sc = e / sm;
        ss[tid] = sc;
        aout[((size_t)b * TT + step) * TS + tid] = sc;
    }
    __syncthreads();
    double a = 0.0;
    const float* vcol = Vb + (size_t)b * TS * D + tid;
    for (int t2 = 0; t2 < TS; ++t2) a += (double)ss[t2] * (double)vcol[(size_t)t2 * D];
    ctx[(size_t)b * D + tid] = (float)a;
}

// ---------------- fused out_argmax(st) + attn(st+1), one row per block, 512 threads ----------------
__global__ __launch_bounds__(512)
void out_attn(const float* __restrict__ h, const float* __restrict__ W,
              const float* __restrict__ bias, float* __restrict__ res,
              int step, int* __restrict__ amax,
              const float* __restrict__ qtab, const __hip_bfloat16* __restrict__ Kb,
              const float* __restrict__ Vb, float* __restrict__ aout,
              float* __restrict__ ctx, int doAttn)
{
    const int b = blockIdx.x, tid = threadIdx.x;
    __shared__ float hs[D];
    __shared__ double vals[DTGT];
    __shared__ int tok;
    __shared__ float qs[D];
    __shared__ float ss[TS];

    // phase 1: out projection + argmax (r14 arithmetic, tid<128 active)
    hs[tid] = h[(size_t)b * D + tid];
    __syncthreads();
    if (tid < DTGT) {
        double acc = (double)bias[tid];
        for (int k = 0; k < D; ++k) acc += (double)hs[k] * (double)W[(size_t)k * DTGT + tid];
        vals[tid] = acc;
        res[((size_t)b * TT + step) * DTGT + tid] = (float)acc;
    }
    __syncthreads();
    if (tid == 0) {
        double best = vals[0]; int bi = 0;
        for (int j = 1; j < DTGT; ++j) if (vals[j] > best) { best = vals[j]; bi = j; }
        amax[b] = bi;
        tok = bi;
    }
    __syncthreads();

    if (!doAttn) return;

    // phase 2: attention for step+1 (r14-verbatim arithmetic)
    qs[tid] = qtab[(size_t)tok * D + tid];
    __syncthreads();
    const int t = tid >> 3, l8 = tid & 7;
    const __hip_bfloat16* krow = Kb + ((size_t)b * TS + t) * D;
    double acc = 0.0;
    for (int d = l8; d < D; d += 8) acc += (double)qs[d] * (double)__bfloat162float(krow[d]);
    acc += __shfl_xor(acc, 4);
    acc += __shfl_xor(acc, 2);
    acc += __shfl_xor(acc, 1);
    if (l8 == 0) ss[t] = (float)acc;
    __syncthreads();
    if (tid < TS) {
        float v = ss[tid], mx = v;
#pragma unroll
        for (int o = 32; o; o >>= 1) mx = fmaxf(mx, __shfl_xor(mx, o));
        float e = expf(v - mx), sm = e;
#pragma unroll
        for (int o = 32; o; o >>= 1) sm += __shfl_xor(sm, o);
        float sc = e / sm;
        ss[tid] = sc;
        aout[((size_t)b * TT + (step + 1)) * TS + tid] = sc;
    }
    __syncthreads();
    double a = 0.0;
    const float* vcol = Vb + (size_t)b * TS * D + tid;
    for (int t2 = 0; t2 < TS; ++t2) a += (double)ss[t2] * (double)vcol[(size_t)t2 * D];
    ctx[(size_t)b * D + tid] = (float)a;
}

// ---------------- decoder init: h0/c0 (r14-verbatim) ----------------
__global__ __launch_bounds__(512)
void hc_init(const float* __restrict__ hF, const float* __restrict__ hB,
             const float* __restrict__ cF, const float* __restrict__ cB,
             const float* __restrict__ hpw, const float* __restrict__ hpb,
             const float* __restrict__ cpw, const float* __restrict__ cpb,
             float* __restrict__ h0, float* __restrict__ c0)
{
    __shared__ float s0[D], s1[D], s2[D], s3[D];
    const int b = blockIdx.x, j = threadIdx.x;
    s0[j] = hF[(size_t)b * D + j]; s1[j] = hB[(size_t)b * D + j];
    s2[j] = cF[(size_t)b * D + j]; s3[j] = cB[(size_t)b * D + j];
    __syncthreads();
    double a = (double)hpb[j];
    for (int k = 0; k < D; ++k) a += (double)s0[k] * (double)hpw[(size_t)k * D + j];
    for (int k = 0; k < D; ++k) a += (double)s1[k] * (double)hpw[(size_t)(k + D) * D + j];
    h0[(size_t)b * D + j] = (float)tanh(a);
    a = (double)cpb[j];
    for (int k = 0; k < D; ++k) a += (double)s2[k] * (double)cpw[(size_t)k * D + j];
    for (int k = 0; k < D; ++k) a += (double)s3[k] * (double)cpw[(size_t)(k + D) * D + j];
    c0[(size_t)b * D + j] = (float)tanh(a);
}

__global__ void init_amax(const int* __restrict__ tgt, int* __restrict__ amax)
{
    int b = blockIdx.x * 256 + threadIdx.x;
    if (b < NB) amax[b] = tgt[(size_t)b * TT];
}

} // namespace k77

extern "C" void kernel_launch(void* const* d_in, const int* in_sizes, int n_in,
                              void* d_out, int out_size, void* d_ws, size_t ws_size,
                              hipStream_t stream)
{
    using namespace k77;
    (void)in_sizes; (void)n_in; (void)out_size;

    const int*   src        = (const int*)  d_in[0];
    const int*   tgt        = (const int*)  d_in[1];
    const float* enc_emb_w  = (const float*)d_in[2];
    const float* enc_wi_f   = (const float*)d_in[3];
    const float* enc_wh_f   = (const float*)d_in[4];
    const float* enc_bi_f   = (const float*)d_in[5];
    const float* enc_bh_f   = (const float*)d_in[6];
    const float* enc_wi_b   = (const float*)d_in[7];
    const float* enc_wh_b   = (const float*)d_in[8];
    const float* enc_bi_b   = (const float*)d_in[9];
    const float* enc_bh_b   = (const float*)d_in[10];
    const float* enc_post_w = (const float*)d_in[11];
    const float* enc_post_b = (const float*)d_in[12];
    const float* h_post_w   = (const float*)d_in[13];
    const float* h_post_b   = (const float*)d_in[14];
    const float* c_post_w   = (const float*)d_in[15];
    const float* c_post_b   = (const float*)d_in[16];
    const float* wq_w       = (const float*)d_in[17];
    const float* wq_b       = (const float*)d_in[18];
    const float* wk_w       = (const float*)d_in[19];
    const float* wk_b       = (const float*)d_in[20];
    const float* wv_w       = (const float*)d_in[21];
    const float* wv_b       = (const float*)d_in[22];
    const float* wo_w       = (const float*)d_in[23];
    const float* wo_b       = (const float*)d_in[24];
    const float* dec_emb_w  = (const float*)d_in[25];
    const float* dec_wi     = (const float*)d_in[26];
    const float* dec_wh     = (const float*)d_in[27];
    const float* dec_bi     = (const float*)d_in[28];
    const float* dec_bh     = (const float*)d_in[29];
    const float* dec_post_w = (const float*)d_in[30];
    const float* dec_post_b = (const float*)d_in[31];

    float* ws = (float*)d_ws;
    size_t off = 0;
    auto alloc = [&](size_t n) { float* p = ws + off; off += n; return p; };
    float* hF0     = alloc((size_t)NB * D);
    float* hF1     = alloc((size_t)NB * D);
    float* hB0     = alloc((size_t)NB * D);
    float* hB1     = alloc((size_t)NB * D);
    float* cF      = alloc((size_t)NB * D);
    float* cB      = alloc((size_t)NB * D);
    float* hd0     = alloc((size_t)NB * D);
    float* hd1     = alloc((size_t)NB * D);
    float* cdec    = alloc((size_t)NB * D);
    float* ctxb    = alloc((size_t)NB * D);
    float* tabPf   = alloc((size_t)128 * G4);
    float* tabPb   = alloc((size_t)128 * G4);
    float* dec_tabP= alloc((size_t)128 * G4);
    float* q_tab   = alloc((size_t)128 * D);
    float* WKVo    = alloc((size_t)1024 * 1024);
    float* bkvo    = alloc(1024);
    float* WhPf    = alloc((size_t)D * G4);
    float* WhPb    = alloc((size_t)D * G4);
    float* dec_wiP = alloc((size_t)D * G4);
    float* dec_whP = alloc((size_t)D * G4);
    float* Wv_tmp  = alloc((size_t)1024 * D);
    float* bv_tmp  = alloc(D);
    int*   amax    = (int*)alloc(1024);
    int*   dlayD   = (int*)alloc(64);

    const size_t commonF = off;
    const size_t kvCnt   = (size_t)NB * TS * D;
    const size_t need    = commonF * 4 + kvCnt * 2 + kvCnt * 4;   // ~249 MB

    if (ws_size < need) {
        hipMemsetAsync(d_out, 0x7F, 1024, stream);   // sentinel: ws too small
        return;
    }
    __hip_bfloat16* Kh = (__hip_bfloat16*)(ws + commonF);
    float*          Vf = (float*)((char*)Kh + kvCnt * 2);

    float* attn_out = (float*)d_out;
    float* res_out  = attn_out + (size_t)NB * TT * TS;

    const float scale = 0.044194173824159216f;   // 512^-0.5

    float* hFbuf[2] = {hF0, hF1};
    float* hBbuf[2] = {hB0, hB1};
    float* hd[2]    = {hd0, hd1};

    // ---------- MFMA layout probe ----------
    probe_mfma<<<1, 64, 0, stream>>>(dlayD);
    dlay_check<<<1, 64, 0, stream>>>(dlayD, attn_out);

    // ---------- precompute ----------
    Tab3 t3;
    t3.A0 = enc_emb_w; t3.A1 = enc_emb_w; t3.A2 = dec_emb_w;
    t3.B0 = enc_wi_f;  t3.B1 = enc_wi_b;  t3.B2 = dec_wi;
    t3.p0 = enc_bi_f;  t3.p1 = enc_bi_b;  t3.p2 = dec_bi;
    t3.q0 = enc_bh_f;  t3.q1 = enc_bh_b;  t3.q2 = dec_bh;
    t3.C0 = tabPf;     t3.C1 = tabPb;     t3.C2 = dec_tabP;
    tab3_gemm64<<<dim3(8, 128, 3), 256, 0, stream>>>(t3);
    tab_gemm64<<<dim3(2, 128), 256, 0, stream>>>(dec_emb_w, wq_w, wq_b, nullptr, q_tab, 128, D, D, D, scale, 0);
    tab_gemm64<<<dim3(2, 1024), 256, 0, stream>>>(enc_post_w, wk_w, nullptr, nullptr, WKVo, 1024, D, D, 1024, 1.f, 0);
    tab_gemm64<<<dim3(2, 1024), 256, 0, stream>>>(enc_post_w, wv_w, nullptr, nullptr, Wv_tmp, 1024, D, D, D, 1.f, 0);
    tab_gemm64<<<dim3(2, 1024), 256, 0, stream>>>(Wv_tmp, wo_w, nullptr, nullptr, WKVo + D, 1024, D, D, 1024, 1.f, 0);
    tab_gemm64<<<dim3(2, 1), 256, 0, stream>>>(enc_post_b, wk_w, wk_b, nullptr, bkvo, 1, D, D, D, 1.f, 0);
    tab_gemm64<<<dim3(2, 1), 256, 0, stream>>>(enc_post_b, wv_w, wv_b, nullptr, bv_tmp, 1, D, D, D, 1.f, 0);
    tab_gemm64<<<dim3(2, 1), 256, 0, stream>>>(bv_tmp, wo_w, wo_b, nullptr, bkvo + D, 1, D, D, D, 1.f, 0);
    Perm4 p4;
    p4.i0 = enc_wh_f; p4.o0 = WhPf;    p4.r0 = 0;
    p4.i1 = enc_wh_b; p4.o1 = WhPb;    p4.r1 = 0;
    p4.i2 = dec_wi;   p4.o2 = dec_wiP; p4.r2 = 512;
    p4.i3 = dec_wh;   p4.o3 = dec_whP; p4.r3 = 0;
    permW4<<<dim3(8, 512, 4), 256, 0, stream>>>(p4);
    init_kv<<<2048, 256, 0, stream>>>(bkvo, Kh, Vf);

    // ---------- encoder: 65 fused launches (gates(t) + fold(t-1)) ----------
    for (int t = 0; t < TS; ++t) {
        EncArgs ea;
        ea.hFr = hFbuf[t & 1]; ea.hBr = hBbuf[t & 1];
        ea.hFw = hFbuf[(t + 1) & 1]; ea.hBw = hBbuf[(t + 1) & 1];
        ea.cF = cF; ea.cB = cB;
        ea.WhPf = WhPf; ea.WhPb = WhPb; ea.tabPf = tabPf; ea.tabPb = tabPb;
        ea.srcF = src + t; ea.srcB = src + (TS - 1 - t);
        ea.WKVo = WKVo; ea.Kb = Kh; ea.Vb = Vf;
        ea.foldF = t - 1; ea.foldB = TS - t;   // fold for step t-1 (reads h(t) = hFr/hBr)
        ea.K = t ? D : 0; ea.useC = t ? 1 : 0; ea.nG = 1024;
        ea.dlayp = dlayD;
        const int grid = 1024 + (t ? 512 : 0);
        enc_mega<<<grid, 256, 0, stream>>>(ea);
    }
    {   // final fold for step 63 (reads h(64) = buf[0])
        EncArgs ea;
        ea.hFr = hFbuf[0]; ea.hBr = hBbuf[0];
        ea.hFw = nullptr; ea.hBw = nullptr; ea.cF = cF; ea.cB = cB;
        ea.WhPf = WhPf; ea.WhPb = WhPb; ea.tabPf = tabPf; ea.tabPb = tabPb;
        ea.srcF = src; ea.srcB = src;
        ea.WKVo = WKVo; ea.Kb = Kh; ea.Vb = Vf;
        ea.foldF = 63; ea.foldB = 0;
        ea.K = 0; ea.useC = 0; ea.nG = 0;
        ea.dlayp = dlayD;
        enc_mega<<<512, 256, 0, stream>>>(ea);
    }

    // ---------- decoder initial h, c ----------
    hc_init<<<NB, 512, 0, stream>>>(hFbuf[0], hBbuf[0], cF, cB,
                                    h_post_w, h_post_b, c_post_w, c_post_b, hd0, cdec);
    init_amax<<<4, 256, 0, stream>>>(tgt, amax);

    // ---------- decoder: attn(0) + 64x(gates; out+attn) ----------
    attn_kernel<<<NB, 512, 0, stream>>>(q_tab, amax, Kh, Vf, attn_out, 0, ctxb);
    for (int st = 0; st < TT; ++st) {
        DGArgs da;
        da.ctx = ctxb; da.h = hd[st & 1];
        da.wiP = dec_wiP; da.whP = dec_whP; da.tabP = dec_tabP;
        da.amax = amax; da.cdec = cdec; da.hw = hd[(st + 1) & 1];
        da.dlayp = dlayD;
        dec_gates<<<512, 256, 0, stream>>>(da);
        out_attn<<<NB, 512, 0, stream>>>(hd[(st + 1) & 1], dec_post_w, dec_post_b, res_out,
                                         st, amax, q_tab, Kh, Vf, attn_out, ctxb,
                                         st < TT - 1 ? 1 : 0);
    }
}

// Round 18
// 22903.802 us; speedup vs baseline: 4.3889x; 1.1814x over previous
//
#include <hip/hip_runtime.h>
#include <hip/hip_bf16.h>

namespace k77 {

typedef long long ll;
typedef double f64x4 __attribute__((ext_vector_type(4)));

constexpr int D    = 512;
constexpr int DTGT = 128;
constexpr int NB   = 1024;
constexpr int TS   = 64;
constexpr int TT   = 64;
constexpr int G4   = 2048;

// ---------------- runtime MFMA-f64 C/D-layout probe (r14-verified) ----------------
__global__ void probe_mfma(int* __restrict__ dlay)
{
    __shared__ double ref[256];
    __shared__ int ok[4];
    const int l = threadIdx.x;           // 64 threads
    const int l15 = l & 15, l4 = l >> 4;
    if (l < 4) ok[l] = 1;
    double a = 1.0 + 3.0 * l15 + 7.0 * l4;
    double b = 2.0 + 5.0 * l15 + 11.0 * l4;
    f64x4 d = {0.0, 0.0, 0.0, 0.0};
    d = __builtin_amdgcn_mfma_f64_16x16x4f64(a, b, d, 0, 0, 0);
    if (l < 16) {
        for (int j = 0; j < 16; ++j) {
            double s = 0.0;
            for (int k = 0; k < 4; ++k)
                s += (1.0 + 3.0 * l + 7.0 * k) * (2.0 + 5.0 * j + 11.0 * k);
            ref[l * 16 + j] = s;
        }
    }
    __syncthreads();
#pragma unroll
    for (int n = 0; n < 4; ++n) {
        if (d[n] != ref[(l4 * 4 + n) * 16 + l15]) atomicAnd(&ok[0], 0);
        if (d[n] != ref[(l4 + 4 * n) * 16 + l15]) atomicAnd(&ok[1], 0);
        if (d[n] != ref[l15 * 16 + (l4 * 4 + n)]) atomicAnd(&ok[2], 0);
        if (d[n] != ref[l15 * 16 + (l4 + 4 * n)]) atomicAnd(&ok[3], 0);
    }
    __syncthreads();
    if (l == 0) {
        int r = -1;
        for (int i = 3; i >= 0; --i) if (ok[i]) r = i;
        *dlay = r;
    }
}

__global__ void dlay_check(const int* __restrict__ dlay, float* __restrict__ out0)
{
    if (*dlay < 0)
        for (int i = threadIdx.x; i < 256; i += 64) out0[i] = 3.0e38f;
}

__device__ __forceinline__ void dmap(int dl, int l15, int l4, int n, int& r, int& c)
{
    if (dl == 1)      { r = l4 + 4 * n;  c = l15; }
    else if (dl == 2) { r = l15;         c = l4 * 4 + n; }
    else if (dl == 3) { r = l15;         c = l4 + 4 * n; }
    else              { r = l4 * 4 + n;  c = l15; }
}

// ---------------- precompute GEMM (f64 accumulate, f32 store) ----------------
__global__ void tab_gemm64(const float* __restrict__ A, const float* __restrict__ B,
                           const float* __restrict__ b1, const float* __restrict__ b2,
                           float* __restrict__ C, int M, int N, int K, int ldc, float scale, int perm)
{
    int j = blockIdx.x * 256 + threadIdx.x;
    int m = blockIdx.y;
    if (j >= N || m >= M) return;
    const float* ar = A + (size_t)m * K;
    double acc = 0.0;
    for (int k = 0; k < K; ++k) acc += (double)ar[k] * (double)B[(size_t)k * N + j];
    if (b1) acc += (double)b1[j];
    if (b2) acc += (double)b2[j];
    int j2 = perm ? ((j & 511) * 4 + (j >> 9)) : j;
    C[(size_t)m * ldc + j2] = (float)(acc * (double)scale);
}

// three 128x2048 permuted tables in one launch (z selects)
struct Tab3 { const float *A0,*A1,*A2,*B0,*B1,*B2,*p0,*p1,*p2,*q0,*q1,*q2; float *C0,*C1,*C2; };
__global__ void tab3_gemm64(Tab3 t)
{
    int j = blockIdx.x * 256 + threadIdx.x;   // 0..2047
    int m = blockIdx.y;                        // 0..127
    int z = blockIdx.z;
    const float* A  = z == 0 ? t.A0 : (z == 1 ? t.A1 : t.A2);
    const float* B  = z == 0 ? t.B0 : (z == 1 ? t.B1 : t.B2);
    const float* b1 = z == 0 ? t.p0 : (z == 1 ? t.p1 : t.p2);
    const float* b2 = z == 0 ? t.q0 : (z == 1 ? t.q1 : t.q2);
    float*       C  = z == 0 ? t.C0 : (z == 1 ? t.C1 : t.C2);
    const float* ar = A + (size_t)m * D;
    double acc = 0.0;
    for (int k = 0; k < D; ++k) acc += (double)ar[k] * (double)B[(size_t)k * G4 + j];
    acc += (double)b1[j];
    acc += (double)b2[j];
    C[(size_t)m * G4 + (j & 511) * 4 + (j >> 9)] = (float)acc;
}

// four 512x2048 weight permutes in one launch (z selects)
struct Perm4 { const float *i0,*i1,*i2,*i3; float *o0,*o1,*o2,*o3; int r0,r1,r2,r3; };
__global__ void permW4(Perm4 p)
{
    int j = blockIdx.x * 256 + threadIdx.x;   // 0..2047
    int k = blockIdx.y;                        // 0..511
    int z = blockIdx.z;
    const float* in = z == 0 ? p.i0 : (z == 1 ? p.i1 : (z == 2 ? p.i2 : p.i3));
    float*      out = z == 0 ? p.o0 : (z == 1 ? p.o1 : (z == 2 ? p.o2 : p.o3));
    int      rowoff = z == 0 ? p.r0 : (z == 1 ? p.r1 : (z == 2 ? p.r2 : p.r3));
    out[(size_t)k * G4 + (j & 511) * 4 + (j >> 9)] = in[(size_t)(k + rowoff) * G4 + j];
}

__global__ void init_kv(const float* __restrict__ bkvo, __hip_bfloat16* __restrict__ Kb,
                        float* __restrict__ Vb)
{
    for (ll i = (ll)blockIdx.x * 256 + threadIdx.x; i < (ll)NB * TS * D; i += (ll)gridDim.x * 256) {
        int d = (int)(i & (D - 1));
        Kb[i] = __float2bfloat16(bkvo[d]);
        Vb[i] = bkvo[D + d];
    }
}

// ---------------- gates GEMM (MFMA f64) + LSTM cell body ----------------
// Transposed f32 staging (As[m][k] LD34, Bs[j][kr] LD35 — conflict-free writes, 2-way reads).
// G-bounce in f32 with the table add folded in: (float)(acc + (double)tab) — same single
// f64-add-then-round as r14's epilogue => bit-identical values. LDS 17.7 KB/block.
template<int USE2>
__device__ __forceinline__ void gates_body(
    double* smem, const float* a0, const float* a1,
    const float* B0, const float* B1,
    const float* tab, const int* idx, int idxStride,
    float* cb, float* hb, int bx, int by, int K, int useC, int dl, int tid)
{
    float* As = (float*)smem;                   // [64 m][34 k]
    float* Bs = As + 64 * 34;                   // [64 j][35 kr]
    const int row0 = by * 64, col0 = bx * 64;
    const int wave = tid >> 6, lane = tid & 63;
    const int wr = wave >> 1, wc = wave & 1;
    const int l15 = lane & 15, l4 = lane >> 4;

    f64x4 acc[2][2];
#pragma unroll
    for (int i = 0; i < 2; ++i)
#pragma unroll
        for (int j = 0; j < 2; ++j) acc[i][j] = (f64x4){0.0, 0.0, 0.0, 0.0};

    for (int k0 = 0; k0 < K; k0 += 32) {
#pragma unroll
        for (int l = 0; l < 8; ++l) {
            int t = tid + l * 256;
            {   int k = t & 31, m = t >> 5;
                int kk = k0 + k;
                float v;
                if (USE2 && kk >= D) v = a1[(size_t)(row0 + m) * D + (kk - D)];
                else                 v = a0[(size_t)(row0 + m) * D + kk];
                As[m * 34 + k] = v;
            }
            {   int j = t & 63, kr = t >> 6;
                int kk = k0 + kr;
                float v;
                if (USE2 && kk >= D) v = B1[(size_t)(kk - D) * G4 + col0 + j];
                else                 v = B0[(size_t)kk * G4 + col0 + j];
                Bs[j * 35 + kr] = v;
            }
        }
        __syncthreads();
#pragma unroll
        for (int kk4 = 0; kk4 < 8; ++kk4) {
            const int kr = kk4 * 4 + l4;
            double a0f = (double)As[(wr * 32 + l15) * 34 + kr];
            double a1f = (double)As[(wr * 32 + 16 + l15) * 34 + kr];
            double b0f = (double)Bs[(wc * 32 + l15) * 35 + kr];
            double b1f = (double)Bs[(wc * 32 + 16 + l15) * 35 + kr];
            acc[0][0] = __builtin_amdgcn_mfma_f64_16x16x4f64(a0f, b0f, acc[0][0], 0, 0, 0);
            acc[0][1] = __builtin_amdgcn_mfma_f64_16x16x4f64(a0f, b1f, acc[0][1], 0, 0, 0);
            acc[1][0] = __builtin_amdgcn_mfma_f64_16x16x4f64(a1f, b0f, acc[1][0], 0, 0, 0);
            acc[1][1] = __builtin_amdgcn_mfma_f64_16x16x4f64(a1f, b1f, acc[1][1], 0, 0, 0);
        }
        __syncthreads();
    }

    // bounce acc -> f32 gates in LDS (tab added in f64, rounded once — r14-identical values)
    float* G = (float*)smem;                    // [64][66]
#pragma unroll
    for (int tr = 0; tr < 2; ++tr)
#pragma unroll
        for (int tc = 0; tc < 2; ++tc)
#pragma unroll
            for (int n = 0; n < 4; ++n) {
                int r, c;
                dmap(dl, l15, l4, n, r, c);
                int lr = wr * 32 + tr * 16 + r;
                int lc = wc * 32 + tc * 16 + c;
                const float* trw = tab + (size_t)idx[(size_t)(row0 + lr) * idxStride] * G4;
                G[lr * 66 + lc] = (float)(acc[tr][tc][n] + (double)trw[col0 + lc]);
            }
    __syncthreads();

    const int ty = tid >> 4, tx = tid & 15;
    const int d  = (col0 + tx * 4) >> 2;
#pragma unroll
    for (int i = 0; i < 4; ++i) {
        int rl  = ty * 4 + i;
        int row = row0 + rl;
        float gi = G[rl * 66 + tx * 4 + 0];
        float gf = G[rl * 66 + tx * 4 + 1];
        float gg = G[rl * 66 + tx * 4 + 2];
        float go = G[rl * 66 + tx * 4 + 3];
        float c  = useC ? cb[(size_t)row * D + d] : 0.f;
        float si = 1.f / (1.f + expf(-gi));
        float sf = 1.f / (1.f + expf(-gf));
        float so = 1.f / (1.f + expf(-go));
        c = sf * c + si * tanhf(gg);
        cb[(size_t)row * D + d] = c;
        hb[(size_t)row * D + d] = so * tanhf(c);
    }
}

// ---------------- K/V' fold body (MFMA f64, transposed staging, r14-identical math) ----------------
__device__ __forceinline__ void fold_body(
    double* smem, const float* h, const float* W, int rowoff,
    __hip_bfloat16* Kb, float* Vb, int trow, int bx, int by, int dl, int tid)
{
    float* As = (float*)smem;                   // [64 m][34 k]
    float* Bs = As + 64 * 34;                   // [64 j][35 kr]
    const int row0 = by * 64, col0 = bx * 64;
    const int wave = tid >> 6, lane = tid & 63;
    const int wr = wave >> 1, wc = wave & 1;
    const int l15 = lane & 15, l4 = lane >> 4;

    f64x4 acc[2][2];
#pragma unroll
    for (int i = 0; i < 2; ++i)
#pragma unroll
        for (int j = 0; j < 2; ++j) acc[i][j] = (f64x4){0.0, 0.0, 0.0, 0.0};

    for (int k0 = 0; k0 < D; k0 += 32) {
#pragma unroll
        for (int l = 0; l < 8; ++l) {
            int t = tid + l * 256;
            {   int k = t & 31, m = t >> 5;
                As[m * 34 + k] = h[(size_t)(row0 + m) * D + k0 + k];
            }
            {   int j = t & 63, kr = t >> 6;
                Bs[j * 35 + kr] = W[(size_t)(rowoff + k0 + kr) * 1024 + col0 + j];
            }
        }
        __syncthreads();
#pragma unroll
        for (int kk4 = 0; kk4 < 8; ++kk4) {
            const int kr = kk4 * 4 + l4;
            double a0f = (double)As[(wr * 32 + l15) * 34 + kr];
            double a1f = (double)As[(wr * 32 + 16 + l15) * 34 + kr];
            double b0f = (double)Bs[(wc * 32 + l15) * 35 + kr];
            double b1f = (double)Bs[(wc * 32 + 16 + l15) * 35 + kr];
            acc[0][0] = __builtin_amdgcn_mfma_f64_16x16x4f64(a0f, b0f, acc[0][0], 0, 0, 0);
            acc[0][1] = __builtin_amdgcn_mfma_f64_16x16x4f64(a0f, b1f, acc[0][1], 0, 0, 0);
            acc[1][0] = __builtin_amdgcn_mfma_f64_16x16x4f64(a1f, b0f, acc[1][0], 0, 0, 0);
            acc[1][1] = __builtin_amdgcn_mfma_f64_16x16x4f64(a1f, b1f, acc[1][1], 0, 0, 0);
        }
        __syncthreads();
    }

#pragma unroll
    for (int tr = 0; tr < 2; ++tr)
#pragma unroll
        for (int tc = 0; tc < 2; ++tc)
#pragma unroll
            for (int n = 0; n < 4; ++n) {
                int r, c;
                dmap(dl, l15, l4, n, r, c);
                int row = row0 + wr * 32 + tr * 16 + r;
                int col = col0 + wc * 32 + tc * 16 + c;
                double v = acc[tr][tc][n];
                ll ix = ((ll)row * TS + trow) * D + (col & (D - 1));
                if (col < D) {
                    double v2 = v + (double)__bfloat162float(Kb[ix]);
                    Kb[ix] = __float2bfloat16((float)v2);
                } else {
                    Vb[ix] = (float)((double)Vb[ix] + v);
                }
            }
}

// ---------------- fused ENCODER step: gates(t) tiles + fold(t-1) tiles, one launch ----------------
struct EncArgs {
    const float *hFr, *hBr;
    float *hFw, *hBw, *cF, *cB;
    const float *WhPf, *WhPb, *tabPf, *tabPb;
    const int *srcF, *srcB;
    const float *WKVo;
    __hip_bfloat16 *Kb; float *Vb;
    int foldF, foldB;
    int K, useC, nG;
    const int *dlayp;
};

__global__ __launch_bounds__(256)
void enc_mega(EncArgs a)
{
    __shared__ double smem[2208];   // max(staging 17664 B, G 16896 B)
    const int bid = blockIdx.x;
    const int tid = threadIdx.x;
    const int dl  = a.dlayp[0];
    if (bid < a.nG) {
        const int dir = bid >> 9;             // 0 = F, 1 = B
        const int tt  = bid & 511;
        gates_body<0>(smem,
                      dir ? a.hBr : a.hFr, nullptr,
                      dir ? a.WhPb : a.WhPf, nullptr,
                      dir ? a.tabPb : a.tabPf,
                      dir ? a.srcB : a.srcF, TS,
                      dir ? a.cB : a.cF,
                      dir ? a.hBw : a.hFw,
                      tt & 31, tt >> 5, a.K, a.useC, dl, tid);
    } else {
        const int ff = bid - a.nG;            // 0..511
        const int fz = ff >> 8;
        fold_body(smem, fz ? a.hBr : a.hFr, a.WKVo, fz ? D : 0,
                  a.Kb, a.Vb, fz ? a.foldB : a.foldF,
                  ff & 15, (ff >> 4) & 15, dl, tid);
    }
}

// ---------------- decoder gates launch ----------------
struct DGArgs {
    const float *ctx, *h;
    const float *wiP, *whP, *tabP;
    const int *amax;
    float *cdec, *hw;
    const int *dlayp;
};

__global__ __launch_bounds__(256)
void dec_gates(DGArgs a)
{
    __shared__ double smem[2208];
    const int bid = blockIdx.x;   // 0..511
    gates_body<1>(smem, a.ctx, a.h, a.wiP, a.whP, a.tabP,
                  a.amax, 1, a.cdec, a.hw, bid & 31, bid >> 5, 2 * D, 1,
                  a.dlayp[0], threadIdx.x);
}

// ---------------- attention for step 0 (r14-verbatim, 512 threads) ----------------
__global__ void attn_kernel(const float* __restrict__ qtab, const int* __restrict__ amax,
                            const __hip_bfloat16* __restrict__ Kb, const float* __restrict__ Vb,
                            float* __restrict__ aout, int step, float* __restrict__ ctx)
{
    const int b = blockIdx.x, tid = threadIdx.x;
    __shared__ float qs[D];
    __shared__ float ss[TS];
    qs[tid] = qtab[(size_t)amax[b] * D + tid];
    __syncthreads();
    const int t = tid >> 3, l8 = tid & 7;
    const __hip_bfloat16* krow = Kb + ((size_t)b * TS + t) * D;
    double acc = 0.0;
    for (int d = l8; d < D; d += 8) acc += (double)qs[d] * (double)__bfloat162float(krow[d]);
    acc += __shfl_xor(acc, 4);
    acc += __shfl_xor(acc, 2);
    acc += __shfl_xor(acc, 1);
    if (l8 == 0) ss[t] = (float)acc;
    __syncthreads();
    if (tid < TS) {
        float v = ss[tid], mx = v;
#pragma unroll
        for (int o = 32; o; o >>= 1) mx = fmaxf(mx, __shfl_xor(mx, o));
        float e = expf(v - mx), sm = e;
#pragma unroll
        for (int o = 32; o; o >>= 1) sm += __shfl_xor(sm, o);
        float sc = e / sm;
        ss[tid] = sc;
        aout[((size_t)b * TT + step) * TS + tid] = sc;
    }
    __syncthreads();
    double a = 0.0;
    const float* vcol = Vb + (size_t)b * TS * D + tid;
    for (int t2 = 0; t2 < TS; ++t2) a += (double)ss[t2] * (double)vcol[(size_t)t2 * D];
    ctx[(size_t)b * D + tid] = (float)a;
}

// ---------------- fused out_argmax(st) + attn(st+1), one row per block, 512 threads ----------------
__global__ __launch_bounds__(512)
void out_attn(const float* __restrict__ h, const float* __restrict__ W,
              const float* __restrict__ bias, float* __restrict__ res,
              int step, int* __restrict__ amax,
              const float* __restrict__ qtab, const __hip_bfloat16* __restrict__ Kb,
              const float* __restrict__ Vb, float* __restrict__ aout,
              float* __restrict__ ctx, int doAttn)
{
    const int b = blockIdx.x, tid = threadIdx.x;
    __shared__ float hs[D];
    __shared__ double vals[DTGT];
    __shared__ int tok;
    __shared__ float qs[D];
    __shared__ float ss[TS];

    hs[tid] = h[(size_t)b * D + tid];
    __syncthreads();
    if (tid < DTGT) {
        double acc = (double)bias[tid];
        for (int k = 0; k < D; ++k) acc += (double)hs[k] * (double)W[(size_t)k * DTGT + tid];
        vals[tid] = acc;
        res[((size_t)b * TT + step) * DTGT + tid] = (float)acc;
    }
    __syncthreads();
    if (tid == 0) {
        double best = vals[0]; int bi = 0;
        for (int j = 1; j < DTGT; ++j) if (vals[j] > best) { best = vals[j]; bi = j; }
        amax[b] = bi;
        tok = bi;
    }
    __syncthreads();

    if (!doAttn) return;

    qs[tid] = qtab[(size_t)tok * D + tid];
    __syncthreads();
    const int t = tid >> 3, l8 = tid & 7;
    const __hip_bfloat16* krow = Kb + ((size_t)b * TS + t) * D;
    double acc = 0.0;
    for (int d = l8; d < D; d += 8) acc += (double)qs[d] * (double)__bfloat162float(krow[d]);
    acc += __shfl_xor(acc, 4);
    acc += __shfl_xor(acc, 2);
    acc += __shfl_xor(acc, 1);
    if (l8 == 0) ss[t] = (float)acc;
    __syncthreads();
    if (tid < TS) {
        float v = ss[tid], mx = v;
#pragma unroll
        for (int o = 32; o; o >>= 1) mx = fmaxf(mx, __shfl_xor(mx, o));
        float e = expf(v - mx), sm = e;
#pragma unroll
        for (int o = 32; o; o >>= 1) sm += __shfl_xor(sm, o);
        float sc = e / sm;
        ss[tid] = sc;
        aout[((size_t)b * TT + (step + 1)) * TS + tid] = sc;
    }
    __syncthreads();
    double a = 0.0;
    const float* vcol = Vb + (size_t)b * TS * D + tid;
    for (int t2 = 0; t2 < TS; ++t2) a += (double)ss[t2] * (double)vcol[(size_t)t2 * D];
    ctx[(size_t)b * D + tid] = (float)a;
}

// ---------------- decoder init: h0/c0 (r14-verbatim) ----------------
__global__ __launch_bounds__(512)
void hc_init(const float* __restrict__ hF, const float* __restrict__ hB,
             const float* __restrict__ cF, const float* __restrict__ cB,
             const float* __restrict__ hpw, const float* __restrict__ hpb,
             const float* __restrict__ cpw, const float* __restrict__ cpb,
             float* __restrict__ h0, float* __restrict__ c0)
{
    __shared__ float s0[D], s1[D], s2[D], s3[D];
    const int b = blockIdx.x, j = threadIdx.x;
    s0[j] = hF[(size_t)b * D + j]; s1[j] = hB[(size_t)b * D + j];
    s2[j] = cF[(size_t)b * D + j]; s3[j] = cB[(size_t)b * D + j];
    __syncthreads();
    double a = (double)hpb[j];
    for (int k = 0; k < D; ++k) a += (double)s0[k] * (double)hpw[(size_t)k * D + j];
    for (int k = 0; k < D; ++k) a += (double)s1[k] * (double)hpw[(size_t)(k + D) * D + j];
    h0[(size_t)b * D + j] = (float)tanh(a);
    a = (double)cpb[j];
    for (int k = 0; k < D; ++k) a += (double)s2[k] * (double)cpw[(size_t)k * D + j];
    for (int k = 0; k < D; ++k) a += (double)s3[k] * (double)cpw[(size_t)(k + D) * D + j];
    c0[(size_t)b * D + j] = (float)tanh(a);
}

__global__ void init_amax(const int* __restrict__ tgt, int* __restrict__ amax)
{
    int b = blockIdx.x * 256 + threadIdx.x;
    if (b < NB) amax[b] = tgt[(size_t)b * TT];
}

} // namespace k77

extern "C" void kernel_launch(void* const* d_in, const int* in_sizes, int n_in,
                              void* d_out, int out_size, void* d_ws, size_t ws_size,
                              hipStream_t stream)
{
    using namespace k77;
    (void)in_sizes; (void)n_in; (void)out_size;

    const int*   src        = (const int*)  d_in[0];
    const int*   tgt        = (const int*)  d_in[1];
    const float* enc_emb_w  = (const float*)d_in[2];
    const float* enc_wi_f   = (const float*)d_in[3];
    const float* enc_wh_f   = (const float*)d_in[4];
    const float* enc_bi_f   = (const float*)d_in[5];
    const float* enc_bh_f   = (const float*)d_in[6];
    const float* enc_wi_b   = (const float*)d_in[7];
    const float* enc_wh_b   = (const float*)d_in[8];
    const float* enc_bi_b   = (const float*)d_in[9];
    const float* enc_bh_b   = (const float*)d_in[10];
    const float* enc_post_w = (const float*)d_in[11];
    const float* enc_post_b = (const float*)d_in[12];
    const float* h_post_w   = (const float*)d_in[13];
    const float* h_post_b   = (const float*)d_in[14];
    const float* c_post_w   = (const float*)d_in[15];
    const float* c_post_b   = (const float*)d_in[16];
    const float* wq_w       = (const float*)d_in[17];
    const float* wq_b       = (const float*)d_in[18];
    const float* wk_w       = (const float*)d_in[19];
    const float* wk_b       = (const float*)d_in[20];
    const float* wv_w       = (const float*)d_in[21];
    const float* wv_b       = (const float*)d_in[22];
    const float* wo_w       = (const float*)d_in[23];
    const float* wo_b       = (const float*)d_in[24];
    const float* dec_emb_w  = (const float*)d_in[25];
    const float* dec_wi     = (const float*)d_in[26];
    const float* dec_wh     = (const float*)d_in[27];
    const float* dec_bi     = (const float*)d_in[28];
    const float* dec_bh     = (const float*)d_in[29];
    const float* dec_post_w = (const float*)d_in[30];
    const float* dec_post_b = (const float*)d_in[31];

    float* ws = (float*)d_ws;
    size_t off = 0;
    auto alloc = [&](size_t n) { float* p = ws + off; off += n; return p; };
    float* hF0     = alloc((size_t)NB * D);
    float* hF1     = alloc((size_t)NB * D);
    float* hB0     = alloc((size_t)NB * D);
    float* hB1     = alloc((size_t)NB * D);
    float* cF      = alloc((size_t)NB * D);
    float* cB      = alloc((size_t)NB * D);
    float* hd0     = alloc((size_t)NB * D);
    float* hd1     = alloc((size_t)NB * D);
    float* cdec    = alloc((size_t)NB * D);
    float* ctxb    = alloc((size_t)NB * D);
    float* tabPf   = alloc((size_t)128 * G4);
    float* tabPb   = alloc((size_t)128 * G4);
    float* dec_tabP= alloc((size_t)128 * G4);
    float* q_tab   = alloc((size_t)128 * D);
    float* WKVo    = alloc((size_t)1024 * 1024);
    float* bkvo    = alloc(1024);
    float* WhPf    = alloc((size_t)D * G4);
    float* WhPb    = alloc((size_t)D * G4);
    float* dec_wiP = alloc((size_t)D * G4);
    float* dec_whP = alloc((size_t)D * G4);
    float* Wv_tmp  = alloc((size_t)1024 * D);
    float* bv_tmp  = alloc(D);
    int*   amax    = (int*)alloc(1024);
    int*   dlayD   = (int*)alloc(64);

    const size_t commonF = off;
    const size_t kvCnt   = (size_t)NB * TS * D;
    const size_t need    = commonF * 4 + kvCnt * 2 + kvCnt * 4;   // ~249 MB

    if (ws_size < need) {
        hipMemsetAsync(d_out, 0x7F, 1024, stream);   // sentinel: ws too small
        return;
    }
    __hip_bfloat16* Kh = (__hip_bfloat16*)(ws + commonF);
    float*          Vf = (float*)((char*)Kh + kvCnt * 2);

    float* attn_out = (float*)d_out;
    float* res_out  = attn_out + (size_t)NB * TT * TS;

    const float scale = 0.044194173824159216f;   // 512^-0.5

    float* hFbuf[2] = {hF0, hF1};
    float* hBbuf[2] = {hB0, hB1};
    float* hd[2]    = {hd0, hd1};

    // ---------- MFMA layout probe ----------
    probe_mfma<<<1, 64, 0, stream>>>(dlayD);
    dlay_check<<<1, 64, 0, stream>>>(dlayD, attn_out);

    // ---------- precompute ----------
    Tab3 t3;
    t3.A0 = enc_emb_w; t3.A1 = enc_emb_w; t3.A2 = dec_emb_w;
    t3.B0 = enc_wi_f;  t3.B1 = enc_wi_b;  t3.B2 = dec_wi;
    t3.p0 = enc_bi_f;  t3.p1 = enc_bi_b;  t3.p2 = dec_bi;
    t3.q0 = enc_bh_f;  t3.q1 = enc_bh_b;  t3.q2 = dec_bh;
    t3.C0 = tabPf;     t3.C1 = tabPb;     t3.C2 = dec_tabP;
    tab3_gemm64<<<dim3(8, 128, 3), 256, 0, stream>>>(t3);
    tab_gemm64<<<dim3(2, 128), 256, 0, stream>>>(dec_emb_w, wq_w, wq_b, nullptr, q_tab, 128, D, D, D, scale, 0);
    tab_gemm64<<<dim3(2, 1024), 256, 0, stream>>>(enc_post_w, wk_w, nullptr, nullptr, WKVo, 1024, D, D, 1024, 1.f, 0);
    tab_gemm64<<<dim3(2, 1024), 256, 0, stream>>>(enc_post_w, wv_w, nullptr, nullptr, Wv_tmp, 1024, D, D, D, 1.f, 0);
    tab_gemm64<<<dim3(2, 1024), 256, 0, stream>>>(Wv_tmp, wo_w, nullptr, nullptr, WKVo + D, 1024, D, D, 1024, 1.f, 0);
    tab_gemm64<<<dim3(2, 1), 256, 0, stream>>>(enc_post_b, wk_w, wk_b, nullptr, bkvo, 1, D, D, D, 1.f, 0);
    tab_gemm64<<<dim3(2, 1), 256, 0, stream>>>(enc_post_b, wv_w, wv_b, nullptr, bv_tmp, 1, D, D, D, 1.f, 0);
    tab_gemm64<<<dim3(2, 1), 256, 0, stream>>>(bv_tmp, wo_w, wo_b, nullptr, bkvo + D, 1, D, D, D, 1.f, 0);
    Perm4 p4;
    p4.i0 = enc_wh_f; p4.o0 = WhPf;    p4.r0 = 0;
    p4.i1 = enc_wh_b; p4.o1 = WhPb;    p4.r1 = 0;
    p4.i2 = dec_wi;   p4.o2 = dec_wiP; p4.r2 = 512;
    p4.i3 = dec_wh;   p4.o3 = dec_whP; p4.r3 = 0;
    permW4<<<dim3(8, 512, 4), 256, 0, stream>>>(p4);
    init_kv<<<2048, 256, 0, stream>>>(bkvo, Kh, Vf);

    // ---------- encoder: 65 fused launches (gates(t) + fold(t-1)) ----------
    for (int t = 0; t < TS; ++t) {
        EncArgs ea;
        ea.hFr = hFbuf[t & 1]; ea.hBr = hBbuf[t & 1];
        ea.hFw = hFbuf[(t + 1) & 1]; ea.hBw = hBbuf[(t + 1) & 1];
        ea.cF = cF; ea.cB = cB;
        ea.WhPf = WhPf; ea.WhPb = WhPb; ea.tabPf = tabPf; ea.tabPb = tabPb;
        ea.srcF = src + t; ea.srcB = src + (TS - 1 - t);
        ea.WKVo = WKVo; ea.Kb = Kh; ea.Vb = Vf;
        ea.foldF = t - 1; ea.foldB = TS - t;
        ea.K = t ? D : 0; ea.useC = t ? 1 : 0; ea.nG = 1024;
        ea.dlayp = dlayD;
        const int grid = 1024 + (t ? 512 : 0);
        enc_mega<<<grid, 256, 0, stream>>>(ea);
    }
    {   // final fold for step 63
        EncArgs ea;
        ea.hFr = hFbuf[0]; ea.hBr = hBbuf[0];
        ea.hFw = nullptr; ea.hBw = nullptr; ea.cF = cF; ea.cB = cB;
        ea.WhPf = WhPf; ea.WhPb = WhPb; ea.tabPf = tabPf; ea.tabPb = tabPb;
        ea.srcF = src; ea.srcB = src;
        ea.WKVo = WKVo; ea.Kb = Kh; ea.Vb = Vf;
        ea.foldF = 63; ea.foldB = 0;
        ea.K = 0; ea.useC = 0; ea.nG = 0;
        ea.dlayp = dlayD;
        enc_mega<<<512, 256, 0, stream>>>(ea);
    }

    // ---------- decoder initial h, c ----------
    hc_init<<<NB, 512, 0, stream>>>(hFbuf[0], hBbuf[0], cF, cB,
                                    h_post_w, h_post_b, c_post_w, c_post_b, hd0, cdec);
    init_amax<<<4, 256, 0, stream>>>(tgt, amax);

    // ---------- decoder: attn(0) + 64x(gates; out+attn) ----------
    attn_kernel<<<NB, 512, 0, stream>>>(q_tab, amax, Kh, Vf, attn_out, 0, ctxb);
    for (int st = 0; st < TT; ++st) {
        DGArgs da;
        da.ctx = ctxb; da.h = hd[st & 1];
        da.wiP = dec_wiP; da.whP = dec_whP; da.tabP = dec_tabP;
        da.amax = amax; da.cdec = cdec; da.hw = hd[(st + 1) & 1];
        da.dlayp = dlayD;
        dec_gates<<<512, 256, 0, stream>>>(da);
        out_attn<<<NB, 512, 0, stream>>>(hd[(st + 1) & 1], dec_post_w, dec_post_b, res_out,
                                         st, amax, q_tab, Kh, Vf, attn_out, ctxb,
                                         st < TT - 1 ? 1 : 0);
    }
}

// Round 19
// 20653.052 us; speedup vs baseline: 4.8672x; 1.1090x over previous
//
#include <hip/hip_runtime.h>
#include <hip/hip_bf16.h>

namespace k77 {

typedef long long ll;
typedef double f64x4 __attribute__((ext_vector_type(4)));

constexpr int D    = 512;
constexpr int DTGT = 128;
constexpr int NB   = 1024;
constexpr int TS   = 64;
constexpr int TT   = 64;
constexpr int G4   = 2048;

// ---------------- runtime MFMA-f64 C/D-layout probe (r14-verified) ----------------
__global__ void probe_mfma(int* __restrict__ dlay)
{
    __shared__ double ref[256];
    __shared__ int ok[4];
    const int l = threadIdx.x;           // 64 threads
    const int l15 = l & 15, l4 = l >> 4;
    if (l < 4) ok[l] = 1;
    double a = 1.0 + 3.0 * l15 + 7.0 * l4;
    double b = 2.0 + 5.0 * l15 + 11.0 * l4;
    f64x4 d = {0.0, 0.0, 0.0, 0.0};
    d = __builtin_amdgcn_mfma_f64_16x16x4f64(a, b, d, 0, 0, 0);
    if (l < 16) {
        for (int j = 0; j < 16; ++j) {
            double s = 0.0;
            for (int k = 0; k < 4; ++k)
                s += (1.0 + 3.0 * l + 7.0 * k) * (2.0 + 5.0 * j + 11.0 * k);
            ref[l * 16 + j] = s;
        }
    }
    __syncthreads();
#pragma unroll
    for (int n = 0; n < 4; ++n) {
        if (d[n] != ref[(l4 * 4 + n) * 16 + l15]) atomicAnd(&ok[0], 0);
        if (d[n] != ref[(l4 + 4 * n) * 16 + l15]) atomicAnd(&ok[1], 0);
        if (d[n] != ref[l15 * 16 + (l4 * 4 + n)]) atomicAnd(&ok[2], 0);
        if (d[n] != ref[l15 * 16 + (l4 + 4 * n)]) atomicAnd(&ok[3], 0);
    }
    __syncthreads();
    if (l == 0) {
        int r = -1;
        for (int i = 3; i >= 0; --i) if (ok[i]) r = i;
        *dlay = r;
    }
}

__global__ void dlay_check(const int* __restrict__ dlay, float* __restrict__ out0)
{
    if (*dlay < 0)
        for (int i = threadIdx.x; i < 256; i += 64) out0[i] = 3.0e38f;
}

__device__ __forceinline__ void dmap(int dl, int l15, int l4, int n, int& r, int& c)
{
    if (dl == 1)      { r = l4 + 4 * n;  c = l15; }
    else if (dl == 2) { r = l15;         c = l4 * 4 + n; }
    else if (dl == 3) { r = l15;         c = l4 + 4 * n; }
    else              { r = l4 * 4 + n;  c = l15; }
}

// ---------------- precompute GEMM (f64 accumulate, f32 store) ----------------
__global__ void tab_gemm64(const float* __restrict__ A, const float* __restrict__ B,
                           const float* __restrict__ b1, const float* __restrict__ b2,
                           float* __restrict__ C, int M, int N, int K, int ldc, float scale, int perm)
{
    int j = blockIdx.x * 256 + threadIdx.x;
    int m = blockIdx.y;
    if (j >= N || m >= M) return;
    const float* ar = A + (size_t)m * K;
    double acc = 0.0;
    for (int k = 0; k < K; ++k) acc += (double)ar[k] * (double)B[(size_t)k * N + j];
    if (b1) acc += (double)b1[j];
    if (b2) acc += (double)b2[j];
    int j2 = perm ? ((j & 511) * 4 + (j >> 9)) : j;
    C[(size_t)m * ldc + j2] = (float)(acc * (double)scale);
}

// three 128x2048 permuted tables in one launch (z selects)
struct Tab3 { const float *A0,*A1,*A2,*B0,*B1,*B2,*p0,*p1,*p2,*q0,*q1,*q2; float *C0,*C1,*C2; };
__global__ void tab3_gemm64(Tab3 t)
{
    int j = blockIdx.x * 256 + threadIdx.x;   // 0..2047
    int m = blockIdx.y;                        // 0..127
    int z = blockIdx.z;
    const float* A  = z == 0 ? t.A0 : (z == 1 ? t.A1 : t.A2);
    const float* B  = z == 0 ? t.B0 : (z == 1 ? t.B1 : t.B2);
    const float* b1 = z == 0 ? t.p0 : (z == 1 ? t.p1 : t.p2);
    const float* b2 = z == 0 ? t.q0 : (z == 1 ? t.q1 : t.q2);
    float*       C  = z == 0 ? t.C0 : (z == 1 ? t.C1 : t.C2);
    const float* ar = A + (size_t)m * D;
    double acc = 0.0;
    for (int k = 0; k < D; ++k) acc += (double)ar[k] * (double)B[(size_t)k * G4 + j];
    acc += (double)b1[j];
    acc += (double)b2[j];
    C[(size_t)m * G4 + (j & 511) * 4 + (j >> 9)] = (float)acc;
}

// four 512x2048 weight permutes in one launch (z selects)
struct Perm4 { const float *i0,*i1,*i2,*i3; float *o0,*o1,*o2,*o3; int r0,r1,r2,r3; };
__global__ void permW4(Perm4 p)
{
    int j = blockIdx.x * 256 + threadIdx.x;   // 0..2047
    int k = blockIdx.y;                        // 0..511
    int z = blockIdx.z;
    const float* in = z == 0 ? p.i0 : (z == 1 ? p.i1 : (z == 2 ? p.i2 : p.i3));
    float*      out = z == 0 ? p.o0 : (z == 1 ? p.o1 : (z == 2 ? p.o2 : p.o3));
    int      rowoff = z == 0 ? p.r0 : (z == 1 ? p.r1 : (z == 2 ? p.r2 : p.r3));
    out[(size_t)k * G4 + (j & 511) * 4 + (j >> 9)] = in[(size_t)(k + rowoff) * G4 + j];
}

__global__ void init_kv(const float* __restrict__ bkvo, __hip_bfloat16* __restrict__ Kb,
                        float* __restrict__ Vb)
{
    for (ll i = (ll)blockIdx.x * 256 + threadIdx.x; i < (ll)NB * TS * D; i += (ll)gridDim.x * 256) {
        int d = (int)(i & (D - 1));
        Kb[i] = __float2bfloat16(bkvo[d]);
        Vb[i] = bkvo[D + d];
    }
}

// ---------------- gates GEMM (MFMA f64) + LSTM cell body — 64x32 tile ----------------
// 4 waves: wr=wave>>1 rows (2x32), wc=wave&1 cols (2x16). Per-output K-order identical
// to r18 (sequential chunks, same 4-k MFMA slabs) + single f64 tab-add-then-round.
template<int USE2>
__device__ __forceinline__ void gates_body(
    double* smem, const float* a0, const float* a1,
    const float* B0, const float* B1,
    const float* tab, const int* idx, int idxStride,
    float* cb, float* hb, int bx, int by, int K, int useC, int dl, int tid)
{
    float* As = (float*)smem;                   // [64 m][34 k]
    float* Bs = As + 64 * 34;                   // [32 j][35 kr]
    const int row0 = by * 64, col0 = bx * 32;
    const int wave = tid >> 6, lane = tid & 63;
    const int wr = wave >> 1, wc = wave & 1;
    const int l15 = lane & 15, l4 = lane >> 4;

    f64x4 acc[2];
    acc[0] = (f64x4){0.0, 0.0, 0.0, 0.0};
    acc[1] = (f64x4){0.0, 0.0, 0.0, 0.0};

    for (int k0 = 0; k0 < K; k0 += 32) {
#pragma unroll
        for (int l = 0; l < 8; ++l) {          // A: 64 rows x 32 k
            int t = tid + l * 256;
            int k = t & 31, m = t >> 5;
            int kk = k0 + k;
            float v;
            if (USE2 && kk >= D) v = a1[(size_t)(row0 + m) * D + (kk - D)];
            else                 v = a0[(size_t)(row0 + m) * D + kk];
            As[m * 34 + k] = v;
        }
#pragma unroll
        for (int l = 0; l < 4; ++l) {          // B: 32 cols x 32 k
            int t = tid + l * 256;
            int j = t & 31, kr = t >> 5;
            int kk = k0 + kr;
            float v;
            if (USE2 && kk >= D) v = B1[(size_t)(kk - D) * G4 + col0 + j];
            else                 v = B0[(size_t)kk * G4 + col0 + j];
            Bs[j * 35 + kr] = v;
        }
        __syncthreads();
#pragma unroll
        for (int kk4 = 0; kk4 < 8; ++kk4) {
            const int kr = kk4 * 4 + l4;
            double a0f = (double)As[(wr * 32 + l15) * 34 + kr];
            double a1f = (double)As[(wr * 32 + 16 + l15) * 34 + kr];
            double b0f = (double)Bs[(wc * 16 + l15) * 35 + kr];
            acc[0] = __builtin_amdgcn_mfma_f64_16x16x4f64(a0f, b0f, acc[0], 0, 0, 0);
            acc[1] = __builtin_amdgcn_mfma_f64_16x16x4f64(a1f, b0f, acc[1], 0, 0, 0);
        }
        __syncthreads();
    }

    // bounce acc -> f32 gates (tab added in f64, rounded once — r18-identical values)
    float* G = (float*)smem;                    // [64][33]
#pragma unroll
    for (int tr = 0; tr < 2; ++tr)
#pragma unroll
        for (int n = 0; n < 4; ++n) {
            int r, c;
            dmap(dl, l15, l4, n, r, c);
            int lr = wr * 32 + tr * 16 + r;
            int lc = wc * 16 + c;
            const float* trw = tab + (size_t)idx[(size_t)(row0 + lr) * idxStride] * G4;
            G[lr * 33 + lc] = (float)(acc[tr][n] + (double)trw[col0 + lc]);
        }
    __syncthreads();

    // cell: 256 threads x (2 rows x 1 quad)
    const int ty = tid >> 3, tx = tid & 7;      // ty 0..31, tx 0..7
    const int d  = (col0 + tx * 4) >> 2;
#pragma unroll
    for (int i = 0; i < 2; ++i) {
        int rl  = ty * 2 + i;
        int row = row0 + rl;
        float gi = G[rl * 33 + tx * 4 + 0];
        float gf = G[rl * 33 + tx * 4 + 1];
        float gg = G[rl * 33 + tx * 4 + 2];
        float go = G[rl * 33 + tx * 4 + 3];
        float c  = useC ? cb[(size_t)row * D + d] : 0.f;
        float si = 1.f / (1.f + expf(-gi));
        float sf = 1.f / (1.f + expf(-gf));
        float so = 1.f / (1.f + expf(-go));
        c = sf * c + si * tanhf(gg);
        cb[(size_t)row * D + d] = c;
        hb[(size_t)row * D + d] = so * tanhf(c);
    }
}

// ---------------- K/V' fold body (64x64, transposed staging, r18-verbatim) ----------------
__device__ __forceinline__ void fold_body(
    double* smem, const float* h, const float* W, int rowoff,
    __hip_bfloat16* Kb, float* Vb, int trow, int bx, int by, int dl, int tid)
{
    float* As = (float*)smem;                   // [64 m][34 k]
    float* Bs = As + 64 * 34;                   // [64 j][35 kr]
    const int row0 = by * 64, col0 = bx * 64;
    const int wave = tid >> 6, lane = tid & 63;
    const int wr = wave >> 1, wc = wave & 1;
    const int l15 = lane & 15, l4 = lane >> 4;

    f64x4 acc[2][2];
#pragma unroll
    for (int i = 0; i < 2; ++i)
#pragma unroll
        for (int j = 0; j < 2; ++j) acc[i][j] = (f64x4){0.0, 0.0, 0.0, 0.0};

    for (int k0 = 0; k0 < D; k0 += 32) {
#pragma unroll
        for (int l = 0; l < 8; ++l) {
            int t = tid + l * 256;
            {   int k = t & 31, m = t >> 5;
                As[m * 34 + k] = h[(size_t)(row0 + m) * D + k0 + k];
            }
            {   int j = t & 63, kr = t >> 6;
                Bs[j * 35 + kr] = W[(size_t)(rowoff + k0 + kr) * 1024 + col0 + j];
            }
        }
        __syncthreads();
#pragma unroll
        for (int kk4 = 0; kk4 < 8; ++kk4) {
            const int kr = kk4 * 4 + l4;
            double a0f = (double)As[(wr * 32 + l15) * 34 + kr];
            double a1f = (double)As[(wr * 32 + 16 + l15) * 34 + kr];
            double b0f = (double)Bs[(wc * 32 + l15) * 35 + kr];
            double b1f = (double)Bs[(wc * 32 + 16 + l15) * 35 + kr];
            acc[0][0] = __builtin_amdgcn_mfma_f64_16x16x4f64(a0f, b0f, acc[0][0], 0, 0, 0);
            acc[0][1] = __builtin_amdgcn_mfma_f64_16x16x4f64(a0f, b1f, acc[0][1], 0, 0, 0);
            acc[1][0] = __builtin_amdgcn_mfma_f64_16x16x4f64(a1f, b0f, acc[1][0], 0, 0, 0);
            acc[1][1] = __builtin_amdgcn_mfma_f64_16x16x4f64(a1f, b1f, acc[1][1], 0, 0, 0);
        }
        __syncthreads();
    }

#pragma unroll
    for (int tr = 0; tr < 2; ++tr)
#pragma unroll
        for (int tc = 0; tc < 2; ++tc)
#pragma unroll
            for (int n = 0; n < 4; ++n) {
                int r, c;
                dmap(dl, l15, l4, n, r, c);
                int row = row0 + wr * 32 + tr * 16 + r;
                int col = col0 + wc * 32 + tc * 16 + c;
                double v = acc[tr][tc][n];
                ll ix = ((ll)row * TS + trow) * D + (col & (D - 1));
                if (col < D) {
                    double v2 = v + (double)__bfloat162float(Kb[ix]);
                    Kb[ix] = __float2bfloat16((float)v2);
                } else {
                    Vb[ix] = (float)((double)Vb[ix] + v);
                }
            }
}

// ---------------- fused ENCODER step: gates(t) 2048 tiles + fold(t-1) 512 tiles ----------------
struct EncArgs {
    const float *hFr, *hBr;
    float *hFw, *hBw, *cF, *cB;
    const float *WhPf, *WhPb, *tabPf, *tabPb;
    const int *srcF, *srcB;
    const float *WKVo;
    __hip_bfloat16 *Kb; float *Vb;
    int foldF, foldB;
    int K, useC, nG;
    const int *dlayp;
};

__global__ __launch_bounds__(256)
void enc_mega(EncArgs a)
{
    __shared__ double smem[2208];   // fold staging 17664 B is the max
    const int bid = blockIdx.x;
    const int tid = threadIdx.x;
    const int dl  = a.dlayp[0];
    if (bid < a.nG) {
        const int dir = bid >> 10;            // 0 = F, 1 = B (1024 tiles each)
        const int tt  = bid & 1023;           // bx 0..63 (col), by 0..15 (row)
        gates_body<0>(smem,
                      dir ? a.hBr : a.hFr, nullptr,
                      dir ? a.WhPb : a.WhPf, nullptr,
                      dir ? a.tabPb : a.tabPf,
                      dir ? a.srcB : a.srcF, TS,
                      dir ? a.cB : a.cF,
                      dir ? a.hBw : a.hFw,
                      tt & 63, tt >> 6, a.K, a.useC, dl, tid);
    } else {
        const int ff = bid - a.nG;            // 0..511
        const int fz = ff >> 8;
        fold_body(smem, fz ? a.hBr : a.hFr, a.WKVo, fz ? D : 0,
                  a.Kb, a.Vb, fz ? a.foldB : a.foldF,
                  ff & 15, (ff >> 4) & 15, dl, tid);
    }
}

// ---------------- decoder gates launch (1024 tiles of 64x32) ----------------
struct DGArgs {
    const float *ctx, *h;
    const float *wiP, *whP, *tabP;
    const int *amax;
    float *cdec, *hw;
    const int *dlayp;
};

__global__ __launch_bounds__(256)
void dec_gates(DGArgs a)
{
    __shared__ double smem[1648];   // gates staging 13184 B
    const int bid = blockIdx.x;     // 0..1023: bx 0..63, by 0..15
    gates_body<1>(smem, a.ctx, a.h, a.wiP, a.whP, a.tabP,
                  a.amax, 1, a.cdec, a.hw, bid & 63, bid >> 6, 2 * D, 1,
                  a.dlayp[0], threadIdx.x);
}

// ---------------- attention for step 0 (r14-verbatim, 512 threads) ----------------
__global__ void attn_kernel(const float* __restrict__ qtab, const int* __restrict__ amax,
                            const __hip_bfloat16* __restrict__ Kb, const float* __restrict__ Vb,
                            float* __restrict__ aout, int step, float* __restrict__ ctx)
{
    const int b = blockIdx.x, tid = threadIdx.x;
    __shared__ float qs[D];
    __shared__ float ss[TS];
    qs[tid] = qtab[(size_t)amax[b] * D + tid];
    __syncthreads();
    const int t = tid >> 3, l8 = tid & 7;
    const __hip_bfloat16* krow = Kb + ((size_t)b * TS + t) * D;
    double acc = 0.0;
    for (int d = l8; d < D; d += 8) acc += (double)qs[d] * (double)__bfloat162float(krow[d]);
    acc += __shfl_xor(acc, 4);
    acc += __shfl_xor(acc, 2);
    acc += __shfl_xor(acc, 1);
    if (l8 == 0) ss[t] = (float)acc;
    __syncthreads();
    if (tid < TS) {
        float v = ss[tid], mx = v;
#pragma unroll
        for (int o = 32; o; o >>= 1) mx = fmaxf(mx, __shfl_xor(mx, o));
        float e = expf(v - mx), sm = e;
#pragma unroll
        for (int o = 32; o; o >>= 1) sm += __shfl_xor(sm, o);
        float sc = e / sm;
        ss[tid] = sc;
        aout[((size_t)b * TT + step) * TS + tid] = sc;
    }
    __syncthreads();
    double a = 0.0;
    const float* vcol = Vb + (size_t)b * TS * D + tid;
    for (int t2 = 0; t2 < TS; ++t2) a += (double)ss[t2] * (double)vcol[(size_t)t2 * D];
    ctx[(size_t)b * D + tid] = (float)a;
}

// ---------------- fused out_argmax(st) + attn(st+1), one row per block, 512 threads ----------------
__global__ __launch_bounds__(512)
void out_attn(const float* __restrict__ h, const float* __restrict__ W,
              const float* __restrict__ bias, float* __restrict__ res,
              int step, int* __restrict__ amax,
              const float* __restrict__ qtab, const __hip_bfloat16* __restrict__ Kb,
              const float* __restrict__ Vb, float* __restrict__ aout,
              float* __restrict__ ctx, int doAttn)
{
    const int b = blockIdx.x, tid = threadIdx.x;
    __shared__ float hs[D];
    __shared__ double vals[DTGT];
    __shared__ int tok;
    __shared__ float qs[D];
    __shared__ float ss[TS];

    hs[tid] = h[(size_t)b * D + tid];
    __syncthreads();
    if (tid < DTGT) {
        double acc = (double)bias[tid];
        for (int k = 0; k < D; ++k) acc += (double)hs[k] * (double)W[(size_t)k * DTGT + tid];
        vals[tid] = acc;
        res[((size_t)b * TT + step) * DTGT + tid] = (float)acc;
    }
    __syncthreads();
    if (tid == 0) {
        double best = vals[0]; int bi = 0;
        for (int j = 1; j < DTGT; ++j) if (vals[j] > best) { best = vals[j]; bi = j; }
        amax[b] = bi;
        tok = bi;
    }
    __syncthreads();

    if (!doAttn) return;

    qs[tid] = qtab[(size_t)tok * D + tid];
    __syncthreads();
    const int t = tid >> 3, l8 = tid & 7;
    const __hip_bfloat16* krow = Kb + ((size_t)b * TS + t) * D;
    double acc = 0.0;
    for (int d = l8; d < D; d += 8) acc += (double)qs[d] * (double)__bfloat162float(krow[d]);
    acc += __shfl_xor(acc, 4);
    acc += __shfl_xor(acc, 2);
    acc += __shfl_xor(acc, 1);
    if (l8 == 0) ss[t] = (float)acc;
    __syncthreads();
    if (tid < TS) {
        float v = ss[tid], mx = v;
#pragma unroll
        for (int o = 32; o; o >>= 1) mx = fmaxf(mx, __shfl_xor(mx, o));
        float e = expf(v - mx), sm = e;
#pragma unroll
        for (int o = 32; o; o >>= 1) sm += __shfl_xor(sm, o);
        float sc = e / sm;
        ss[tid] = sc;
        aout[((size_t)b * TT + (step + 1)) * TS + tid] = sc;
    }
    __syncthreads();
    double a = 0.0;
    const float* vcol = Vb + (size_t)b * TS * D + tid;
    for (int t2 = 0; t2 < TS; ++t2) a += (double)ss[t2] * (double)vcol[(size_t)t2 * D];
    ctx[(size_t)b * D + tid] = (float)a;
}

// ---------------- decoder init: h0/c0 (r14-verbatim) ----------------
__global__ __launch_bounds__(512)
void hc_init(const float* __restrict__ hF, const float* __restrict__ hB,
             const float* __restrict__ cF, const float* __restrict__ cB,
             const float* __restrict__ hpw, const float* __restrict__ hpb,
             const float* __restrict__ cpw, const float* __restrict__ cpb,
             float* __restrict__ h0, float* __restrict__ c0)
{
    __shared__ float s0[D], s1[D], s2[D], s3[D];
    const int b = blockIdx.x, j = threadIdx.x;
    s0[j] = hF[(size_t)b * D + j]; s1[j] = hB[(size_t)b * D + j];
    s2[j] = cF[(size_t)b * D + j]; s3[j] = cB[(size_t)b * D + j];
    __syncthreads();
    double a = (double)hpb[j];
    for (int k = 0; k < D; ++k) a += (double)s0[k] * (double)hpw[(size_t)k * D + j];
    for (int k = 0; k < D; ++k) a += (double)s1[k] * (double)hpw[(size_t)(k + D) * D + j];
    h0[(size_t)b * D + j] = (float)tanh(a);
    a = (double)cpb[j];
    for (int k = 0; k < D; ++k) a += (double)s2[k] * (double)cpw[(size_t)k * D + j];
    for (int k = 0; k < D; ++k) a += (double)s3[k] * (double)cpw[(size_t)(k + D) * D + j];
    c0[(size_t)b * D + j] = (float)tanh(a);
}

__global__ void init_amax(const int* __restrict__ tgt, int* __restrict__ amax)
{
    int b = blockIdx.x * 256 + threadIdx.x;
    if (b < NB) amax[b] = tgt[(size_t)b * TT];
}

} // namespace k77

extern "C" void kernel_launch(void* const* d_in, const int* in_sizes, int n_in,
                              void* d_out, int out_size, void* d_ws, size_t ws_size,
                              hipStream_t stream)
{
    using namespace k77;
    (void)in_sizes; (void)n_in; (void)out_size;

    const int*   src        = (const int*)  d_in[0];
    const int*   tgt        = (const int*)  d_in[1];
    const float* enc_emb_w  = (const float*)d_in[2];
    const float* enc_wi_f   = (const float*)d_in[3];
    const float* enc_wh_f   = (const float*)d_in[4];
    const float* enc_bi_f   = (const float*)d_in[5];
    const float* enc_bh_f   = (const float*)d_in[6];
    const float* enc_wi_b   = (const float*)d_in[7];
    const float* enc_wh_b   = (const float*)d_in[8];
    const float* enc_bi_b   = (const float*)d_in[9];
    const float* enc_bh_b   = (const float*)d_in[10];
    const float* enc_post_w = (const float*)d_in[11];
    const float* enc_post_b = (const float*)d_in[12];
    const float* h_post_w   = (const float*)d_in[13];
    const float* h_post_b   = (const float*)d_in[14];
    const float* c_post_w   = (const float*)d_in[15];
    const float* c_post_b   = (const float*)d_in[16];
    const float* wq_w       = (const float*)d_in[17];
    const float* wq_b       = (const float*)d_in[18];
    const float* wk_w       = (const float*)d_in[19];
    const float* wk_b       = (const float*)d_in[20];
    const float* wv_w       = (const float*)d_in[21];
    const float* wv_b       = (const float*)d_in[22];
    const float* wo_w       = (const float*)d_in[23];
    const float* wo_b       = (const float*)d_in[24];
    const float* dec_emb_w  = (const float*)d_in[25];
    const float* dec_wi     = (const float*)d_in[26];
    const float* dec_wh     = (const float*)d_in[27];
    const float* dec_bi     = (const float*)d_in[28];
    const float* dec_bh     = (const float*)d_in[29];
    const float* dec_post_w = (const float*)d_in[30];
    const float* dec_post_b = (const float*)d_in[31];

    float* ws = (float*)d_ws;
    size_t off = 0;
    auto alloc = [&](size_t n) { float* p = ws + off; off += n; return p; };
    float* hF0     = alloc((size_t)NB * D);
    float* hF1     = alloc((size_t)NB * D);
    float* hB0     = alloc((size_t)NB * D);
    float* hB1     = alloc((size_t)NB * D);
    float* cF      = alloc((size_t)NB * D);
    float* cB      = alloc((size_t)NB * D);
    float* hd0     = alloc((size_t)NB * D);
    float* hd1     = alloc((size_t)NB * D);
    float* cdec    = alloc((size_t)NB * D);
    float* ctxb    = alloc((size_t)NB * D);
    float* tabPf   = alloc((size_t)128 * G4);
    float* tabPb   = alloc((size_t)128 * G4);
    float* dec_tabP= alloc((size_t)128 * G4);
    float* q_tab   = alloc((size_t)128 * D);
    float* WKVo    = alloc((size_t)1024 * 1024);
    float* bkvo    = alloc(1024);
    float* WhPf    = alloc((size_t)D * G4);
    float* WhPb    = alloc((size_t)D * G4);
    float* dec_wiP = alloc((size_t)D * G4);
    float* dec_whP = alloc((size_t)D * G4);
    float* Wv_tmp  = alloc((size_t)1024 * D);
    float* bv_tmp  = alloc(D);
    int*   amax    = (int*)alloc(1024);
    int*   dlayD   = (int*)alloc(64);

    const size_t commonF = off;
    const size_t kvCnt   = (size_t)NB * TS * D;
    const size_t need    = commonF * 4 + kvCnt * 2 + kvCnt * 4;   // ~249 MB

    if (ws_size < need) {
        hipMemsetAsync(d_out, 0x7F, 1024, stream);   // sentinel: ws too small
        return;
    }
    __hip_bfloat16* Kh = (__hip_bfloat16*)(ws + commonF);
    float*          Vf = (float*)((char*)Kh + kvCnt * 2);

    float* attn_out = (float*)d_out;
    float* res_out  = attn_out + (size_t)NB * TT * TS;

    const float scale = 0.044194173824159216f;   // 512^-0.5

    float* hFbuf[2] = {hF0, hF1};
    float* hBbuf[2] = {hB0, hB1};
    float* hd[2]    = {hd0, hd1};

    // ---------- MFMA layout probe ----------
    probe_mfma<<<1, 64, 0, stream>>>(dlayD);
    dlay_check<<<1, 64, 0, stream>>>(dlayD, attn_out);

    // ---------- precompute ----------
    Tab3 t3;
    t3.A0 = enc_emb_w; t3.A1 = enc_emb_w; t3.A2 = dec_emb_w;
    t3.B0 = enc_wi_f;  t3.B1 = enc_wi_b;  t3.B2 = dec_wi;
    t3.p0 = enc_bi_f;  t3.p1 = enc_bi_b;  t3.p2 = dec_bi;
    t3.q0 = enc_bh_f;  t3.q1 = enc_bh_b;  t3.q2 = dec_bh;
    t3.C0 = tabPf;     t3.C1 = tabPb;     t3.C2 = dec_tabP;
    tab3_gemm64<<<dim3(8, 128, 3), 256, 0, stream>>>(t3);
    tab_gemm64<<<dim3(2, 128), 256, 0, stream>>>(dec_emb_w, wq_w, wq_b, nullptr, q_tab, 128, D, D, D, scale, 0);
    tab_gemm64<<<dim3(2, 1024), 256, 0, stream>>>(enc_post_w, wk_w, nullptr, nullptr, WKVo, 1024, D, D, 1024, 1.f, 0);
    tab_gemm64<<<dim3(2, 1024), 256, 0, stream>>>(enc_post_w, wv_w, nullptr, nullptr, Wv_tmp, 1024, D, D, D, 1.f, 0);
    tab_gemm64<<<dim3(2, 1024), 256, 0, stream>>>(Wv_tmp, wo_w, nullptr, nullptr, WKVo + D, 1024, D, D, 1024, 1.f, 0);
    tab_gemm64<<<dim3(2, 1), 256, 0, stream>>>(enc_post_b, wk_w, wk_b, nullptr, bkvo, 1, D, D, D, 1.f, 0);
    tab_gemm64<<<dim3(2, 1), 256, 0, stream>>>(enc_post_b, wv_w, wv_b, nullptr, bv_tmp, 1, D, D, D, 1.f, 0);
    tab_gemm64<<<dim3(2, 1), 256, 0, stream>>>(bv_tmp, wo_w, wo_b, nullptr, bkvo + D, 1, D, D, D, 1.f, 0);
    Perm4 p4;
    p4.i0 = enc_wh_f; p4.o0 = WhPf;    p4.r0 = 0;
    p4.i1 = enc_wh_b; p4.o1 = WhPb;    p4.r1 = 0;
    p4.i2 = dec_wi;   p4.o2 = dec_wiP; p4.r2 = 512;
    p4.i3 = dec_wh;   p4.o3 = dec_whP; p4.r3 = 0;
    permW4<<<dim3(8, 512, 4), 256, 0, stream>>>(p4);
    init_kv<<<2048, 256, 0, stream>>>(bkvo, Kh, Vf);

    // ---------- encoder: 65 fused launches (gates(t) + fold(t-1)) ----------
    for (int t = 0; t < TS; ++t) {
        EncArgs ea;
        ea.hFr = hFbuf[t & 1]; ea.hBr = hBbuf[t & 1];
        ea.hFw = hFbuf[(t + 1) & 1]; ea.hBw = hBbuf[(t + 1) & 1];
        ea.cF = cF; ea.cB = cB;
        ea.WhPf = WhPf; ea.WhPb = WhPb; ea.tabPf = tabPf; ea.tabPb = tabPb;
        ea.srcF = src + t; ea.srcB = src + (TS - 1 - t);
        ea.WKVo = WKVo; ea.Kb = Kh; ea.Vb = Vf;
        ea.foldF = t - 1; ea.foldB = TS - t;
        ea.K = t ? D : 0; ea.useC = t ? 1 : 0; ea.nG = 2048;
        ea.dlayp = dlayD;
        const int grid = 2048 + (t ? 512 : 0);
        enc_mega<<<grid, 256, 0, stream>>>(ea);
    }
    {   // final fold for step 63
        EncArgs ea;
        ea.hFr = hFbuf[0]; ea.hBr = hBbuf[0];
        ea.hFw = nullptr; ea.hBw = nullptr; ea.cF = cF; ea.cB = cB;
        ea.WhPf = WhPf; ea.WhPb = WhPb; ea.tabPf = tabPf; ea.tabPb = tabPb;
        ea.srcF = src; ea.srcB = src;
        ea.WKVo = WKVo; ea.Kb = Kh; ea.Vb = Vf;
        ea.foldF = 63; ea.foldB = 0;
        ea.K = 0; ea.useC = 0; ea.nG = 0;
        ea.dlayp = dlayD;
        enc_mega<<<512, 256, 0, stream>>>(ea);
    }

    // ---------- decoder initial h, c ----------
    hc_init<<<NB, 512, 0, stream>>>(hFbuf[0], hBbuf[0], cF, cB,
                                    h_post_w, h_post_b, c_post_w, c_post_b, hd0, cdec);
    init_amax<<<4, 256, 0, stream>>>(tgt, amax);

    // ---------- decoder: attn(0) + 64x(gates; out+attn) ----------
    attn_kernel<<<NB, 512, 0, stream>>>(q_tab, amax, Kh, Vf, attn_out, 0, ctxb);
    for (int st = 0; st < TT; ++st) {
        DGArgs da;
        da.ctx = ctxb; da.h = hd[st & 1];
        da.wiP = dec_wiP; da.whP = dec_whP; da.tabP = dec_tabP;
        da.amax = amax; da.cdec = cdec; da.hw = hd[(st + 1) & 1];
        da.dlayp = dlayD;
        dec_gates<<<1024, 256, 0, stream>>>(da);
        out_attn<<<NB, 512, 0, stream>>>(hd[(st + 1) & 1], dec_post_w, dec_post_b, res_out,
                                         st, amax, q_tab, Kh, Vf, attn_out, ctxb,
                                         st < TT - 1 ? 1 : 0);
    }
}